// Round 11
// baseline (229.146 us; speedup 1.0000x reference)
//
#include <hip/hip_runtime.h>
#include <math.h>

// ---- problem constants ----
#define TOK    50176      // 2*8*56*56 tokens
#define CH     128
#define NWIN   128        // B * 64 windows
#define NTOK   392        // 8*7*7 tokens per window
#define NHEADS 4
#define QSCALE 0.17677669529663687f   // 32^-0.5
#define LOG2E  1.44269504f
#define LNEPS  1e-3f

typedef unsigned short u16;
typedef unsigned int   u32;
typedef u16   u16x4  __attribute__((ext_vector_type(4)));
typedef u16   u16x8  __attribute__((ext_vector_type(8)));
typedef u32   u32x4  __attribute__((ext_vector_type(4)));
typedef short s16x8  __attribute__((ext_vector_type(8)));
typedef float f32x4  __attribute__((ext_vector_type(4)));

__device__ __forceinline__ float bf2f(u16 u) {
    return __uint_as_float(((u32)u) << 16);
}
__device__ __forceinline__ u16 f2bf(float f) {
    u32 u = __float_as_uint(f);
    return (u16)((u + 0x7fffu + ((u >> 16) & 1u)) >> 16);
}
// packed f32x2 -> bf16x2 (RNE), lo = a, hi = b
__device__ __forceinline__ u32 pkbf(float a, float b) {
    u32 r;
    asm("v_cvt_pk_bf16_f32 %0, %1, %2" : "=v"(r) : "v"(a), "v"(b));
    return r;
}
__device__ __forceinline__ f32x4 mfma16(s16x8 a, s16x8 b, f32x4 c) {
    return __builtin_amdgcn_mfma_f32_16x16x32_bf16(a, b, c, 0, 0, 0);
}

// token m in window layout -> flat token index in original layout (+3 roll)
__device__ __forceinline__ int src_index(int m) {
    int b = m / NTOK, t = m - b * NTOK;
    int batch = b >> 6, wIdx = b & 63;
    int bh = wIdx >> 3, bw = wIdx & 7;
    int d = t / 49, rem = t - d * 49;
    int h7 = rem / 7, w7 = rem - h7 * 7;
    int h = bh * 7 + h7 + 3; if (h >= 56) h -= 56;
    int w = bw * 7 + w7 + 3; if (w >= 56) w -= 56;
    return ((batch * 8 + d) * 56 + h) * 56 + w;
}

// ---- weight transpose + f32->bf16 convert: dst[n][k] = src[k][n] * sc ----
__global__ __launch_bounds__(256) void convT(
    const float* __restrict__ src, u16* __restrict__ dst,
    int K, int N, int scaleN, float scaleArg)
{
    __shared__ float t[32][33];
    int n0 = blockIdx.x * 32, k0 = blockIdx.y * 32;
    int tx = threadIdx.x & 31, ty = threadIdx.x >> 5;   // ty 0..7
    #pragma unroll
    for (int r = 0; r < 4; ++r)
        t[ty + r * 8][tx] = src[(size_t)(k0 + ty + r * 8) * N + n0 + tx];
    __syncthreads();
    #pragma unroll
    for (int r = 0; r < 4; ++r) {
        int n = n0 + ty + r * 8;
        float sc = (n < scaleN) ? scaleArg : 1.f;
        dst[(size_t)n * K + k0 + tx] = f2bf(t[tx][ty + r * 8] * sc);
    }
}

// ---- LN1: gather f32 x via src_index, LN, -> bf16 window layout ----
__global__ __launch_bounds__(128) void ln_kernel(
    const float* __restrict__ xin,
    const float* __restrict__ g, const float* __restrict__ bta,
    u16* __restrict__ out)
{
    int m = blockIdx.x, c = threadIdx.x;
    float v = xin[(size_t)src_index(m) * CH + c];
    float s1 = v, s2 = v * v;
    #pragma unroll
    for (int o = 32; o; o >>= 1) { s1 += __shfl_xor(s1, o); s2 += __shfl_xor(s2, o); }
    __shared__ float ps[2][2];
    int w = c >> 6;
    if ((c & 63) == 0) { ps[w][0] = s1; ps[w][1] = s2; }
    __syncthreads();
    s1 = ps[0][0] + ps[1][0];
    s2 = ps[0][1] + ps[1][1];
    float mean = s1 * (1.f / CH);
    float var  = s2 * (1.f / CH) - mean * mean;
    float r = rsqrtf(var + LNEPS);
    out[(size_t)m * CH + c] = f2bf((v - mean) * r * g[c] + bta[c]);
}

// ---- MFMA GEMM, BM=64 x BN=128, 512 threads (8 waves = 4m x 2n), BK=128 ----
template<int EPI, int KTOT>
__global__ __launch_bounds__(512, 6) void gemm_mfma(
    const u16* __restrict__ A, const u16* __restrict__ W,
    const float* __restrict__ bias, void* __restrict__ outp,
    int Nn, const float* __restrict__ resid,
    const float* __restrict__ lng, const float* __restrict__ lnb,
    u16* __restrict__ ln_out)
{
    __shared__ u16 As[4][64][32];        // 16 KB  [kc][row][k32]
    __shared__ u16 Bs[4][128][32];       // 32 KB
    __shared__ float lnred[2][4][16][2]; // [wn][wm][rl][sum,sq]  1 KB

    int tid = threadIdx.x, w = tid >> 6, l = tid & 63;
    int c16 = l & 15, g4 = l >> 4;
    int m0 = blockIdx.y * 64, n0 = blockIdx.x * 128;
    int wm = w & 3, wn = w >> 2;
    const int NCH = KTOT / 128;

    f32x4 acc[4] = {};
    u16x8 va[2], vb[4];

    #pragma unroll
    for (int p = 0; p < 2; ++p) {
        int e = tid + p * 512, row = e >> 4, c8 = e & 15;
        va[p] = *(const u16x8*)&A[(size_t)(m0 + row) * KTOT + c8 * 8];
    }
    #pragma unroll
    for (int p = 0; p < 4; ++p) {
        int e = tid + p * 512, row = e >> 4, c8 = e & 15;
        vb[p] = *(const u16x8*)&W[(size_t)(n0 + row) * KTOT + c8 * 8];
    }
    for (int ch = 0; ch < NCH; ++ch) {
        #pragma unroll
        for (int p = 0; p < 2; ++p) {
            int e = tid + p * 512, row = e >> 4, c8 = e & 15;
            *(u16x8*)&As[c8 >> 2][row][(c8 & 3) * 8] = va[p];
        }
        #pragma unroll
        for (int p = 0; p < 4; ++p) {
            int e = tid + p * 512, row = e >> 4, c8 = e & 15;
            *(u16x8*)&Bs[c8 >> 2][row][(c8 & 3) * 8] = vb[p];
        }
        __syncthreads();
        if (ch + 1 < NCH) {
            #pragma unroll
            for (int p = 0; p < 2; ++p) {
                int e = tid + p * 512, row = e >> 4, c8 = e & 15;
                va[p] = *(const u16x8*)&A[(size_t)(m0 + row) * KTOT + (ch + 1) * 128 + c8 * 8];
            }
            #pragma unroll
            for (int p = 0; p < 4; ++p) {
                int e = tid + p * 512, row = e >> 4, c8 = e & 15;
                vb[p] = *(const u16x8*)&W[(size_t)(n0 + row) * KTOT + (ch + 1) * 128 + c8 * 8];
            }
        }
        #pragma unroll
        for (int kc = 0; kc < 4; ++kc) {
            s16x8 af = __builtin_bit_cast(s16x8,
                *(const u16x8*)&As[kc][wm * 16 + c16][g4 * 8]);
            #pragma unroll
            for (int ni = 0; ni < 4; ++ni) {
                s16x8 bf = __builtin_bit_cast(s16x8,
                    *(const u16x8*)&Bs[kc][wn * 64 + ni * 16 + c16][g4 * 8]);
                acc[ni] = mfma16(af, bf, acc[ni]);
            }
        }
        if (ch + 1 < NCH) __syncthreads();
    }

    if (EPI == 2) {
        float psum[4], psq[4];
        int dstl[4];
        #pragma unroll
        for (int r = 0; r < 4; ++r) {
            int m = m0 + wm * 16 + g4 * 4 + r;
            int dst = src_index(m);
            dstl[r] = dst;
            float s = 0.f, q = 0.f;
            #pragma unroll
            for (int ni = 0; ni < 4; ++ni) {
                int col = wn * 64 + ni * 16 + c16;
                float v = acc[ni][r] + bias[col] + resid[(size_t)dst * CH + col];
                acc[ni][r] = v;
                s += v; q += v * v;
            }
            psum[r] = s; psq[r] = q;
        }
        #pragma unroll
        for (int o = 1; o <= 8; o <<= 1)
            #pragma unroll
            for (int r = 0; r < 4; ++r) {
                psum[r] += __shfl_xor(psum[r], o);
                psq[r]  += __shfl_xor(psq[r], o);
            }
        if (c16 == 0) {
            #pragma unroll
            for (int r = 0; r < 4; ++r) {
                int rl = g4 * 4 + r;
                lnred[wn][wm][rl][0] = psum[r];
                lnred[wn][wm][rl][1] = psq[r];
            }
        }
        __syncthreads();
        float gl[4], bl[4];
        #pragma unroll
        for (int ni = 0; ni < 4; ++ni) {
            int col = wn * 64 + ni * 16 + c16;
            gl[ni] = lng[col]; bl[ni] = lnb[col];
        }
        #pragma unroll
        for (int r = 0; r < 4; ++r) {
            int rl = g4 * 4 + r;
            float s = lnred[0][wm][rl][0] + lnred[1][wm][rl][0];
            float q = lnred[0][wm][rl][1] + lnred[1][wm][rl][1];
            float mean = s * (1.f / CH);
            float var  = q * (1.f / CH) - mean * mean;
            float rstd = rsqrtf(var + LNEPS);
            int dst = dstl[r];
            #pragma unroll
            for (int ni = 0; ni < 4; ++ni) {
                int col = wn * 64 + ni * 16 + c16;
                float v = acc[ni][r];
                ((float*)outp)[(size_t)dst * CH + col] = v;
                ln_out[(size_t)dst * CH + col] = f2bf((v - mean) * rstd * gl[ni] + bl[ni]);
            }
        }
    } else {
        #pragma unroll
        for (int r = 0; r < 4; ++r) {
            int m = m0 + wm * 16 + g4 * 4 + r;
            #pragma unroll
            for (int ni = 0; ni < 4; ++ni) {
                int col = n0 + wn * 64 + ni * 16 + c16;
                float v = acc[ni][r];
                if (EPI == 1) {
                    v += bias[col] * (col < 128 ? QSCALE * LOG2E : 1.f);
                    ((u16*)outp)[(size_t)m * Nn + col] = f2bf(v);
                } else if (EPI == 3) {
                    v += bias[col];
                    v = 0.5f * v * (1.f + erff(v * 0.70710678118654752f));
                    ((u16*)outp)[(size_t)m * Nn + col] = f2bf(v);
                } else {
                    v += bias[col];
                    ((float*)outp)[(size_t)m * CH + col] = v + resid[(size_t)m * CH + col];
                }
            }
        }
    }
}

// ---- bias+mask table, f32 * LOG2E, TRANSPOSED MFMA C-fragment layout ----
// [hw][t][nt=26][lane][r]: value = bias(q = t*16 + (l&15), k = nt*16 + (l>>4)*4 + r)
__global__ __launch_bounds__(64) void bias_k(
    const float* __restrict__ rpb, float* __restrict__ biasT2)
{
    int nt = blockIdx.x;   // 0..25 (k tile; includes pad)
    int t  = blockIdx.y;   // 0..24 (q tile)
    int hw = blockIdx.z;   // head*4 + wt
    int l  = threadIdx.x;  // 0..63
    int head = hw >> 2, wt = hw & 3;
    int bh7 = wt >> 1, bw7 = wt & 1;
    int i = t * 16 + (l & 15);            // q row
    if (i > NTOK - 1) i = NTOK - 1;
    int kb = nt * 16 + (l >> 4) * 4;      // k col base
    f32x4 outv;
    #pragma unroll
    for (int r = 0; r < 4; ++r) {
        int j = kb + r;                   // k col
        float v;
        if (j >= NTOK) v = -100.f;
        else {
            int di = i / 49, ri = i - di * 49, hi = ri / 7, wi = ri - hi * 7;
            int dj = j / 49, rj = j - dj * 49, hj = rj / 7, wj = rj - hj * 7;
            int bidx = (di - dj + 7) * 169 + (hi - hj + 6) * 13 + (wi - wj + 6);
            v = rpb[bidx * NHEADS + head];
            int regi = (bh7 ? (hi < 4 ? 1 : 2) : 0) * 3 + (bw7 ? (wi < 4 ? 1 : 2) : 0);
            int regj = (bh7 ? (hj < 4 ? 1 : 2) : 0) * 3 + (bw7 ? (wj < 4 ? 1 : 2) : 0);
            if (regi != regj) v -= 100.f;
        }
        outv[r] = v * LOG2E;
    }
    *(f32x4*)&biasT2[((((size_t)hw * 25 + t) * 26 + nt) << 8) + (l << 2)] = outv;
}

// ---- flash-strip MFMA attention: swapped QK^T, P via packed-b32 LDS,
//      2-deep K/bias register prefetch. 8 waves/block, LDS 37 KB.
// lane (c16,g4) after mfma(K,Q): S[k = strip + g4*4+r][q = q0 + c16]
__global__ __launch_bounds__(512, 4) void attn_mfma(
    const u16* __restrict__ Qb, const float* __restrict__ biasT2,
    u16* __restrict__ O)
{
    __shared__ u16 Vt[32][420];      // 26880 B, cols 400..415 zero
    __shared__ u16 Pst[8][16][40];   // 10240 B, per-wave P strip [q16][k32 pad40]

    int bid = blockIdx.x;
    int win = bid >> 2, head = bid & 3;
    int tid = threadIdx.x, w = tid >> 6, l = tid & 63;
    int c16 = l & 15, g4 = l >> 4;

    const size_t qbase = (size_t)win * NTOK * 384;
    for (int e = tid; e < 1600; e += 512) {
        int j = e >> 2, d0 = (e & 3) * 8;
        u16x8 vv = {0, 0, 0, 0, 0, 0, 0, 0};
        if (j < NTOK)
            vv = *(const u16x8*)&Qb[qbase + (size_t)j * 384 + 256 + head * 32 + d0];
        #pragma unroll
        for (int i = 0; i < 8; ++i) Vt[d0 + i][j] = vv[i];
    }
    if (tid < 32 * 16) Vt[tid >> 4][400 + (tid & 15)] = 0;
    __syncthreads();

    int wIdx = win & 63;
    int wt = (((wIdx >> 3) == 7) ? 2 : 0) + (((wIdx & 7) == 7) ? 1 : 0);
    const float* bt = biasT2 + (((size_t)(head * 4 + wt) * 25 * 26) << 8) + (l << 2);
    const u16* kroot = Qb + qbase + 128 + head * 32 + g4 * 8;
    u16 (*myP)[40] = Pst[w];
    u32* prow = (u32*)&myP[c16][0];   // this lane writes k-pairs of q-row c16

#define LOADK(JB, KA, KB2, CA, CB2) do {                                        \
        int _kr0 = (JB) * 32 + c16;      if (_kr0 > NTOK - 1) _kr0 = NTOK - 1;  \
        int _kr1 = (JB) * 32 + 16 + c16; if (_kr1 > NTOK - 1) _kr1 = NTOK - 1;  \
        KA  = __builtin_bit_cast(s16x8, *(const u16x8*)&kroot[(size_t)_kr0 * 384]); \
        KB2 = __builtin_bit_cast(s16x8, *(const u16x8*)&kroot[(size_t)_kr1 * 384]); \
        CA  = *(const f32x4*)(btt + (((size_t)((JB) * 2 + 0)) << 8));           \
        CB2 = *(const f32x4*)(btt + (((size_t)((JB) * 2 + 1)) << 8));           \
    } while (0)

#define STRIP(JB, KA, KB2, CA, CB2) do {                                        \
        f32x4 _s0 = mfma16(KA,  qfrag, CA);                                     \
        f32x4 _s1 = mfma16(KB2, qfrag, CB2);                                    \
        float _p0 = exp2f(_s0[0]), _p1 = exp2f(_s0[1]);                         \
        float _p2 = exp2f(_s0[2]), _p3 = exp2f(_s0[3]);                         \
        float _p4 = exp2f(_s1[0]), _p5 = exp2f(_s1[1]);                         \
        float _p6 = exp2f(_s1[2]), _p7 = exp2f(_s1[3]);                         \
        lsum += ((_p0 + _p1) + (_p2 + _p3)) + ((_p4 + _p5) + (_p6 + _p7));      \
        prow[g4 * 2 + 0]     = pkbf(_p0, _p1);                                  \
        prow[g4 * 2 + 1]     = pkbf(_p2, _p3);                                  \
        prow[8 + g4 * 2 + 0] = pkbf(_p4, _p5);                                  \
        prow[8 + g4 * 2 + 1] = pkbf(_p6, _p7);                                  \
        s16x8 _pa = __builtin_bit_cast(s16x8, *(const u16x8*)&myP[c16][g4 * 8]);\
        { s16x8 _vb = __builtin_bit_cast(s16x8,                                 \
              *(const u16x8*)&Vt[c16][(JB) * 32 + g4 * 8]);                     \
          oacc0 = mfma16(_pa, _vb, oacc0); }                                    \
        { s16x8 _vb = __builtin_bit_cast(s16x8,                                 \
              *(const u16x8*)&Vt[16 + c16][(JB) * 32 + g4 * 8]);                \
          oacc1 = mfma16(_pa, _vb, oacc1); }                                    \
    } while (0)

    for (int t = w; t < 25; t += 8) {
        int q0 = t * 16;
        int qr = q0 + c16; if (qr > NTOK - 1) qr = NTOK - 1;
        s16x8 qfrag = __builtin_bit_cast(s16x8,
            *(const u16x8*)&Qb[qbase + (size_t)qr * 384 + head * 32 + g4 * 8]);
        const float* btt = bt + (((size_t)t * 26) << 8);

        float lsum = 0.f;
        f32x4 oacc0 = {0.f,0.f,0.f,0.f}, oacc1 = {0.f,0.f,0.f,0.f};

        s16x8 k0a, k0b, k1a, k1b;
        f32x4 c0a, c0b, c1a, c1b;
        LOADK(0, k0a, k0b, c0a, c0b);
        #pragma unroll
        for (int jh = 0; jh < 6; ++jh) {
            LOADK(jh * 2 + 1, k1a, k1b, c1a, c1b);   // prefetch next strip
            STRIP(jh * 2, k0a, k0b, c0a, c0b);
            LOADK(jh * 2 + 2, k0a, k0b, c0a, c0b);   // prefetch next-next
            STRIP(jh * 2 + 1, k1a, k1b, c1a, c1b);
        }
        STRIP(12, k0a, k0b, c0a, c0b);

        // denominator for q = q0 + c16: sum the 4 g4 groups
        lsum += __shfl_xor(lsum, 16);
        lsum += __shfl_xor(lsum, 32);
        float linv = 1.f / lsum;
        // O rows at this lane are q = q0 + g4*4 + r; fetch their denominators
        float rinv[4];
        #pragma unroll
        for (int r = 0; r < 4; ++r) rinv[r] = __shfl(linv, g4 * 4 + r);

        #pragma unroll
        for (int r = 0; r < 4; ++r) {
            int qrow = q0 + g4 * 4 + r;
            if (qrow < NTOK) {
                size_t ob = ((size_t)(win * NTOK + qrow)) * CH + head * 32 + c16;
                O[ob]      = f2bf(oacc0[r] * rinv[r]);
                O[ob + 16] = f2bf(oacc1[r] * rinv[r]);
            }
        }
    }
#undef LOADK
#undef STRIP
}

extern "C" void kernel_launch(void* const* d_in, const int* in_sizes, int n_in,
                              void* d_out, int out_size, void* d_ws, size_t ws_size,
                              hipStream_t stream) {
    const float* x      = (const float*)d_in[0];
    const float* n1g    = (const float*)d_in[1];
    const float* n1b    = (const float*)d_in[2];
    const float* qkv_w  = (const float*)d_in[3];
    const float* qkv_b  = (const float*)d_in[4];
    const float* proj_w = (const float*)d_in[5];
    const float* proj_b = (const float*)d_in[6];
    const float* rpb    = (const float*)d_in[7];
    const float* n2g    = (const float*)d_in[8];
    const float* n2b    = (const float*)d_in[9];
    const float* fc1_w  = (const float*)d_in[10];
    const float* fc1_b  = (const float*)d_in[11];
    const float* fc2_w  = (const float*)d_in[12];
    const float* fc2_b  = (const float*)d_in[13];
    float* out = (float*)d_out;

    char* ws = (char*)d_ws;
    size_t off = 0;
    u16* A_bf  = (u16*)(ws + off);  off += (size_t)TOK * 128 * 2;
    u16* Qb_bf = (u16*)(ws + off);  off += (size_t)TOK * 384 * 2;
    u16* O_bf  = (u16*)(ws + off);  off += (size_t)TOK * 128 * 2;
    float* R   = (float*)(ws + off); off += (size_t)TOK * 128 * 4;
    u16* qkvT  = (u16*)(ws + off);  off += 384 * 128 * 2;
    u16* projT = (u16*)(ws + off);  off += 128 * 128 * 2;
    u16* fc1T  = (u16*)(ws + off);  off += 512 * 128 * 2;
    u16* fc2T  = (u16*)(ws + off);  off += 128 * 512 * 2;
    u16* H_bf  = Qb_bf;             // overlays Qb+O exactly; both dead by fc1
    float* biasT2 = (float*)A_bf;   // overlay; A_bf dead after qkv GEMM,
                                    // rewritten by proj's fused LN2

    // 0. weight transposes (+bf16); Q weights pre-scaled by QSCALE*LOG2E
    hipLaunchKernelGGL(convT, dim3(384/32, 128/32), dim3(256), 0, stream,
                       qkv_w,  qkvT, 128, 384, 128, QSCALE * LOG2E);
    hipLaunchKernelGGL(convT, dim3(128/32, 128/32), dim3(256), 0, stream,
                       proj_w, projT, 128, 128, 0, 1.f);
    hipLaunchKernelGGL(convT, dim3(512/32, 128/32), dim3(256), 0, stream,
                       fc1_w,  fc1T, 128, 512, 0, 1.f);
    hipLaunchKernelGGL(convT, dim3(128/32, 512/32), dim3(256), 0, stream,
                       fc2_w,  fc2T, 512, 128, 0, 1.f);
    // 1. LN1 + shift + window_partition -> bf16
    hipLaunchKernelGGL(ln_kernel, dim3(TOK), dim3(128), 0, stream, x, n1g, n1b, A_bf);
    // 2. qkv GEMM -> bf16
    hipLaunchKernelGGL((gemm_mfma<1, 128>), dim3(3, TOK/64), dim3(512), 0, stream,
                       A_bf, qkvT, qkv_b, Qb_bf, 384, nullptr, nullptr, nullptr, nullptr);
    // 2b. bias+mask table, transposed fragment layout, *LOG2E (A_bf dead; overlay)
    hipLaunchKernelGGL(bias_k, dim3(26, 25, 16), dim3(64), 0, stream, rpb, biasT2);
    // 3. swapped-QK^T flash attention (prefetched, P via packed LDS) -> bf16
    hipLaunchKernelGGL(attn_mfma, dim3(NWIN * NHEADS), dim3(512), 0, stream,
                       Qb_bf, biasT2, O_bf);
    // 4. proj GEMM + unshift + residual -> f32 R, fused LN2 -> bf16 A_bf
    hipLaunchKernelGGL((gemm_mfma<2, 128>), dim3(1, TOK/64), dim3(512), 0, stream,
                       O_bf, projT, proj_b, R, 128, x, n2g, n2b, A_bf);
    // 5. fc1 + GELU -> bf16
    hipLaunchKernelGGL((gemm_mfma<3, 128>), dim3(4, TOK/64), dim3(512), 0, stream,
                       A_bf, fc1T, fc1_b, H_bf, 512, nullptr, nullptr, nullptr, nullptr);
    // 6. fc2 + residual -> f32 out
    hipLaunchKernelGGL((gemm_mfma<4, 512>), dim3(1, TOK/64), dim3(512), 0, stream,
                       H_bf, fc2T, fc2_b, out, 128, R, nullptr, nullptr, nullptr);
}

// Round 12
// 175.317 us; speedup vs baseline: 1.3070x; 1.3070x over previous
//
#include <hip/hip_runtime.h>
#include <math.h>

// ---- problem constants ----
#define TOK    50176      // 2*8*56*56 tokens
#define CH     128
#define NWIN   128        // B * 64 windows
#define NTOK   392        // 8*7*7 tokens per window
#define NHEADS 4
#define QSCALE 0.17677669529663687f   // 32^-0.5
#define LNEPS  1e-3f

typedef unsigned short u16;
typedef unsigned int   u32;
typedef u16   u16x4  __attribute__((ext_vector_type(4)));
typedef u16   u16x8  __attribute__((ext_vector_type(8)));
typedef short s16x8  __attribute__((ext_vector_type(8)));
typedef float f32x4  __attribute__((ext_vector_type(4)));

__device__ __forceinline__ float bf2f(u16 u) {
    return __uint_as_float(((u32)u) << 16);
}
__device__ __forceinline__ u16 f2bf(float f) {
    u32 u = __float_as_uint(f);
    return (u16)((u + 0x7fffu + ((u >> 16) & 1u)) >> 16);
}
__device__ __forceinline__ f32x4 mfma16(s16x8 a, s16x8 b, f32x4 c) {
    return __builtin_amdgcn_mfma_f32_16x16x32_bf16(a, b, c, 0, 0, 0);
}

// token m in window layout -> flat token index in original layout (+3 roll)
__device__ __forceinline__ int src_index(int m) {
    int b = m / NTOK, t = m - b * NTOK;
    int batch = b >> 6, wIdx = b & 63;
    int bh = wIdx >> 3, bw = wIdx & 7;
    int d = t / 49, rem = t - d * 49;
    int h7 = rem / 7, w7 = rem - h7 * 7;
    int h = bh * 7 + h7 + 3; if (h >= 56) h -= 56;
    int w = bw * 7 + w7 + 3; if (w >= 56) w -= 56;
    return ((batch * 8 + d) * 56 + h) * 56 + w;
}

// ---- weight transpose + f32->bf16 convert: dst[n][k] = src[k][n] * sc ----
__global__ __launch_bounds__(256) void convT(
    const float* __restrict__ src, u16* __restrict__ dst,
    int K, int N, int scaleN)
{
    __shared__ float t[32][33];
    int n0 = blockIdx.x * 32, k0 = blockIdx.y * 32;
    int tx = threadIdx.x & 31, ty = threadIdx.x >> 5;   // ty 0..7
    #pragma unroll
    for (int r = 0; r < 4; ++r)
        t[ty + r * 8][tx] = src[(size_t)(k0 + ty + r * 8) * N + n0 + tx];
    __syncthreads();
    #pragma unroll
    for (int r = 0; r < 4; ++r) {
        int n = n0 + ty + r * 8;
        float sc = (n < scaleN) ? QSCALE : 1.f;
        dst[(size_t)n * K + k0 + tx] = f2bf(t[tx][ty + r * 8] * sc);
    }
}

// ---- LN1: gather f32 x via src_index, LN, -> bf16 window layout ----
__global__ __launch_bounds__(128) void ln_kernel(
    const float* __restrict__ xin,
    const float* __restrict__ g, const float* __restrict__ bta,
    u16* __restrict__ out)
{
    int m = blockIdx.x, c = threadIdx.x;
    float v = xin[(size_t)src_index(m) * CH + c];
    float s1 = v, s2 = v * v;
    #pragma unroll
    for (int o = 32; o; o >>= 1) { s1 += __shfl_xor(s1, o); s2 += __shfl_xor(s2, o); }
    __shared__ float ps[2][2];
    int w = c >> 6;
    if ((c & 63) == 0) { ps[w][0] = s1; ps[w][1] = s2; }
    __syncthreads();
    s1 = ps[0][0] + ps[1][0];
    s2 = ps[0][1] + ps[1][1];
    float mean = s1 * (1.f / CH);
    float var  = s2 * (1.f / CH) - mean * mean;
    float r = rsqrtf(var + LNEPS);
    out[(size_t)m * CH + c] = f2bf((v - mean) * r * g[c] + bta[c]);
}

// ---- MFMA GEMM, BM=64 x BN=128, 512 threads (8 waves = 4m x 2n), BK=128 ----
// C[M][N] = A[M][K]_bf16 * W[N][K]_bf16 + bias
// EPI 1: qkv -> bf16 (bias QSCALE'd for n<128)
// EPI 2: proj + residual scatter -> bf16 R, FUSED LN2 -> bf16 ln_out
// EPI 3: gelu -> bf16
// EPI 4: fc2 + bf16 resid -> f32 out
template<int EPI, int KTOT>
__global__ __launch_bounds__(512, 6) void gemm_mfma(
    const u16* __restrict__ A, const u16* __restrict__ W,
    const float* __restrict__ bias, void* __restrict__ outp,
    int Nn, const float* __restrict__ resid, const u16* __restrict__ residb,
    const float* __restrict__ lng, const float* __restrict__ lnb,
    u16* __restrict__ ln_out)
{
    __shared__ u16 As[4][64][32];        // 16 KB  [kc][row][k32]
    __shared__ u16 Bs[4][128][32];       // 32 KB
    __shared__ float lnred[2][4][16][2]; // [wn][wm][rl][sum,sq]  1 KB

    int tid = threadIdx.x, w = tid >> 6, l = tid & 63;
    int c16 = l & 15, g4 = l >> 4;
    int m0 = blockIdx.y * 64, n0 = blockIdx.x * 128;
    int wm = w & 3, wn = w >> 2;
    const int NCH = KTOT / 128;

    f32x4 acc[4] = {};
    u16x8 va[2], vb[4];

    #pragma unroll
    for (int p = 0; p < 2; ++p) {
        int e = tid + p * 512, row = e >> 4, c8 = e & 15;
        va[p] = *(const u16x8*)&A[(size_t)(m0 + row) * KTOT + c8 * 8];
    }
    #pragma unroll
    for (int p = 0; p < 4; ++p) {
        int e = tid + p * 512, row = e >> 4, c8 = e & 15;
        vb[p] = *(const u16x8*)&W[(size_t)(n0 + row) * KTOT + c8 * 8];
    }
    for (int ch = 0; ch < NCH; ++ch) {
        #pragma unroll
        for (int p = 0; p < 2; ++p) {
            int e = tid + p * 512, row = e >> 4, c8 = e & 15;
            *(u16x8*)&As[c8 >> 2][row][(c8 & 3) * 8] = va[p];
        }
        #pragma unroll
        for (int p = 0; p < 4; ++p) {
            int e = tid + p * 512, row = e >> 4, c8 = e & 15;
            *(u16x8*)&Bs[c8 >> 2][row][(c8 & 3) * 8] = vb[p];
        }
        __syncthreads();
        if (ch + 1 < NCH) {
            #pragma unroll
            for (int p = 0; p < 2; ++p) {
                int e = tid + p * 512, row = e >> 4, c8 = e & 15;
                va[p] = *(const u16x8*)&A[(size_t)(m0 + row) * KTOT + (ch + 1) * 128 + c8 * 8];
            }
            #pragma unroll
            for (int p = 0; p < 4; ++p) {
                int e = tid + p * 512, row = e >> 4, c8 = e & 15;
                vb[p] = *(const u16x8*)&W[(size_t)(n0 + row) * KTOT + (ch + 1) * 128 + c8 * 8];
            }
        }
        #pragma unroll
        for (int kc = 0; kc < 4; ++kc) {
            s16x8 af = __builtin_bit_cast(s16x8,
                *(const u16x8*)&As[kc][wm * 16 + c16][g4 * 8]);
            #pragma unroll
            for (int ni = 0; ni < 4; ++ni) {
                s16x8 bf = __builtin_bit_cast(s16x8,
                    *(const u16x8*)&Bs[kc][wn * 64 + ni * 16 + c16][g4 * 8]);
                acc[ni] = mfma16(af, bf, acc[ni]);
            }
        }
        if (ch + 1 < NCH) __syncthreads();
    }

    if (EPI == 2) {
        float psum[4], psq[4];
        int dstl[4];
        #pragma unroll
        for (int r = 0; r < 4; ++r) {
            int m = m0 + wm * 16 + g4 * 4 + r;
            int dst = src_index(m);
            dstl[r] = dst;
            float s = 0.f, q = 0.f;
            #pragma unroll
            for (int ni = 0; ni < 4; ++ni) {
                int col = wn * 64 + ni * 16 + c16;
                float v = acc[ni][r] + bias[col] + resid[(size_t)dst * CH + col];
                acc[ni][r] = v;
                s += v; q += v * v;
            }
            psum[r] = s; psq[r] = q;
        }
        #pragma unroll
        for (int o = 1; o <= 8; o <<= 1)
            #pragma unroll
            for (int r = 0; r < 4; ++r) {
                psum[r] += __shfl_xor(psum[r], o);
                psq[r]  += __shfl_xor(psq[r], o);
            }
        if (c16 == 0) {
            #pragma unroll
            for (int r = 0; r < 4; ++r) {
                int rl = g4 * 4 + r;
                lnred[wn][wm][rl][0] = psum[r];
                lnred[wn][wm][rl][1] = psq[r];
            }
        }
        __syncthreads();
        float gl[4], bl[4];
        #pragma unroll
        for (int ni = 0; ni < 4; ++ni) {
            int col = wn * 64 + ni * 16 + c16;
            gl[ni] = lng[col]; bl[ni] = lnb[col];
        }
        #pragma unroll
        for (int r = 0; r < 4; ++r) {
            int rl = g4 * 4 + r;
            float s = lnred[0][wm][rl][0] + lnred[1][wm][rl][0];
            float q = lnred[0][wm][rl][1] + lnred[1][wm][rl][1];
            float mean = s * (1.f / CH);
            float var  = q * (1.f / CH) - mean * mean;
            float rstd = rsqrtf(var + LNEPS);
            int dst = dstl[r];
            #pragma unroll
            for (int ni = 0; ni < 4; ++ni) {
                int col = wn * 64 + ni * 16 + c16;
                float v = acc[ni][r];
                ((u16*)outp)[(size_t)dst * CH + col] = f2bf(v);
                ln_out[(size_t)dst * CH + col] = f2bf((v - mean) * rstd * gl[ni] + bl[ni]);
            }
        }
    } else {
        #pragma unroll
        for (int r = 0; r < 4; ++r) {
            int m = m0 + wm * 16 + g4 * 4 + r;
            #pragma unroll
            for (int ni = 0; ni < 4; ++ni) {
                int col = n0 + wn * 64 + ni * 16 + c16;
                float v = acc[ni][r];
                if (EPI == 1) {
                    v += bias[col] * (col < 128 ? QSCALE : 1.f);
                    ((u16*)outp)[(size_t)m * Nn + col] = f2bf(v);
                } else if (EPI == 3) {
                    v += bias[col];
                    v = 0.5f * v * (1.f + erff(v * 0.70710678118654752f));
                    ((u16*)outp)[(size_t)m * Nn + col] = f2bf(v);
                } else { // EPI 4
                    v += bias[col];
                    ((float*)outp)[(size_t)m * CH + col]
                        = v + bf2f(residb[(size_t)m * CH + col]);
                }
            }
        }
    }
}

// ---- bias+mask table, f32, MFMA C-fragment layout: [hw][t][nt=26][lane][r] ----
__global__ __launch_bounds__(64) void bias_k(
    const float* __restrict__ rpb, float* __restrict__ biasT2)
{
    int nt = blockIdx.x;   // 0..25 (col tile; 25 is all -100 pad)
    int t  = blockIdx.y;   // 0..24 (row tile)
    int hw = blockIdx.z;   // head*4 + wt
    int l  = threadIdx.x;  // 0..63
    int head = hw >> 2, wt = hw & 3;
    int bh7 = wt >> 1, bw7 = wt & 1;
    int j = nt * 16 + (l & 15);
    int rb = t * 16 + (l >> 4) * 4;
    f32x4 outv;
    #pragma unroll
    for (int r = 0; r < 4; ++r) {
        int i = rb + r; if (i > NTOK - 1) i = NTOK - 1;
        float v;
        if (j >= NTOK) v = -100.f;
        else {
            int di = i / 49, ri = i - di * 49, hi = ri / 7, wi = ri - hi * 7;
            int dj = j / 49, rj = j - dj * 49, hj = rj / 7, wj = rj - hj * 7;
            int bidx = (di - dj + 7) * 169 + (hi - hj + 6) * 13 + (wi - wj + 6);
            v = rpb[bidx * NHEADS + head];
            int regi = (bh7 ? (hi < 4 ? 1 : 2) : 0) * 3 + (bw7 ? (wi < 4 ? 1 : 2) : 0);
            int regj = (bh7 ? (hj < 4 ? 1 : 2) : 0) * 3 + (bw7 ? (wj < 4 ? 1 : 2) : 0);
            if (regi != regj) v -= 100.f;
        }
        outv[r] = v;
    }
    *(f32x4*)&biasT2[((((size_t)hw * 25 + t) * 26 + nt) << 8) + (l << 2)] = outv;
}

// ---- flash-strip MFMA attention, 8 waves/block, K-frags from global/L2 ----
// no-max softmax, bias in MFMA C-operand; LDS = V^T + P strips only (37 KB)
__global__ __launch_bounds__(512, 4) void attn_mfma(
    const u16* __restrict__ Qb, const float* __restrict__ biasT2,
    u16* __restrict__ O)
{
    __shared__ u16 Vt[32][420];      // 26880 B, cols 400..415 zero
    __shared__ u16 Pst[8][16][40];   // 10240 B, per-wave P strip

    int bid = blockIdx.x;
    int win = bid >> 2, head = bid & 3;
    int tid = threadIdx.x, w = tid >> 6, l = tid & 63;
    int c16 = l & 15, g4 = l >> 4;

    const size_t qbase = (size_t)win * NTOK * 384;
    // stage V transposed (K stays in global/L2)
    for (int e = tid; e < 1600; e += 512) {
        int j = e >> 2, d0 = (e & 3) * 8;
        u16x8 vv = {0, 0, 0, 0, 0, 0, 0, 0};
        if (j < NTOK)
            vv = *(const u16x8*)&Qb[qbase + (size_t)j * 384 + 256 + head * 32 + d0];
        #pragma unroll
        for (int i = 0; i < 8; ++i) Vt[d0 + i][j] = vv[i];
    }
    {
        int e = tid;
        if (e < 32 * 16) Vt[e >> 4][400 + (e & 15)] = 0;
    }
    __syncthreads();

    int wIdx = win & 63;
    int wt = (((wIdx >> 3) == 7) ? 2 : 0) + (((wIdx & 7) == 7) ? 1 : 0);
    const float* bt = biasT2 + (((size_t)(head * 4 + wt) * 25 * 26) << 8) + (l << 2);
    u16 (*myP)[40] = Pst[w];
    const u16* kroot = Qb + qbase + 128 + head * 32 + g4 * 8;

    for (int t = w; t < 25; t += 8) {
        int row0 = t * 16;
        int qr = row0 + c16; if (qr > NTOK - 1) qr = NTOK - 1;
        s16x8 afrag = __builtin_bit_cast(s16x8,
            *(const u16x8*)&Qb[qbase + (size_t)qr * 384 + head * 32 + g4 * 8]);
        const float* btt = bt + (((size_t)t * 26) << 8);

        float l4[4] = {0.f, 0.f, 0.f, 0.f};
        f32x4 oacc[2] = {{0.f,0.f,0.f,0.f},{0.f,0.f,0.f,0.f}};

        for (int jb = 0; jb < 13; ++jb) {
            f32x4 s[2];
            #pragma unroll
            for (int kk = 0; kk < 2; ++kk) {
                f32x4 cb = *(const f32x4*)(btt + (((size_t)(jb * 2 + kk)) << 8));
                int kr = jb * 32 + kk * 16 + c16;
                if (kr > NTOK - 1) kr = NTOK - 1;   // pad rows: bias=-100 -> exp2 -> 0
                s16x8 bfrag = __builtin_bit_cast(s16x8,
                    *(const u16x8*)&kroot[(size_t)kr * 384]);
                s[kk] = mfma16(afrag, bfrag, cb);
            }
            #pragma unroll
            for (int kk = 0; kk < 2; ++kk)
                #pragma unroll
                for (int r = 0; r < 4; ++r) {
                    float p = exp2f(s[kk][r] * 1.44269504f);
                    l4[r] += p;
                    myP[g4 * 4 + r][kk * 16 + c16] = f2bf(p);
                }
            s16x8 pa = __builtin_bit_cast(s16x8, *(const u16x8*)&myP[c16][g4 * 8]);
            #pragma unroll
            for (int nd = 0; nd < 2; ++nd) {
                s16x8 vb = __builtin_bit_cast(s16x8,
                    *(const u16x8*)&Vt[nd * 16 + c16][jb * 32 + g4 * 8]);
                oacc[nd] = mfma16(pa, vb, oacc[nd]);
            }
        }

        #pragma unroll
        for (int r = 0; r < 4; ++r) {
            #pragma unroll
            for (int o = 1; o <= 8; o <<= 1)
                l4[r] += __shfl_xor(l4[r], o);
            l4[r] = 1.f / l4[r];
        }

        #pragma unroll
        for (int nd = 0; nd < 2; ++nd)
            #pragma unroll
            for (int r = 0; r < 4; ++r) {
                int qrow = row0 + g4 * 4 + r;
                if (qrow < NTOK)
                    O[((size_t)(win * NTOK + qrow)) * CH + head * 32 + nd * 16 + c16]
                        = f2bf(oacc[nd][r] * l4[r]);
            }
    }
}

extern "C" void kernel_launch(void* const* d_in, const int* in_sizes, int n_in,
                              void* d_out, int out_size, void* d_ws, size_t ws_size,
                              hipStream_t stream) {
    const float* x      = (const float*)d_in[0];
    const float* n1g    = (const float*)d_in[1];
    const float* n1b    = (const float*)d_in[2];
    const float* qkv_w  = (const float*)d_in[3];
    const float* qkv_b  = (const float*)d_in[4];
    const float* proj_w = (const float*)d_in[5];
    const float* proj_b = (const float*)d_in[6];
    const float* rpb    = (const float*)d_in[7];
    const float* n2g    = (const float*)d_in[8];
    const float* n2b    = (const float*)d_in[9];
    const float* fc1_w  = (const float*)d_in[10];
    const float* fc1_b  = (const float*)d_in[11];
    const float* fc2_w  = (const float*)d_in[12];
    const float* fc2_b  = (const float*)d_in[13];
    float* out = (float*)d_out;

    char* ws = (char*)d_ws;
    size_t off = 0;
    u16* A_bf  = (u16*)(ws + off);  off += (size_t)TOK * 128 * 2;
    u16* Qb_bf = (u16*)(ws + off);  off += (size_t)TOK * 384 * 2;
    u16* O_bf  = (u16*)(ws + off);  off += (size_t)TOK * 128 * 2;
    u16* R_bf  = (u16*)(ws + off);  off += (size_t)TOK * 128 * 2;   // bf16 residual trunk
    u16* qkvT  = (u16*)(ws + off);  off += 384 * 128 * 2;
    u16* projT = (u16*)(ws + off);  off += 128 * 128 * 2;
    u16* fc1T  = (u16*)(ws + off);  off += 512 * 128 * 2;
    u16* fc2T  = (u16*)(ws + off);  off += 128 * 512 * 2;
    u16* H_bf  = Qb_bf;             // overlays Qb+O exactly; both dead by fc1
    float* biasT2 = (float*)A_bf;   // 10.65 MB overlay in A_bf (12.85 MB);
                                    // A_bf dead after qkv GEMM, rewritten by proj's LN2

    // 0. weight transposes (+bf16), QSCALE folded into Wq
    hipLaunchKernelGGL(convT, dim3(384/32, 128/32), dim3(256), 0, stream, qkv_w,  qkvT, 128, 384, 128);
    hipLaunchKernelGGL(convT, dim3(128/32, 128/32), dim3(256), 0, stream, proj_w, projT, 128, 128, 0);
    hipLaunchKernelGGL(convT, dim3(512/32, 128/32), dim3(256), 0, stream, fc1_w,  fc1T, 128, 512, 0);
    hipLaunchKernelGGL(convT, dim3(128/32, 512/32), dim3(256), 0, stream, fc2_w,  fc2T, 512, 128, 0);
    // 1. LN1 + shift + window_partition -> bf16
    hipLaunchKernelGGL(ln_kernel, dim3(TOK), dim3(128), 0, stream, x, n1g, n1b, A_bf);
    // 2. qkv GEMM -> bf16
    hipLaunchKernelGGL((gemm_mfma<1, 128>), dim3(3, TOK/64), dim3(512), 0, stream,
                       A_bf, qkvT, qkv_b, Qb_bf, 384, nullptr, nullptr, nullptr, nullptr, nullptr);
    // 2b. bias+mask table (A_bf dead; overlay)
    hipLaunchKernelGGL(bias_k, dim3(26, 25, 16), dim3(64), 0, stream, rpb, biasT2);
    // 3. flash MFMA windowed attention (8 waves/block) -> bf16
    hipLaunchKernelGGL(attn_mfma, dim3(NWIN * NHEADS), dim3(512), 0, stream,
                       Qb_bf, biasT2, O_bf);
    // 4. proj GEMM + unshift + residual -> bf16 R, fused LN2 -> bf16 A_bf
    hipLaunchKernelGGL((gemm_mfma<2, 128>), dim3(1, TOK/64), dim3(512), 0, stream,
                       O_bf, projT, proj_b, R_bf, 128, x, nullptr, n2g, n2b, A_bf);
    // 5. fc1 + GELU -> bf16
    hipLaunchKernelGGL((gemm_mfma<3, 128>), dim3(4, TOK/64), dim3(512), 0, stream,
                       A_bf, fc1T, fc1_b, H_bf, 512, nullptr, nullptr, nullptr, nullptr, nullptr);
    // 6. fc2 + bf16 residual -> f32 out
    hipLaunchKernelGGL((gemm_mfma<4, 512>), dim3(1, TOK/64), dim3(512), 0, stream,
                       H_bf, fc2T, fc2_b, out, 128, nullptr, R_bf, nullptr, nullptr, nullptr);
}

// Round 13
// 167.387 us; speedup vs baseline: 1.3690x; 1.0474x over previous
//
#include <hip/hip_runtime.h>
#include <math.h>

// ---- problem constants ----
#define TOK    50176      // 2*8*56*56 tokens
#define CH     128
#define NWIN   128        // B * 64 windows
#define NTOK   392        // 8*7*7 tokens per window
#define NHEADS 4
#define QSCALE 0.17677669529663687f   // 32^-0.5
#define LNEPS  1e-3f

typedef unsigned short u16;
typedef unsigned int   u32;
typedef u16   u16x4  __attribute__((ext_vector_type(4)));
typedef u16   u16x8  __attribute__((ext_vector_type(8)));
typedef short s16x8  __attribute__((ext_vector_type(8)));
typedef float f32x4  __attribute__((ext_vector_type(4)));

__device__ __forceinline__ float bf2f(u16 u) {
    return __uint_as_float(((u32)u) << 16);
}
__device__ __forceinline__ u16 f2bf(float f) {
    u32 u = __float_as_uint(f);
    return (u16)((u + 0x7fffu + ((u >> 16) & 1u)) >> 16);
}
__device__ __forceinline__ f32x4 mfma16(s16x8 a, s16x8 b, f32x4 c) {
    return __builtin_amdgcn_mfma_f32_16x16x32_bf16(a, b, c, 0, 0, 0);
}

// token m in window layout -> flat token index in original layout (+3 roll)
__device__ __forceinline__ int src_index(int m) {
    int b = m / NTOK, t = m - b * NTOK;
    int batch = b >> 6, wIdx = b & 63;
    int bh = wIdx >> 3, bw = wIdx & 7;
    int d = t / 49, rem = t - d * 49;
    int h7 = rem / 7, w7 = rem - h7 * 7;
    int h = bh * 7 + h7 + 3; if (h >= 56) h -= 56;
    int w = bw * 7 + w7 + 3; if (w >= 56) w -= 56;
    return ((batch * 8 + d) * 56 + h) * 56 + w;
}

// ---- weight transpose + f32->bf16 convert: dst[n][k] = src[k][n] * sc ----
__global__ __launch_bounds__(256) void convT(
    const float* __restrict__ src, u16* __restrict__ dst,
    int K, int N, int scaleN)
{
    __shared__ float t[32][33];
    int n0 = blockIdx.x * 32, k0 = blockIdx.y * 32;
    int tx = threadIdx.x & 31, ty = threadIdx.x >> 5;   // ty 0..7
    #pragma unroll
    for (int r = 0; r < 4; ++r)
        t[ty + r * 8][tx] = src[(size_t)(k0 + ty + r * 8) * N + n0 + tx];
    __syncthreads();
    #pragma unroll
    for (int r = 0; r < 4; ++r) {
        int n = n0 + ty + r * 8;
        float sc = (n < scaleN) ? QSCALE : 1.f;
        dst[(size_t)n * K + k0 + tx] = f2bf(t[tx][ty + r * 8] * sc);
    }
}

// ---- LN1: gather f32 x via src_index, LN, -> bf16 window layout ----
__global__ __launch_bounds__(128) void ln_kernel(
    const float* __restrict__ xin,
    const float* __restrict__ g, const float* __restrict__ bta,
    u16* __restrict__ out)
{
    int m = blockIdx.x, c = threadIdx.x;
    float v = xin[(size_t)src_index(m) * CH + c];
    float s1 = v, s2 = v * v;
    #pragma unroll
    for (int o = 32; o; o >>= 1) { s1 += __shfl_xor(s1, o); s2 += __shfl_xor(s2, o); }
    __shared__ float ps[2][2];
    int w = c >> 6;
    if ((c & 63) == 0) { ps[w][0] = s1; ps[w][1] = s2; }
    __syncthreads();
    s1 = ps[0][0] + ps[1][0];
    s2 = ps[0][1] + ps[1][1];
    float mean = s1 * (1.f / CH);
    float var  = s2 * (1.f / CH) - mean * mean;
    float r = rsqrtf(var + LNEPS);
    out[(size_t)m * CH + c] = f2bf((v - mean) * r * g[c] + bta[c]);
}

// ---- MFMA GEMM, BM=64 x BN=128, 512 threads (8 waves = 4m x 2n), BK=128 ----
// EPI 1: qkv -> bf16; EPI 2: proj + resid -> bf16 R + fused LN2 -> bf16;
// EPI 3: gelu -> bf16; EPI 4: fc2 + bf16 resid -> f32 out
template<int EPI, int KTOT>
__global__ __launch_bounds__(512, 6) void gemm_mfma(
    const u16* __restrict__ A, const u16* __restrict__ W,
    const float* __restrict__ bias, void* __restrict__ outp,
    int Nn, const float* __restrict__ resid, const u16* __restrict__ residb,
    const float* __restrict__ lng, const float* __restrict__ lnb,
    u16* __restrict__ ln_out)
{
    __shared__ u16 As[4][64][32];        // 16 KB  [kc][row][k32]
    __shared__ u16 Bs[4][128][32];       // 32 KB
    __shared__ float lnred[2][4][16][2]; // 1 KB

    int tid = threadIdx.x, w = tid >> 6, l = tid & 63;
    int c16 = l & 15, g4 = l >> 4;
    int m0 = blockIdx.y * 64, n0 = blockIdx.x * 128;
    int wm = w & 3, wn = w >> 2;
    const int NCH = KTOT / 128;

    f32x4 acc[4] = {};
    u16x8 va[2], vb[4];

    #pragma unroll
    for (int p = 0; p < 2; ++p) {
        int e = tid + p * 512, row = e >> 4, c8 = e & 15;
        va[p] = *(const u16x8*)&A[(size_t)(m0 + row) * KTOT + c8 * 8];
    }
    #pragma unroll
    for (int p = 0; p < 4; ++p) {
        int e = tid + p * 512, row = e >> 4, c8 = e & 15;
        vb[p] = *(const u16x8*)&W[(size_t)(n0 + row) * KTOT + c8 * 8];
    }
    for (int ch = 0; ch < NCH; ++ch) {
        #pragma unroll
        for (int p = 0; p < 2; ++p) {
            int e = tid + p * 512, row = e >> 4, c8 = e & 15;
            *(u16x8*)&As[c8 >> 2][row][(c8 & 3) * 8] = va[p];
        }
        #pragma unroll
        for (int p = 0; p < 4; ++p) {
            int e = tid + p * 512, row = e >> 4, c8 = e & 15;
            *(u16x8*)&Bs[c8 >> 2][row][(c8 & 3) * 8] = vb[p];
        }
        __syncthreads();
        if (ch + 1 < NCH) {
            #pragma unroll
            for (int p = 0; p < 2; ++p) {
                int e = tid + p * 512, row = e >> 4, c8 = e & 15;
                va[p] = *(const u16x8*)&A[(size_t)(m0 + row) * KTOT + (ch + 1) * 128 + c8 * 8];
            }
            #pragma unroll
            for (int p = 0; p < 4; ++p) {
                int e = tid + p * 512, row = e >> 4, c8 = e & 15;
                vb[p] = *(const u16x8*)&W[(size_t)(n0 + row) * KTOT + (ch + 1) * 128 + c8 * 8];
            }
        }
        #pragma unroll
        for (int kc = 0; kc < 4; ++kc) {
            s16x8 af = __builtin_bit_cast(s16x8,
                *(const u16x8*)&As[kc][wm * 16 + c16][g4 * 8]);
            #pragma unroll
            for (int ni = 0; ni < 4; ++ni) {
                s16x8 bf = __builtin_bit_cast(s16x8,
                    *(const u16x8*)&Bs[kc][wn * 64 + ni * 16 + c16][g4 * 8]);
                acc[ni] = mfma16(af, bf, acc[ni]);
            }
        }
        if (ch + 1 < NCH) __syncthreads();
    }

    if (EPI == 2) {
        float psum[4], psq[4];
        int dstl[4];
        #pragma unroll
        for (int r = 0; r < 4; ++r) {
            int m = m0 + wm * 16 + g4 * 4 + r;
            int dst = src_index(m);
            dstl[r] = dst;
            float s = 0.f, q = 0.f;
            #pragma unroll
            for (int ni = 0; ni < 4; ++ni) {
                int col = wn * 64 + ni * 16 + c16;
                float v = acc[ni][r] + bias[col] + resid[(size_t)dst * CH + col];
                acc[ni][r] = v;
                s += v; q += v * v;
            }
            psum[r] = s; psq[r] = q;
        }
        #pragma unroll
        for (int o = 1; o <= 8; o <<= 1)
            #pragma unroll
            for (int r = 0; r < 4; ++r) {
                psum[r] += __shfl_xor(psum[r], o);
                psq[r]  += __shfl_xor(psq[r], o);
            }
        if (c16 == 0) {
            #pragma unroll
            for (int r = 0; r < 4; ++r) {
                int rl = g4 * 4 + r;
                lnred[wn][wm][rl][0] = psum[r];
                lnred[wn][wm][rl][1] = psq[r];
            }
        }
        __syncthreads();
        float gl[4], bl[4];
        #pragma unroll
        for (int ni = 0; ni < 4; ++ni) {
            int col = wn * 64 + ni * 16 + c16;
            gl[ni] = lng[col]; bl[ni] = lnb[col];
        }
        #pragma unroll
        for (int r = 0; r < 4; ++r) {
            int rl = g4 * 4 + r;
            float s = lnred[0][wm][rl][0] + lnred[1][wm][rl][0];
            float q = lnred[0][wm][rl][1] + lnred[1][wm][rl][1];
            float mean = s * (1.f / CH);
            float var  = q * (1.f / CH) - mean * mean;
            float rstd = rsqrtf(var + LNEPS);
            int dst = dstl[r];
            #pragma unroll
            for (int ni = 0; ni < 4; ++ni) {
                int col = wn * 64 + ni * 16 + c16;
                float v = acc[ni][r];
                ((u16*)outp)[(size_t)dst * CH + col] = f2bf(v);
                ln_out[(size_t)dst * CH + col] = f2bf((v - mean) * rstd * gl[ni] + bl[ni]);
            }
        }
    } else {
        #pragma unroll
        for (int r = 0; r < 4; ++r) {
            int m = m0 + wm * 16 + g4 * 4 + r;
            #pragma unroll
            for (int ni = 0; ni < 4; ++ni) {
                int col = n0 + wn * 64 + ni * 16 + c16;
                float v = acc[ni][r];
                if (EPI == 1) {
                    v += bias[col] * (col < 128 ? QSCALE : 1.f);
                    ((u16*)outp)[(size_t)m * Nn + col] = f2bf(v);
                } else if (EPI == 3) {
                    v += bias[col];
                    v = 0.5f * v * (1.f + erff(v * 0.70710678118654752f));
                    ((u16*)outp)[(size_t)m * Nn + col] = f2bf(v);
                } else { // EPI 4
                    v += bias[col];
                    ((float*)outp)[(size_t)m * CH + col]
                        = v + bf2f(residb[(size_t)m * CH + col]);
                }
            }
        }
    }
}

// ---- bias+mask table, f32, MFMA C-fragment layout: [hw][t][nt=26][lane][r] ----
__global__ __launch_bounds__(64) void bias_k(
    const float* __restrict__ rpb, float* __restrict__ biasT2)
{
    int nt = blockIdx.x;   // 0..25 (col tile; 25 is all -100 pad)
    int t  = blockIdx.y;   // 0..24 (row tile)
    int hw = blockIdx.z;   // head*4 + wt
    int l  = threadIdx.x;  // 0..63
    int head = hw >> 2, wt = hw & 3;
    int bh7 = wt >> 1, bw7 = wt & 1;
    int j = nt * 16 + (l & 15);
    int rb = t * 16 + (l >> 4) * 4;
    f32x4 outv;
    #pragma unroll
    for (int r = 0; r < 4; ++r) {
        int i = rb + r; if (i > NTOK - 1) i = NTOK - 1;
        float v;
        if (j >= NTOK) v = -100.f;
        else {
            int di = i / 49, ri = i - di * 49, hi = ri / 7, wi = ri - hi * 7;
            int dj = j / 49, rj = j - dj * 49, hj = rj / 7, wj = rj - hj * 7;
            int bidx = (di - dj + 7) * 169 + (hi - hj + 6) * 13 + (wi - wj + 6);
            v = rpb[bidx * NHEADS + head];
            int regi = (bh7 ? (hi < 4 ? 1 : 2) : 0) * 3 + (bw7 ? (wi < 4 ? 1 : 2) : 0);
            int regj = (bh7 ? (hj < 4 ? 1 : 2) : 0) * 3 + (bw7 ? (wj < 4 ? 1 : 2) : 0);
            if (regi != regj) v -= 100.f;
        }
        outv[r] = v;
    }
    *(f32x4*)&biasT2[((((size_t)hw * 25 + t) * 26 + nt) << 8) + (l << 2)] = outv;
}

// ---- flash-strip MFMA attention, 8 waves/block, two-tile interleaved ----
// K-frags from global/L2 (shared between paired tiles); bias in MFMA C-operand.
// LDS = V^T + 2 P strips per wave (47.4 KB)
__global__ __launch_bounds__(512, 4) void attn_mfma(
    const u16* __restrict__ Qb, const float* __restrict__ biasT2,
    u16* __restrict__ O)
{
    __shared__ u16 Vt[32][420];         // 26880 B, cols 400..415 zero
    __shared__ u16 Pst[8][2][16][40];   // 20480 B, per-wave 2 P strips

    int bid = blockIdx.x;
    int win = bid >> 2, head = bid & 3;
    int tid = threadIdx.x, w = tid >> 6, l = tid & 63;
    int c16 = l & 15, g4 = l >> 4;

    const size_t qbase = (size_t)win * NTOK * 384;
    for (int e = tid; e < 1600; e += 512) {
        int j = e >> 2, d0 = (e & 3) * 8;
        u16x8 vv = {0, 0, 0, 0, 0, 0, 0, 0};
        if (j < NTOK)
            vv = *(const u16x8*)&Qb[qbase + (size_t)j * 384 + 256 + head * 32 + d0];
        #pragma unroll
        for (int i = 0; i < 8; ++i) Vt[d0 + i][j] = vv[i];
    }
    if (tid < 32 * 16) Vt[tid >> 4][400 + (tid & 15)] = 0;
    __syncthreads();

    int wIdx = win & 63;
    int wt = (((wIdx >> 3) == 7) ? 2 : 0) + (((wIdx & 7) == 7) ? 1 : 0);
    const float* bt = biasT2 + (((size_t)(head * 4 + wt) * 25 * 26) << 8) + (l << 2);
    const u16* kroot = Qb + qbase + 128 + head * 32 + g4 * 8;
    u16 (*myPA)[40] = Pst[w][0];
    u16 (*myPB)[40] = Pst[w][1];

    // ---- paired pass: tiles tA = w, tB = w + 8 (rows < 256, no clamps) ----
    {
        int tA = w, tB = w + 8;
        s16x8 qfragA = __builtin_bit_cast(s16x8,
            *(const u16x8*)&Qb[qbase + (size_t)(tA * 16 + c16) * 384 + head * 32 + g4 * 8]);
        s16x8 qfragB = __builtin_bit_cast(s16x8,
            *(const u16x8*)&Qb[qbase + (size_t)(tB * 16 + c16) * 384 + head * 32 + g4 * 8]);
        const float* bttA = bt + (((size_t)tA * 26) << 8);
        const float* bttB = bt + (((size_t)tB * 26) << 8);

        float l4A[4] = {0.f, 0.f, 0.f, 0.f};
        float l4B[4] = {0.f, 0.f, 0.f, 0.f};
        f32x4 oaccA0 = {0.f,0.f,0.f,0.f}, oaccA1 = {0.f,0.f,0.f,0.f};
        f32x4 oaccB0 = {0.f,0.f,0.f,0.f}, oaccB1 = {0.f,0.f,0.f,0.f};

        for (int jb = 0; jb < 13; ++jb) {
            // shared K fragments (t-independent)
            int kr0 = jb * 32 + c16;      if (kr0 > NTOK - 1) kr0 = NTOK - 1;
            int kr1 = jb * 32 + 16 + c16; if (kr1 > NTOK - 1) kr1 = NTOK - 1;
            s16x8 kf0 = __builtin_bit_cast(s16x8, *(const u16x8*)&kroot[(size_t)kr0 * 384]);
            s16x8 kf1 = __builtin_bit_cast(s16x8, *(const u16x8*)&kroot[(size_t)kr1 * 384]);
            // two independent QK^T chains
            f32x4 sA0 = mfma16(qfragA, kf0, *(const f32x4*)(bttA + (((size_t)(jb*2+0)) << 8)));
            f32x4 sA1 = mfma16(qfragA, kf1, *(const f32x4*)(bttA + (((size_t)(jb*2+1)) << 8)));
            f32x4 sB0 = mfma16(qfragB, kf0, *(const f32x4*)(bttB + (((size_t)(jb*2+0)) << 8)));
            f32x4 sB1 = mfma16(qfragB, kf1, *(const f32x4*)(bttB + (((size_t)(jb*2+1)) << 8)));
            #pragma unroll
            for (int r = 0; r < 4; ++r) {
                float p0 = exp2f(sA0[r] * 1.44269504f);
                float p1 = exp2f(sA1[r] * 1.44269504f);
                l4A[r] += p0 + p1;
                myPA[g4 * 4 + r][c16]      = f2bf(p0);
                myPA[g4 * 4 + r][16 + c16] = f2bf(p1);
            }
            #pragma unroll
            for (int r = 0; r < 4; ++r) {
                float p0 = exp2f(sB0[r] * 1.44269504f);
                float p1 = exp2f(sB1[r] * 1.44269504f);
                l4B[r] += p0 + p1;
                myPB[g4 * 4 + r][c16]      = f2bf(p0);
                myPB[g4 * 4 + r][16 + c16] = f2bf(p1);
            }
            s16x8 paA = __builtin_bit_cast(s16x8, *(const u16x8*)&myPA[c16][g4 * 8]);
            s16x8 paB = __builtin_bit_cast(s16x8, *(const u16x8*)&myPB[c16][g4 * 8]);
            // shared V fragments (t-independent)
            s16x8 vb0 = __builtin_bit_cast(s16x8, *(const u16x8*)&Vt[c16][jb * 32 + g4 * 8]);
            s16x8 vb1 = __builtin_bit_cast(s16x8, *(const u16x8*)&Vt[16 + c16][jb * 32 + g4 * 8]);
            oaccA0 = mfma16(paA, vb0, oaccA0);
            oaccA1 = mfma16(paA, vb1, oaccA1);
            oaccB0 = mfma16(paB, vb0, oaccB0);
            oaccB1 = mfma16(paB, vb1, oaccB1);
        }

        #pragma unroll
        for (int r = 0; r < 4; ++r) {
            #pragma unroll
            for (int o = 1; o <= 8; o <<= 1) {
                l4A[r] += __shfl_xor(l4A[r], o);
                l4B[r] += __shfl_xor(l4B[r], o);
            }
            l4A[r] = 1.f / l4A[r];
            l4B[r] = 1.f / l4B[r];
        }
        #pragma unroll
        for (int r = 0; r < 4; ++r) {
            int qA = tA * 16 + g4 * 4 + r;
            int qB = tB * 16 + g4 * 4 + r;
            size_t oA = ((size_t)(win * NTOK + qA)) * CH + head * 32 + c16;
            size_t oB = ((size_t)(win * NTOK + qB)) * CH + head * 32 + c16;
            O[oA]      = f2bf(oaccA0[r] * l4A[r]);
            O[oA + 16] = f2bf(oaccA1[r] * l4A[r]);
            O[oB]      = f2bf(oaccB0[r] * l4B[r]);
            O[oB + 16] = f2bf(oaccB1[r] * l4B[r]);
        }
    }

    // ---- solo pass: t = w+16 (all waves), plus t = 24 for w = 0 ----
    for (int t = w + 16; t < 25; t += 8) {
        int row0 = t * 16;
        int qr = row0 + c16; if (qr > NTOK - 1) qr = NTOK - 1;
        s16x8 afrag = __builtin_bit_cast(s16x8,
            *(const u16x8*)&Qb[qbase + (size_t)qr * 384 + head * 32 + g4 * 8]);
        const float* btt = bt + (((size_t)t * 26) << 8);

        float l4[4] = {0.f, 0.f, 0.f, 0.f};
        f32x4 oacc[2] = {{0.f,0.f,0.f,0.f},{0.f,0.f,0.f,0.f}};

        for (int jb = 0; jb < 13; ++jb) {
            f32x4 s[2];
            #pragma unroll
            for (int kk = 0; kk < 2; ++kk) {
                f32x4 cb = *(const f32x4*)(btt + (((size_t)(jb * 2 + kk)) << 8));
                int kr = jb * 32 + kk * 16 + c16;
                if (kr > NTOK - 1) kr = NTOK - 1;
                s16x8 bfrag = __builtin_bit_cast(s16x8,
                    *(const u16x8*)&kroot[(size_t)kr * 384]);
                s[kk] = mfma16(afrag, bfrag, cb);
            }
            #pragma unroll
            for (int kk = 0; kk < 2; ++kk)
                #pragma unroll
                for (int r = 0; r < 4; ++r) {
                    float p = exp2f(s[kk][r] * 1.44269504f);
                    l4[r] += p;
                    myPA[g4 * 4 + r][kk * 16 + c16] = f2bf(p);
                }
            s16x8 pa = __builtin_bit_cast(s16x8, *(const u16x8*)&myPA[c16][g4 * 8]);
            #pragma unroll
            for (int nd = 0; nd < 2; ++nd) {
                s16x8 vb = __builtin_bit_cast(s16x8,
                    *(const u16x8*)&Vt[nd * 16 + c16][jb * 32 + g4 * 8]);
                oacc[nd] = mfma16(pa, vb, oacc[nd]);
            }
        }

        #pragma unroll
        for (int r = 0; r < 4; ++r) {
            #pragma unroll
            for (int o = 1; o <= 8; o <<= 1)
                l4[r] += __shfl_xor(l4[r], o);
            l4[r] = 1.f / l4[r];
        }
        #pragma unroll
        for (int nd = 0; nd < 2; ++nd)
            #pragma unroll
            for (int r = 0; r < 4; ++r) {
                int qrow = row0 + g4 * 4 + r;
                if (qrow < NTOK)
                    O[((size_t)(win * NTOK + qrow)) * CH + head * 32 + nd * 16 + c16]
                        = f2bf(oacc[nd][r] * l4[r]);
            }
    }
}

extern "C" void kernel_launch(void* const* d_in, const int* in_sizes, int n_in,
                              void* d_out, int out_size, void* d_ws, size_t ws_size,
                              hipStream_t stream) {
    const float* x      = (const float*)d_in[0];
    const float* n1g    = (const float*)d_in[1];
    const float* n1b    = (const float*)d_in[2];
    const float* qkv_w  = (const float*)d_in[3];
    const float* qkv_b  = (const float*)d_in[4];
    const float* proj_w = (const float*)d_in[5];
    const float* proj_b = (const float*)d_in[6];
    const float* rpb    = (const float*)d_in[7];
    const float* n2g    = (const float*)d_in[8];
    const float* n2b    = (const float*)d_in[9];
    const float* fc1_w  = (const float*)d_in[10];
    const float* fc1_b  = (const float*)d_in[11];
    const float* fc2_w  = (const float*)d_in[12];
    const float* fc2_b  = (const float*)d_in[13];
    float* out = (float*)d_out;

    char* ws = (char*)d_ws;
    size_t off = 0;
    u16* A_bf  = (u16*)(ws + off);  off += (size_t)TOK * 128 * 2;
    u16* Qb_bf = (u16*)(ws + off);  off += (size_t)TOK * 384 * 2;
    u16* O_bf  = (u16*)(ws + off);  off += (size_t)TOK * 128 * 2;
    u16* R_bf  = (u16*)(ws + off);  off += (size_t)TOK * 128 * 2;   // bf16 residual trunk
    u16* qkvT  = (u16*)(ws + off);  off += 384 * 128 * 2;
    u16* projT = (u16*)(ws + off);  off += 128 * 128 * 2;
    u16* fc1T  = (u16*)(ws + off);  off += 512 * 128 * 2;
    u16* fc2T  = (u16*)(ws + off);  off += 128 * 512 * 2;
    u16* H_bf  = Qb_bf;             // overlays Qb+O exactly; both dead by fc1
    float* biasT2 = (float*)A_bf;   // overlay; A_bf dead after qkv GEMM,
                                    // rewritten by proj's fused LN2

    // 0. weight transposes (+bf16), QSCALE folded into Wq
    hipLaunchKernelGGL(convT, dim3(384/32, 128/32), dim3(256), 0, stream, qkv_w,  qkvT, 128, 384, 128);
    hipLaunchKernelGGL(convT, dim3(128/32, 128/32), dim3(256), 0, stream, proj_w, projT, 128, 128, 0);
    hipLaunchKernelGGL(convT, dim3(512/32, 128/32), dim3(256), 0, stream, fc1_w,  fc1T, 128, 512, 0);
    hipLaunchKernelGGL(convT, dim3(128/32, 512/32), dim3(256), 0, stream, fc2_w,  fc2T, 512, 128, 0);
    // 1. LN1 + shift + window_partition -> bf16
    hipLaunchKernelGGL(ln_kernel, dim3(TOK), dim3(128), 0, stream, x, n1g, n1b, A_bf);
    // 2. qkv GEMM -> bf16
    hipLaunchKernelGGL((gemm_mfma<1, 128>), dim3(3, TOK/64), dim3(512), 0, stream,
                       A_bf, qkvT, qkv_b, Qb_bf, 384, nullptr, nullptr, nullptr, nullptr, nullptr);
    // 2b. bias+mask table (A_bf dead; overlay)
    hipLaunchKernelGGL(bias_k, dim3(26, 25, 16), dim3(64), 0, stream, rpb, biasT2);
    // 3. two-tile interleaved flash attention -> bf16
    hipLaunchKernelGGL(attn_mfma, dim3(NWIN * NHEADS), dim3(512), 0, stream,
                       Qb_bf, biasT2, O_bf);
    // 4. proj GEMM + unshift + residual -> bf16 R, fused LN2 -> bf16 A_bf
    hipLaunchKernelGGL((gemm_mfma<2, 128>), dim3(1, TOK/64), dim3(512), 0, stream,
                       O_bf, projT, proj_b, R_bf, 128, x, nullptr, n2g, n2b, A_bf);
    // 5. fc1 + GELU -> bf16
    hipLaunchKernelGGL((gemm_mfma<3, 128>), dim3(4, TOK/64), dim3(512), 0, stream,
                       A_bf, fc1T, fc1_b, H_bf, 512, nullptr, nullptr, nullptr, nullptr, nullptr);
    // 6. fc2 + bf16 residual -> f32 out
    hipLaunchKernelGGL((gemm_mfma<4, 512>), dim3(1, TOK/64), dim3(512), 0, stream,
                       H_bf, fc2T, fc2_b, out, 128, nullptr, R_bf, nullptr, nullptr, nullptr);
}

// Round 14
// 163.428 us; speedup vs baseline: 1.4021x; 1.0242x over previous
//
#include <hip/hip_runtime.h>
#include <math.h>

// ---- problem constants ----
#define TOK    50176      // 2*8*56*56 tokens
#define CH     128
#define NWIN   128        // B * 64 windows
#define NTOK   392        // 8*7*7 tokens per window
#define NHEADS 4
#define QSCALE 0.17677669529663687f   // 32^-0.5
#define LNEPS  1e-3f

typedef unsigned short u16;
typedef unsigned int   u32;
typedef u16   u16x4  __attribute__((ext_vector_type(4)));
typedef u16   u16x8  __attribute__((ext_vector_type(8)));
typedef short s16x8  __attribute__((ext_vector_type(8)));
typedef float f32x4  __attribute__((ext_vector_type(4)));

__device__ __forceinline__ float bf2f(u16 u) {
    return __uint_as_float(((u32)u) << 16);
}
__device__ __forceinline__ u16 f2bf(float f) {
    u32 u = __float_as_uint(f);
    return (u16)((u + 0x7fffu + ((u >> 16) & 1u)) >> 16);
}
__device__ __forceinline__ f32x4 mfma16(s16x8 a, s16x8 b, f32x4 c) {
    return __builtin_amdgcn_mfma_f32_16x16x32_bf16(a, b, c, 0, 0, 0);
}

// token m in window layout -> flat token index in original layout (+3 roll)
__device__ __forceinline__ int src_index(int m) {
    int b = m / NTOK, t = m - b * NTOK;
    int batch = b >> 6, wIdx = b & 63;
    int bh = wIdx >> 3, bw = wIdx & 7;
    int d = t / 49, rem = t - d * 49;
    int h7 = rem / 7, w7 = rem - h7 * 7;
    int h = bh * 7 + h7 + 3; if (h >= 56) h -= 56;
    int w = bw * 7 + w7 + 3; if (w >= 56) w -= 56;
    return ((batch * 8 + d) * 56 + h) * 56 + w;
}

// ---- weight transpose + f32->bf16 convert: dst[n][k] = src[k][n] * sc ----
__global__ __launch_bounds__(256) void convT(
    const float* __restrict__ src, u16* __restrict__ dst,
    int K, int N, int scaleN)
{
    __shared__ float t[32][33];
    int n0 = blockIdx.x * 32, k0 = blockIdx.y * 32;
    int tx = threadIdx.x & 31, ty = threadIdx.x >> 5;   // ty 0..7
    #pragma unroll
    for (int r = 0; r < 4; ++r)
        t[ty + r * 8][tx] = src[(size_t)(k0 + ty + r * 8) * N + n0 + tx];
    __syncthreads();
    #pragma unroll
    for (int r = 0; r < 4; ++r) {
        int n = n0 + ty + r * 8;
        float sc = (n < scaleN) ? QSCALE : 1.f;
        dst[(size_t)n * K + k0 + tx] = f2bf(t[tx][ty + r * 8] * sc);
    }
}

// ---- LN1: gather f32 x via src_index, LN, -> bf16 window layout ----
__global__ __launch_bounds__(128) void ln_kernel(
    const float* __restrict__ xin,
    const float* __restrict__ g, const float* __restrict__ bta,
    u16* __restrict__ out)
{
    int m = blockIdx.x, c = threadIdx.x;
    float v = xin[(size_t)src_index(m) * CH + c];
    float s1 = v, s2 = v * v;
    #pragma unroll
    for (int o = 32; o; o >>= 1) { s1 += __shfl_xor(s1, o); s2 += __shfl_xor(s2, o); }
    __shared__ float ps[2][2];
    int w = c >> 6;
    if ((c & 63) == 0) { ps[w][0] = s1; ps[w][1] = s2; }
    __syncthreads();
    s1 = ps[0][0] + ps[1][0];
    s2 = ps[0][1] + ps[1][1];
    float mean = s1 * (1.f / CH);
    float var  = s2 * (1.f / CH) - mean * mean;
    float r = rsqrtf(var + LNEPS);
    out[(size_t)m * CH + c] = f2bf((v - mean) * r * g[c] + bta[c]);
}

// ---- MFMA GEMM, BM=64 x BN=128, 512 threads (8 waves = 4m x 2n), BK=128 ----
// EPI 1: qkv -> bf16; EPI 2: proj + resid -> bf16 R + fused LN2 -> bf16;
// EPI 3: gelu -> bf16; EPI 4: fc2 + bf16 resid -> f32 out
template<int EPI, int KTOT>
__global__ __launch_bounds__(512, 6) void gemm_mfma(
    const u16* __restrict__ A, const u16* __restrict__ W,
    const float* __restrict__ bias, void* __restrict__ outp,
    int Nn, const float* __restrict__ resid, const u16* __restrict__ residb,
    const float* __restrict__ lng, const float* __restrict__ lnb,
    u16* __restrict__ ln_out)
{
    __shared__ u16 As[4][64][32];        // 16 KB  [kc][row][k32]
    __shared__ u16 Bs[4][128][32];       // 32 KB
    __shared__ float lnred[2][4][16][2]; // 1 KB

    int tid = threadIdx.x, w = tid >> 6, l = tid & 63;
    int c16 = l & 15, g4 = l >> 4;
    int m0 = blockIdx.y * 64, n0 = blockIdx.x * 128;
    int wm = w & 3, wn = w >> 2;
    const int NCH = KTOT / 128;

    f32x4 acc[4] = {};
    u16x8 va[2], vb[4];

    #pragma unroll
    for (int p = 0; p < 2; ++p) {
        int e = tid + p * 512, row = e >> 4, c8 = e & 15;
        va[p] = *(const u16x8*)&A[(size_t)(m0 + row) * KTOT + c8 * 8];
    }
    #pragma unroll
    for (int p = 0; p < 4; ++p) {
        int e = tid + p * 512, row = e >> 4, c8 = e & 15;
        vb[p] = *(const u16x8*)&W[(size_t)(n0 + row) * KTOT + c8 * 8];
    }
    for (int ch = 0; ch < NCH; ++ch) {
        #pragma unroll
        for (int p = 0; p < 2; ++p) {
            int e = tid + p * 512, row = e >> 4, c8 = e & 15;
            *(u16x8*)&As[c8 >> 2][row][(c8 & 3) * 8] = va[p];
        }
        #pragma unroll
        for (int p = 0; p < 4; ++p) {
            int e = tid + p * 512, row = e >> 4, c8 = e & 15;
            *(u16x8*)&Bs[c8 >> 2][row][(c8 & 3) * 8] = vb[p];
        }
        __syncthreads();
        if (ch + 1 < NCH) {
            #pragma unroll
            for (int p = 0; p < 2; ++p) {
                int e = tid + p * 512, row = e >> 4, c8 = e & 15;
                va[p] = *(const u16x8*)&A[(size_t)(m0 + row) * KTOT + (ch + 1) * 128 + c8 * 8];
            }
            #pragma unroll
            for (int p = 0; p < 4; ++p) {
                int e = tid + p * 512, row = e >> 4, c8 = e & 15;
                vb[p] = *(const u16x8*)&W[(size_t)(n0 + row) * KTOT + (ch + 1) * 128 + c8 * 8];
            }
        }
        #pragma unroll
        for (int kc = 0; kc < 4; ++kc) {
            s16x8 af = __builtin_bit_cast(s16x8,
                *(const u16x8*)&As[kc][wm * 16 + c16][g4 * 8]);
            #pragma unroll
            for (int ni = 0; ni < 4; ++ni) {
                s16x8 bf = __builtin_bit_cast(s16x8,
                    *(const u16x8*)&Bs[kc][wn * 64 + ni * 16 + c16][g4 * 8]);
                acc[ni] = mfma16(af, bf, acc[ni]);
            }
        }
        if (ch + 1 < NCH) __syncthreads();
    }

    if (EPI == 2) {
        float psum[4], psq[4];
        int dstl[4];
        #pragma unroll
        for (int r = 0; r < 4; ++r) {
            int m = m0 + wm * 16 + g4 * 4 + r;
            int dst = src_index(m);
            dstl[r] = dst;
            float s = 0.f, q = 0.f;
            #pragma unroll
            for (int ni = 0; ni < 4; ++ni) {
                int col = wn * 64 + ni * 16 + c16;
                float v = acc[ni][r] + bias[col] + resid[(size_t)dst * CH + col];
                acc[ni][r] = v;
                s += v; q += v * v;
            }
            psum[r] = s; psq[r] = q;
        }
        #pragma unroll
        for (int o = 1; o <= 8; o <<= 1)
            #pragma unroll
            for (int r = 0; r < 4; ++r) {
                psum[r] += __shfl_xor(psum[r], o);
                psq[r]  += __shfl_xor(psq[r], o);
            }
        if (c16 == 0) {
            #pragma unroll
            for (int r = 0; r < 4; ++r) {
                int rl = g4 * 4 + r;
                lnred[wn][wm][rl][0] = psum[r];
                lnred[wn][wm][rl][1] = psq[r];
            }
        }
        __syncthreads();
        float gl[4], bl[4];
        #pragma unroll
        for (int ni = 0; ni < 4; ++ni) {
            int col = wn * 64 + ni * 16 + c16;
            gl[ni] = lng[col]; bl[ni] = lnb[col];
        }
        #pragma unroll
        for (int r = 0; r < 4; ++r) {
            int rl = g4 * 4 + r;
            float s = lnred[0][wm][rl][0] + lnred[1][wm][rl][0];
            float q = lnred[0][wm][rl][1] + lnred[1][wm][rl][1];
            float mean = s * (1.f / CH);
            float var  = q * (1.f / CH) - mean * mean;
            float rstd = rsqrtf(var + LNEPS);
            int dst = dstl[r];
            #pragma unroll
            for (int ni = 0; ni < 4; ++ni) {
                int col = wn * 64 + ni * 16 + c16;
                float v = acc[ni][r];
                ((u16*)outp)[(size_t)dst * CH + col] = f2bf(v);
                ln_out[(size_t)dst * CH + col] = f2bf((v - mean) * rstd * gl[ni] + bl[ni]);
            }
        }
    } else {
        #pragma unroll
        for (int r = 0; r < 4; ++r) {
            int m = m0 + wm * 16 + g4 * 4 + r;
            #pragma unroll
            for (int ni = 0; ni < 4; ++ni) {
                int col = n0 + wn * 64 + ni * 16 + c16;
                float v = acc[ni][r];
                if (EPI == 1) {
                    v += bias[col] * (col < 128 ? QSCALE : 1.f);
                    ((u16*)outp)[(size_t)m * Nn + col] = f2bf(v);
                } else if (EPI == 3) {
                    v += bias[col];
                    v = 0.5f * v * (1.f + erff(v * 0.70710678118654752f));
                    ((u16*)outp)[(size_t)m * Nn + col] = f2bf(v);
                } else { // EPI 4
                    v += bias[col];
                    ((float*)outp)[(size_t)m * CH + col]
                        = v + bf2f(residb[(size_t)m * CH + col]);
                }
            }
        }
    }
}

// ---- bias+mask table, f32, MFMA C-fragment layout: [hw][t][nt=26][lane][r] ----
__global__ __launch_bounds__(64) void bias_k(
    const float* __restrict__ rpb, float* __restrict__ biasT2)
{
    int nt = blockIdx.x;   // 0..25 (col tile; 25 is all -100 pad)
    int t  = blockIdx.y;   // 0..24 (row tile)
    int hw = blockIdx.z;   // head*4 + wt
    int l  = threadIdx.x;  // 0..63
    int head = hw >> 2, wt = hw & 3;
    int bh7 = wt >> 1, bw7 = wt & 1;
    int j = nt * 16 + (l & 15);
    int rb = t * 16 + (l >> 4) * 4;
    f32x4 outv;
    #pragma unroll
    for (int r = 0; r < 4; ++r) {
        int i = rb + r; if (i > NTOK - 1) i = NTOK - 1;
        float v;
        if (j >= NTOK) v = -100.f;
        else {
            int di = i / 49, ri = i - di * 49, hi = ri / 7, wi = ri - hi * 7;
            int dj = j / 49, rj = j - dj * 49, hj = rj / 7, wj = rj - hj * 7;
            int bidx = (di - dj + 7) * 169 + (hi - hj + 6) * 13 + (wi - wj + 6);
            v = rpb[bidx * NHEADS + head];
            int regi = (bh7 ? (hi < 4 ? 1 : 2) : 0) * 3 + (bw7 ? (wi < 4 ? 1 : 2) : 0);
            int regj = (bh7 ? (hj < 4 ? 1 : 2) : 0) * 3 + (bw7 ? (wj < 4 ? 1 : 2) : 0);
            if (regi != regj) v -= 100.f;
        }
        outv[r] = v;
    }
    *(f32x4*)&biasT2[((((size_t)hw * 25 + t) * 26 + nt) << 8) + (l << 2)] = outv;
}

// ---- flash-strip MFMA attention, 8 waves/block, THREE-tile interleaved ----
// K-frags from global/L2 (shared among the 3 tiles); bias in MFMA C-operand.
// LDS = V^T + 3 P strips per wave (57.6 KB)
__global__ __launch_bounds__(512, 4) void attn_mfma(
    const u16* __restrict__ Qb, const float* __restrict__ biasT2,
    u16* __restrict__ O)
{
    __shared__ u16 Vt[32][420];         // 26880 B, cols 400..415 zero
    __shared__ u16 Pst[8][3][16][40];   // 30720 B, per-wave 3 P strips

    int bid = blockIdx.x;
    int win = bid >> 2, head = bid & 3;
    int tid = threadIdx.x, w = tid >> 6, l = tid & 63;
    int c16 = l & 15, g4 = l >> 4;

    const size_t qbase = (size_t)win * NTOK * 384;
    for (int e = tid; e < 1600; e += 512) {
        int j = e >> 2, d0 = (e & 3) * 8;
        u16x8 vv = {0, 0, 0, 0, 0, 0, 0, 0};
        if (j < NTOK)
            vv = *(const u16x8*)&Qb[qbase + (size_t)j * 384 + 256 + head * 32 + d0];
        #pragma unroll
        for (int i = 0; i < 8; ++i) Vt[d0 + i][j] = vv[i];
    }
    if (tid < 32 * 16) Vt[tid >> 4][400 + (tid & 15)] = 0;
    __syncthreads();

    int wIdx = win & 63;
    int wt = (((wIdx >> 3) == 7) ? 2 : 0) + (((wIdx & 7) == 7) ? 1 : 0);
    const float* bt = biasT2 + (((size_t)(head * 4 + wt) * 25 * 26) << 8) + (l << 2);
    const u16* kroot = Qb + qbase + 128 + head * 32 + g4 * 8;
    u16 (*myPA)[40] = Pst[w][0];
    u16 (*myPB)[40] = Pst[w][1];
    u16 (*myPC)[40] = Pst[w][2];

    // ---- triple pass: tiles tA = w, tB = w+8, tC = w+16 (rows < 384, clamp-free) ----
    {
        int tA = w, tB = w + 8, tC = w + 16;
        s16x8 qfragA = __builtin_bit_cast(s16x8,
            *(const u16x8*)&Qb[qbase + (size_t)(tA * 16 + c16) * 384 + head * 32 + g4 * 8]);
        s16x8 qfragB = __builtin_bit_cast(s16x8,
            *(const u16x8*)&Qb[qbase + (size_t)(tB * 16 + c16) * 384 + head * 32 + g4 * 8]);
        s16x8 qfragC = __builtin_bit_cast(s16x8,
            *(const u16x8*)&Qb[qbase + (size_t)(tC * 16 + c16) * 384 + head * 32 + g4 * 8]);
        const float* bttA = bt + (((size_t)tA * 26) << 8);
        const float* bttB = bt + (((size_t)tB * 26) << 8);
        const float* bttC = bt + (((size_t)tC * 26) << 8);

        float l4A[4] = {0.f,0.f,0.f,0.f}, l4B[4] = {0.f,0.f,0.f,0.f}, l4C[4] = {0.f,0.f,0.f,0.f};
        f32x4 oaccA0 = {0.f,0.f,0.f,0.f}, oaccA1 = {0.f,0.f,0.f,0.f};
        f32x4 oaccB0 = {0.f,0.f,0.f,0.f}, oaccB1 = {0.f,0.f,0.f,0.f};
        f32x4 oaccC0 = {0.f,0.f,0.f,0.f}, oaccC1 = {0.f,0.f,0.f,0.f};

        for (int jb = 0; jb < 13; ++jb) {
            // shared K fragments (t-independent)
            int kr0 = jb * 32 + c16;      if (kr0 > NTOK - 1) kr0 = NTOK - 1;
            int kr1 = jb * 32 + 16 + c16; if (kr1 > NTOK - 1) kr1 = NTOK - 1;
            s16x8 kf0 = __builtin_bit_cast(s16x8, *(const u16x8*)&kroot[(size_t)kr0 * 384]);
            s16x8 kf1 = __builtin_bit_cast(s16x8, *(const u16x8*)&kroot[(size_t)kr1 * 384]);
            // three independent QK^T chains
            f32x4 sA0 = mfma16(qfragA, kf0, *(const f32x4*)(bttA + (((size_t)(jb*2+0)) << 8)));
            f32x4 sA1 = mfma16(qfragA, kf1, *(const f32x4*)(bttA + (((size_t)(jb*2+1)) << 8)));
            f32x4 sB0 = mfma16(qfragB, kf0, *(const f32x4*)(bttB + (((size_t)(jb*2+0)) << 8)));
            f32x4 sB1 = mfma16(qfragB, kf1, *(const f32x4*)(bttB + (((size_t)(jb*2+1)) << 8)));
            f32x4 sC0 = mfma16(qfragC, kf0, *(const f32x4*)(bttC + (((size_t)(jb*2+0)) << 8)));
            f32x4 sC1 = mfma16(qfragC, kf1, *(const f32x4*)(bttC + (((size_t)(jb*2+1)) << 8)));
            #pragma unroll
            for (int r = 0; r < 4; ++r) {
                float p0 = exp2f(sA0[r] * 1.44269504f);
                float p1 = exp2f(sA1[r] * 1.44269504f);
                l4A[r] += p0 + p1;
                myPA[g4 * 4 + r][c16]      = f2bf(p0);
                myPA[g4 * 4 + r][16 + c16] = f2bf(p1);
            }
            #pragma unroll
            for (int r = 0; r < 4; ++r) {
                float p0 = exp2f(sB0[r] * 1.44269504f);
                float p1 = exp2f(sB1[r] * 1.44269504f);
                l4B[r] += p0 + p1;
                myPB[g4 * 4 + r][c16]      = f2bf(p0);
                myPB[g4 * 4 + r][16 + c16] = f2bf(p1);
            }
            #pragma unroll
            for (int r = 0; r < 4; ++r) {
                float p0 = exp2f(sC0[r] * 1.44269504f);
                float p1 = exp2f(sC1[r] * 1.44269504f);
                l4C[r] += p0 + p1;
                myPC[g4 * 4 + r][c16]      = f2bf(p0);
                myPC[g4 * 4 + r][16 + c16] = f2bf(p1);
            }
            s16x8 paA = __builtin_bit_cast(s16x8, *(const u16x8*)&myPA[c16][g4 * 8]);
            s16x8 paB = __builtin_bit_cast(s16x8, *(const u16x8*)&myPB[c16][g4 * 8]);
            s16x8 paC = __builtin_bit_cast(s16x8, *(const u16x8*)&myPC[c16][g4 * 8]);
            // shared V fragments (t-independent)
            s16x8 vb0 = __builtin_bit_cast(s16x8, *(const u16x8*)&Vt[c16][jb * 32 + g4 * 8]);
            s16x8 vb1 = __builtin_bit_cast(s16x8, *(const u16x8*)&Vt[16 + c16][jb * 32 + g4 * 8]);
            oaccA0 = mfma16(paA, vb0, oaccA0);
            oaccA1 = mfma16(paA, vb1, oaccA1);
            oaccB0 = mfma16(paB, vb0, oaccB0);
            oaccB1 = mfma16(paB, vb1, oaccB1);
            oaccC0 = mfma16(paC, vb0, oaccC0);
            oaccC1 = mfma16(paC, vb1, oaccC1);
        }

        #pragma unroll
        for (int r = 0; r < 4; ++r) {
            #pragma unroll
            for (int o = 1; o <= 8; o <<= 1) {
                l4A[r] += __shfl_xor(l4A[r], o);
                l4B[r] += __shfl_xor(l4B[r], o);
                l4C[r] += __shfl_xor(l4C[r], o);
            }
            l4A[r] = 1.f / l4A[r];
            l4B[r] = 1.f / l4B[r];
            l4C[r] = 1.f / l4C[r];
        }
        #pragma unroll
        for (int r = 0; r < 4; ++r) {
            int qA = tA * 16 + g4 * 4 + r;
            int qB = tB * 16 + g4 * 4 + r;
            int qC = tC * 16 + g4 * 4 + r;
            size_t oA = ((size_t)(win * NTOK + qA)) * CH + head * 32 + c16;
            size_t oB = ((size_t)(win * NTOK + qB)) * CH + head * 32 + c16;
            size_t oC = ((size_t)(win * NTOK + qC)) * CH + head * 32 + c16;
            O[oA]      = f2bf(oaccA0[r] * l4A[r]);
            O[oA + 16] = f2bf(oaccA1[r] * l4A[r]);
            O[oB]      = f2bf(oaccB0[r] * l4B[r]);
            O[oB + 16] = f2bf(oaccB1[r] * l4B[r]);
            O[oC]      = f2bf(oaccC0[r] * l4C[r]);
            O[oC + 16] = f2bf(oaccC1[r] * l4C[r]);
        }
    }

    // ---- solo pass: t = 24 on wave 0 only (8 valid rows, clamped) ----
    if (w == 0) {
        int t = 24;
        int row0 = t * 16;
        int qr = row0 + c16; if (qr > NTOK - 1) qr = NTOK - 1;
        s16x8 afrag = __builtin_bit_cast(s16x8,
            *(const u16x8*)&Qb[qbase + (size_t)qr * 384 + head * 32 + g4 * 8]);
        const float* btt = bt + (((size_t)t * 26) << 8);

        float l4[4] = {0.f, 0.f, 0.f, 0.f};
        f32x4 oacc[2] = {{0.f,0.f,0.f,0.f},{0.f,0.f,0.f,0.f}};

        for (int jb = 0; jb < 13; ++jb) {
            f32x4 s[2];
            #pragma unroll
            for (int kk = 0; kk < 2; ++kk) {
                f32x4 cb = *(const f32x4*)(btt + (((size_t)(jb * 2 + kk)) << 8));
                int kr = jb * 32 + kk * 16 + c16;
                if (kr > NTOK - 1) kr = NTOK - 1;
                s16x8 bfrag = __builtin_bit_cast(s16x8,
                    *(const u16x8*)&kroot[(size_t)kr * 384]);
                s[kk] = mfma16(afrag, bfrag, cb);
            }
            #pragma unroll
            for (int kk = 0; kk < 2; ++kk)
                #pragma unroll
                for (int r = 0; r < 4; ++r) {
                    float p = exp2f(s[kk][r] * 1.44269504f);
                    l4[r] += p;
                    myPA[g4 * 4 + r][kk * 16 + c16] = f2bf(p);
                }
            s16x8 pa = __builtin_bit_cast(s16x8, *(const u16x8*)&myPA[c16][g4 * 8]);
            #pragma unroll
            for (int nd = 0; nd < 2; ++nd) {
                s16x8 vb = __builtin_bit_cast(s16x8,
                    *(const u16x8*)&Vt[nd * 16 + c16][jb * 32 + g4 * 8]);
                oacc[nd] = mfma16(pa, vb, oacc[nd]);
            }
        }

        #pragma unroll
        for (int r = 0; r < 4; ++r) {
            #pragma unroll
            for (int o = 1; o <= 8; o <<= 1)
                l4[r] += __shfl_xor(l4[r], o);
            l4[r] = 1.f / l4[r];
        }
        #pragma unroll
        for (int nd = 0; nd < 2; ++nd)
            #pragma unroll
            for (int r = 0; r < 4; ++r) {
                int qrow = row0 + g4 * 4 + r;
                if (qrow < NTOK)
                    O[((size_t)(win * NTOK + qrow)) * CH + head * 32 + nd * 16 + c16]
                        = f2bf(oacc[nd][r] * l4[r]);
            }
    }
}

extern "C" void kernel_launch(void* const* d_in, const int* in_sizes, int n_in,
                              void* d_out, int out_size, void* d_ws, size_t ws_size,
                              hipStream_t stream) {
    const float* x      = (const float*)d_in[0];
    const float* n1g    = (const float*)d_in[1];
    const float* n1b    = (const float*)d_in[2];
    const float* qkv_w  = (const float*)d_in[3];
    const float* qkv_b  = (const float*)d_in[4];
    const float* proj_w = (const float*)d_in[5];
    const float* proj_b = (const float*)d_in[6];
    const float* rpb    = (const float*)d_in[7];
    const float* n2g    = (const float*)d_in[8];
    const float* n2b    = (const float*)d_in[9];
    const float* fc1_w  = (const float*)d_in[10];
    const float* fc1_b  = (const float*)d_in[11];
    const float* fc2_w  = (const float*)d_in[12];
    const float* fc2_b  = (const float*)d_in[13];
    float* out = (float*)d_out;

    char* ws = (char*)d_ws;
    size_t off = 0;
    u16* A_bf  = (u16*)(ws + off);  off += (size_t)TOK * 128 * 2;
    u16* Qb_bf = (u16*)(ws + off);  off += (size_t)TOK * 384 * 2;
    u16* O_bf  = (u16*)(ws + off);  off += (size_t)TOK * 128 * 2;
    u16* R_bf  = (u16*)(ws + off);  off += (size_t)TOK * 128 * 2;   // bf16 residual trunk
    u16* qkvT  = (u16*)(ws + off);  off += 384 * 128 * 2;
    u16* projT = (u16*)(ws + off);  off += 128 * 128 * 2;
    u16* fc1T  = (u16*)(ws + off);  off += 512 * 128 * 2;
    u16* fc2T  = (u16*)(ws + off);  off += 128 * 512 * 2;
    u16* H_bf  = Qb_bf;             // overlays Qb+O exactly; both dead by fc1
    float* biasT2 = (float*)A_bf;   // overlay; A_bf dead after qkv GEMM,
                                    // rewritten by proj's fused LN2

    // 0. weight transposes (+bf16), QSCALE folded into Wq
    hipLaunchKernelGGL(convT, dim3(384/32, 128/32), dim3(256), 0, stream, qkv_w,  qkvT, 128, 384, 128);
    hipLaunchKernelGGL(convT, dim3(128/32, 128/32), dim3(256), 0, stream, proj_w, projT, 128, 128, 0);
    hipLaunchKernelGGL(convT, dim3(512/32, 128/32), dim3(256), 0, stream, fc1_w,  fc1T, 128, 512, 0);
    hipLaunchKernelGGL(convT, dim3(128/32, 512/32), dim3(256), 0, stream, fc2_w,  fc2T, 512, 128, 0);
    // 1. LN1 + shift + window_partition -> bf16
    hipLaunchKernelGGL(ln_kernel, dim3(TOK), dim3(128), 0, stream, x, n1g, n1b, A_bf);
    // 2. qkv GEMM -> bf16
    hipLaunchKernelGGL((gemm_mfma<1, 128>), dim3(3, TOK/64), dim3(512), 0, stream,
                       A_bf, qkvT, qkv_b, Qb_bf, 384, nullptr, nullptr, nullptr, nullptr, nullptr);
    // 2b. bias+mask table (A_bf dead; overlay)
    hipLaunchKernelGGL(bias_k, dim3(26, 25, 16), dim3(64), 0, stream, rpb, biasT2);
    // 3. three-tile interleaved flash attention -> bf16
    hipLaunchKernelGGL(attn_mfma, dim3(NWIN * NHEADS), dim3(512), 0, stream,
                       Qb_bf, biasT2, O_bf);
    // 4. proj GEMM + unshift + residual -> bf16 R, fused LN2 -> bf16 A_bf
    hipLaunchKernelGGL((gemm_mfma<2, 128>), dim3(1, TOK/64), dim3(512), 0, stream,
                       O_bf, projT, proj_b, R_bf, 128, x, nullptr, n2g, n2b, A_bf);
    // 5. fc1 + GELU -> bf16
    hipLaunchKernelGGL((gemm_mfma<3, 128>), dim3(4, TOK/64), dim3(512), 0, stream,
                       A_bf, fc1T, fc1_b, H_bf, 512, nullptr, nullptr, nullptr, nullptr, nullptr);
    // 6. fc2 + bf16 residual -> f32 out
    hipLaunchKernelGGL((gemm_mfma<4, 512>), dim3(1, TOK/64), dim3(512), 0, stream,
                       H_bf, fc2T, fc2_b, out, 128, nullptr, R_bf, nullptr, nullptr, nullptr);
}

// Round 15
// 162.923 us; speedup vs baseline: 1.4065x; 1.0031x over previous
//
#include <hip/hip_runtime.h>
#include <math.h>

// ---- problem constants ----
#define TOK    50176      // 2*8*56*56 tokens
#define CH     128
#define NWIN   128        // B * 64 windows
#define NTOK   392        // 8*7*7 tokens per window
#define NHEADS 4
#define QSCALE 0.17677669529663687f   // 32^-0.5
#define LNEPS  1e-3f

typedef unsigned short u16;
typedef unsigned int   u32;
typedef u16   u16x4  __attribute__((ext_vector_type(4)));
typedef u16   u16x8  __attribute__((ext_vector_type(8)));
typedef short s16x8  __attribute__((ext_vector_type(8)));
typedef float f32x4  __attribute__((ext_vector_type(4)));

__device__ __forceinline__ float bf2f(u16 u) {
    return __uint_as_float(((u32)u) << 16);
}
__device__ __forceinline__ u16 f2bf(float f) {
    u32 u = __float_as_uint(f);
    return (u16)((u + 0x7fffu + ((u >> 16) & 1u)) >> 16);
}
__device__ __forceinline__ f32x4 mfma16(s16x8 a, s16x8 b, f32x4 c) {
    return __builtin_amdgcn_mfma_f32_16x16x32_bf16(a, b, c, 0, 0, 0);
}

// token m in window layout -> flat token index in original layout (+3 roll)
__device__ __forceinline__ int src_index(int m) {
    int b = m / NTOK, t = m - b * NTOK;
    int batch = b >> 6, wIdx = b & 63;
    int bh = wIdx >> 3, bw = wIdx & 7;
    int d = t / 49, rem = t - d * 49;
    int h7 = rem / 7, w7 = rem - h7 * 7;
    int h = bh * 7 + h7 + 3; if (h >= 56) h -= 56;
    int w = bw * 7 + w7 + 3; if (w >= 56) w -= 56;
    return ((batch * 8 + d) * 56 + h) * 56 + w;
}

// ---- weight transpose + f32->bf16 convert: dst[n][k] = src[k][n] * sc ----
__global__ __launch_bounds__(256) void convT(
    const float* __restrict__ src, u16* __restrict__ dst,
    int K, int N, int scaleN)
{
    __shared__ float t[32][33];
    int n0 = blockIdx.x * 32, k0 = blockIdx.y * 32;
    int tx = threadIdx.x & 31, ty = threadIdx.x >> 5;   // ty 0..7
    #pragma unroll
    for (int r = 0; r < 4; ++r)
        t[ty + r * 8][tx] = src[(size_t)(k0 + ty + r * 8) * N + n0 + tx];
    __syncthreads();
    #pragma unroll
    for (int r = 0; r < 4; ++r) {
        int n = n0 + ty + r * 8;
        float sc = (n < scaleN) ? QSCALE : 1.f;
        dst[(size_t)n * K + k0 + tx] = f2bf(t[tx][ty + r * 8] * sc);
    }
}

// ---- LN1: gather f32 x via src_index, LN, -> bf16 window layout ----
__global__ __launch_bounds__(128) void ln_kernel(
    const float* __restrict__ xin,
    const float* __restrict__ g, const float* __restrict__ bta,
    u16* __restrict__ out)
{
    int m = blockIdx.x, c = threadIdx.x;
    float v = xin[(size_t)src_index(m) * CH + c];
    float s1 = v, s2 = v * v;
    #pragma unroll
    for (int o = 32; o; o >>= 1) { s1 += __shfl_xor(s1, o); s2 += __shfl_xor(s2, o); }
    __shared__ float ps[2][2];
    int w = c >> 6;
    if ((c & 63) == 0) { ps[w][0] = s1; ps[w][1] = s2; }
    __syncthreads();
    s1 = ps[0][0] + ps[1][0];
    s2 = ps[0][1] + ps[1][1];
    float mean = s1 * (1.f / CH);
    float var  = s2 * (1.f / CH) - mean * mean;
    float r = rsqrtf(var + LNEPS);
    out[(size_t)m * CH + c] = f2bf((v - mean) * r * g[c] + bta[c]);
}

// ---- MFMA GEMM, BM=64 x BN=128, 512 threads (8 waves = 4m x 2n), BK=128 ----
// EPI 1: qkv -> bf16; EPI 2: proj + resid -> bf16 R + fused LN2 -> bf16
template<int EPI, int KTOT>
__global__ __launch_bounds__(512, 6) void gemm_mfma(
    const u16* __restrict__ A, const u16* __restrict__ W,
    const float* __restrict__ bias, void* __restrict__ outp,
    int Nn, const float* __restrict__ resid,
    const float* __restrict__ lng, const float* __restrict__ lnb,
    u16* __restrict__ ln_out)
{
    __shared__ u16 As[4][64][32];        // 16 KB  [kc][row][k32]
    __shared__ u16 Bs[4][128][32];       // 32 KB
    __shared__ float lnred[2][4][16][2]; // 1 KB

    int tid = threadIdx.x, w = tid >> 6, l = tid & 63;
    int c16 = l & 15, g4 = l >> 4;
    int m0 = blockIdx.y * 64, n0 = blockIdx.x * 128;
    int wm = w & 3, wn = w >> 2;
    const int NCH = KTOT / 128;

    f32x4 acc[4] = {};
    u16x8 va[2], vb[4];

    #pragma unroll
    for (int p = 0; p < 2; ++p) {
        int e = tid + p * 512, row = e >> 4, c8 = e & 15;
        va[p] = *(const u16x8*)&A[(size_t)(m0 + row) * KTOT + c8 * 8];
    }
    #pragma unroll
    for (int p = 0; p < 4; ++p) {
        int e = tid + p * 512, row = e >> 4, c8 = e & 15;
        vb[p] = *(const u16x8*)&W[(size_t)(n0 + row) * KTOT + c8 * 8];
    }
    for (int ch = 0; ch < NCH; ++ch) {
        #pragma unroll
        for (int p = 0; p < 2; ++p) {
            int e = tid + p * 512, row = e >> 4, c8 = e & 15;
            *(u16x8*)&As[c8 >> 2][row][(c8 & 3) * 8] = va[p];
        }
        #pragma unroll
        for (int p = 0; p < 4; ++p) {
            int e = tid + p * 512, row = e >> 4, c8 = e & 15;
            *(u16x8*)&Bs[c8 >> 2][row][(c8 & 3) * 8] = vb[p];
        }
        __syncthreads();
        if (ch + 1 < NCH) {
            #pragma unroll
            for (int p = 0; p < 2; ++p) {
                int e = tid + p * 512, row = e >> 4, c8 = e & 15;
                va[p] = *(const u16x8*)&A[(size_t)(m0 + row) * KTOT + (ch + 1) * 128 + c8 * 8];
            }
            #pragma unroll
            for (int p = 0; p < 4; ++p) {
                int e = tid + p * 512, row = e >> 4, c8 = e & 15;
                vb[p] = *(const u16x8*)&W[(size_t)(n0 + row) * KTOT + (ch + 1) * 128 + c8 * 8];
            }
        }
        #pragma unroll
        for (int kc = 0; kc < 4; ++kc) {
            s16x8 af = __builtin_bit_cast(s16x8,
                *(const u16x8*)&As[kc][wm * 16 + c16][g4 * 8]);
            #pragma unroll
            for (int ni = 0; ni < 4; ++ni) {
                s16x8 bf = __builtin_bit_cast(s16x8,
                    *(const u16x8*)&Bs[kc][wn * 64 + ni * 16 + c16][g4 * 8]);
                acc[ni] = mfma16(af, bf, acc[ni]);
            }
        }
        if (ch + 1 < NCH) __syncthreads();
    }

    if (EPI == 2) {
        float psum[4], psq[4];
        int dstl[4];
        #pragma unroll
        for (int r = 0; r < 4; ++r) {
            int m = m0 + wm * 16 + g4 * 4 + r;
            int dst = src_index(m);
            dstl[r] = dst;
            float s = 0.f, q = 0.f;
            #pragma unroll
            for (int ni = 0; ni < 4; ++ni) {
                int col = wn * 64 + ni * 16 + c16;
                float v = acc[ni][r] + bias[col] + resid[(size_t)dst * CH + col];
                acc[ni][r] = v;
                s += v; q += v * v;
            }
            psum[r] = s; psq[r] = q;
        }
        #pragma unroll
        for (int o = 1; o <= 8; o <<= 1)
            #pragma unroll
            for (int r = 0; r < 4; ++r) {
                psum[r] += __shfl_xor(psum[r], o);
                psq[r]  += __shfl_xor(psq[r], o);
            }
        if (c16 == 0) {
            #pragma unroll
            for (int r = 0; r < 4; ++r) {
                int rl = g4 * 4 + r;
                lnred[wn][wm][rl][0] = psum[r];
                lnred[wn][wm][rl][1] = psq[r];
            }
        }
        __syncthreads();
        float gl[4], bl[4];
        #pragma unroll
        for (int ni = 0; ni < 4; ++ni) {
            int col = wn * 64 + ni * 16 + c16;
            gl[ni] = lng[col]; bl[ni] = lnb[col];
        }
        #pragma unroll
        for (int r = 0; r < 4; ++r) {
            int rl = g4 * 4 + r;
            float s = lnred[0][wm][rl][0] + lnred[1][wm][rl][0];
            float q = lnred[0][wm][rl][1] + lnred[1][wm][rl][1];
            float mean = s * (1.f / CH);
            float var  = q * (1.f / CH) - mean * mean;
            float rstd = rsqrtf(var + LNEPS);
            int dst = dstl[r];
            #pragma unroll
            for (int ni = 0; ni < 4; ++ni) {
                int col = wn * 64 + ni * 16 + c16;
                float v = acc[ni][r];
                ((u16*)outp)[(size_t)dst * CH + col] = f2bf(v);
                ln_out[(size_t)dst * CH + col] = f2bf((v - mean) * rstd * gl[ni] + bl[ni]);
            }
        }
    } else {
        #pragma unroll
        for (int r = 0; r < 4; ++r) {
            int m = m0 + wm * 16 + g4 * 4 + r;
            #pragma unroll
            for (int ni = 0; ni < 4; ++ni) {
                int col = n0 + wn * 64 + ni * 16 + c16;
                float v = acc[ni][r] + bias[col] * (col < 128 ? QSCALE : 1.f);
                ((u16*)outp)[(size_t)m * Nn + col] = f2bf(v);
            }
        }
    }
}

// ---- fused MLP: out = fc2(gelu(fc1(A) + b1)) + b2 + resid, BM=64, 512 thr ----
// H never touches HBM: per 128-col chunk, fc1 -> gelu -> Hs LDS -> fc2 accumulate.
__global__ __launch_bounds__(512, 2) void mlp_fused(
    const u16* __restrict__ A, const u16* __restrict__ W1,
    const float* __restrict__ b1, const u16* __restrict__ W2,
    const float* __restrict__ b2, const u16* __restrict__ residb,
    float* __restrict__ outp)
{
    __shared__ u16 As[4][64][32];    // 16 KB  [kc][row][k32]
    __shared__ u16 Bs[4][128][32];   // 32 KB  (fc1 chunk wts, then fc2 chunk wts)
    __shared__ u16 Hs[4][64][40];    // 20 KB  [kc][row][k32 pad40]
    // total 68.5 KB -> 2 blocks/CU

    int tid = threadIdx.x, w = tid >> 6, l = tid & 63;
    int c16 = l & 15, g4 = l >> 4;
    int m0 = blockIdx.x * 64;
    int wm = w & 3, wn = w >> 2;

    // stage A tile (K=128)
    #pragma unroll
    for (int p = 0; p < 2; ++p) {
        int e = tid + p * 512, row = e >> 4, c8 = e & 15;
        u16x8 v = *(const u16x8*)&A[(size_t)(m0 + row) * 128 + c8 * 8];
        *(u16x8*)&As[c8 >> 2][row][(c8 & 3) * 8] = v;
    }

    f32x4 acc2[4] = {};
    for (int ch = 0; ch < 4; ++ch) {
        // stage fc1T rows [ch*128, +128)
        #pragma unroll
        for (int p = 0; p < 4; ++p) {
            int e = tid + p * 512, row = e >> 4, c8 = e & 15;
            u16x8 v = *(const u16x8*)&W1[(size_t)(ch * 128 + row) * 128 + c8 * 8];
            *(u16x8*)&Bs[c8 >> 2][row][(c8 & 3) * 8] = v;
        }
        __syncthreads();

        f32x4 hacc[4] = {};
        #pragma unroll
        for (int kc = 0; kc < 4; ++kc) {
            s16x8 af = __builtin_bit_cast(s16x8,
                *(const u16x8*)&As[kc][wm * 16 + c16][g4 * 8]);
            #pragma unroll
            for (int ni = 0; ni < 4; ++ni) {
                s16x8 bf = __builtin_bit_cast(s16x8,
                    *(const u16x8*)&Bs[kc][wn * 64 + ni * 16 + c16][g4 * 8]);
                hacc[ni] = mfma16(af, bf, hacc[ni]);
            }
        }
        // bias + exact gelu -> Hs (C-fragment scatter, row-major [row][k])
        #pragma unroll
        for (int r = 0; r < 4; ++r) {
            int row = wm * 16 + g4 * 4 + r;
            #pragma unroll
            for (int ni = 0; ni < 4; ++ni) {
                int col = wn * 64 + ni * 16 + c16;       // 0..127 within chunk
                float v = hacc[ni][r] + b1[ch * 128 + col];
                v = 0.5f * v * (1.f + erff(v * 0.70710678118654752f));
                Hs[col >> 5][row][col & 31] = f2bf(v);
            }
        }
        __syncthreads();   // Hs visible; Bs reads done -> safe to overwrite

        // stage fc2T k-slice [ch*128, +128) for all 128 outputs
        #pragma unroll
        for (int p = 0; p < 4; ++p) {
            int e = tid + p * 512, row = e >> 4, c8 = e & 15;
            u16x8 v = *(const u16x8*)&W2[(size_t)row * 512 + ch * 128 + c8 * 8];
            *(u16x8*)&Bs[c8 >> 2][row][(c8 & 3) * 8] = v;
        }
        __syncthreads();

        #pragma unroll
        for (int kc = 0; kc < 4; ++kc) {
            s16x8 af = __builtin_bit_cast(s16x8,
                *(const u16x8*)&Hs[kc][wm * 16 + c16][g4 * 8]);
            #pragma unroll
            for (int ni = 0; ni < 4; ++ni) {
                s16x8 bf = __builtin_bit_cast(s16x8,
                    *(const u16x8*)&Bs[kc][wn * 64 + ni * 16 + c16][g4 * 8]);
                acc2[ni] = mfma16(af, bf, acc2[ni]);
            }
        }
        __syncthreads();   // Hs/Bs reads done before next chunk overwrites
    }

    #pragma unroll
    for (int r = 0; r < 4; ++r) {
        int m = m0 + wm * 16 + g4 * 4 + r;
        #pragma unroll
        for (int ni = 0; ni < 4; ++ni) {
            int col = wn * 64 + ni * 16 + c16;
            float v = acc2[ni][r] + b2[col];
            outp[(size_t)m * CH + col] = v + bf2f(residb[(size_t)m * CH + col]);
        }
    }
}

// ---- bias+mask table, f32, MFMA C-fragment layout: [hw][t][nt=26][lane][r] ----
__global__ __launch_bounds__(64) void bias_k(
    const float* __restrict__ rpb, float* __restrict__ biasT2)
{
    int nt = blockIdx.x;   // 0..25 (col tile; 25 is all -100 pad)
    int t  = blockIdx.y;   // 0..24 (row tile)
    int hw = blockIdx.z;   // head*4 + wt
    int l  = threadIdx.x;  // 0..63
    int head = hw >> 2, wt = hw & 3;
    int bh7 = wt >> 1, bw7 = wt & 1;
    int j = nt * 16 + (l & 15);
    int rb = t * 16 + (l >> 4) * 4;
    f32x4 outv;
    #pragma unroll
    for (int r = 0; r < 4; ++r) {
        int i = rb + r; if (i > NTOK - 1) i = NTOK - 1;
        float v;
        if (j >= NTOK) v = -100.f;
        else {
            int di = i / 49, ri = i - di * 49, hi = ri / 7, wi = ri - hi * 7;
            int dj = j / 49, rj = j - dj * 49, hj = rj / 7, wj = rj - hj * 7;
            int bidx = (di - dj + 7) * 169 + (hi - hj + 6) * 13 + (wi - wj + 6);
            v = rpb[bidx * NHEADS + head];
            int regi = (bh7 ? (hi < 4 ? 1 : 2) : 0) * 3 + (bw7 ? (wi < 4 ? 1 : 2) : 0);
            int regj = (bh7 ? (hj < 4 ? 1 : 2) : 0) * 3 + (bw7 ? (wj < 4 ? 1 : 2) : 0);
            if (regi != regj) v -= 100.f;
        }
        outv[r] = v;
    }
    *(f32x4*)&biasT2[((((size_t)hw * 25 + t) * 26 + nt) << 8) + (l << 2)] = outv;
}

// ---- flash-strip MFMA attention, 8 waves/block, THREE-tile interleaved ----
__global__ __launch_bounds__(512, 4) void attn_mfma(
    const u16* __restrict__ Qb, const float* __restrict__ biasT2,
    u16* __restrict__ O)
{
    __shared__ u16 Vt[32][420];         // 26880 B, cols 400..415 zero
    __shared__ u16 Pst[8][3][16][40];   // 30720 B, per-wave 3 P strips

    int bid = blockIdx.x;
    int win = bid >> 2, head = bid & 3;
    int tid = threadIdx.x, w = tid >> 6, l = tid & 63;
    int c16 = l & 15, g4 = l >> 4;

    const size_t qbase = (size_t)win * NTOK * 384;
    for (int e = tid; e < 1600; e += 512) {
        int j = e >> 2, d0 = (e & 3) * 8;
        u16x8 vv = {0, 0, 0, 0, 0, 0, 0, 0};
        if (j < NTOK)
            vv = *(const u16x8*)&Qb[qbase + (size_t)j * 384 + 256 + head * 32 + d0];
        #pragma unroll
        for (int i = 0; i < 8; ++i) Vt[d0 + i][j] = vv[i];
    }
    if (tid < 32 * 16) Vt[tid >> 4][400 + (tid & 15)] = 0;
    __syncthreads();

    int wIdx = win & 63;
    int wt = (((wIdx >> 3) == 7) ? 2 : 0) + (((wIdx & 7) == 7) ? 1 : 0);
    const float* bt = biasT2 + (((size_t)(head * 4 + wt) * 25 * 26) << 8) + (l << 2);
    const u16* kroot = Qb + qbase + 128 + head * 32 + g4 * 8;
    u16 (*myPA)[40] = Pst[w][0];
    u16 (*myPB)[40] = Pst[w][1];
    u16 (*myPC)[40] = Pst[w][2];

    // ---- triple pass: tiles tA = w, tB = w+8, tC = w+16 (rows < 384) ----
    {
        int tA = w, tB = w + 8, tC = w + 16;
        s16x8 qfragA = __builtin_bit_cast(s16x8,
            *(const u16x8*)&Qb[qbase + (size_t)(tA * 16 + c16) * 384 + head * 32 + g4 * 8]);
        s16x8 qfragB = __builtin_bit_cast(s16x8,
            *(const u16x8*)&Qb[qbase + (size_t)(tB * 16 + c16) * 384 + head * 32 + g4 * 8]);
        s16x8 qfragC = __builtin_bit_cast(s16x8,
            *(const u16x8*)&Qb[qbase + (size_t)(tC * 16 + c16) * 384 + head * 32 + g4 * 8]);
        const float* bttA = bt + (((size_t)tA * 26) << 8);
        const float* bttB = bt + (((size_t)tB * 26) << 8);
        const float* bttC = bt + (((size_t)tC * 26) << 8);

        float l4A[4] = {0.f,0.f,0.f,0.f}, l4B[4] = {0.f,0.f,0.f,0.f}, l4C[4] = {0.f,0.f,0.f,0.f};
        f32x4 oaccA0 = {0.f,0.f,0.f,0.f}, oaccA1 = {0.f,0.f,0.f,0.f};
        f32x4 oaccB0 = {0.f,0.f,0.f,0.f}, oaccB1 = {0.f,0.f,0.f,0.f};
        f32x4 oaccC0 = {0.f,0.f,0.f,0.f}, oaccC1 = {0.f,0.f,0.f,0.f};

        for (int jb = 0; jb < 13; ++jb) {
            int kr0 = jb * 32 + c16;      if (kr0 > NTOK - 1) kr0 = NTOK - 1;
            int kr1 = jb * 32 + 16 + c16; if (kr1 > NTOK - 1) kr1 = NTOK - 1;
            s16x8 kf0 = __builtin_bit_cast(s16x8, *(const u16x8*)&kroot[(size_t)kr0 * 384]);
            s16x8 kf1 = __builtin_bit_cast(s16x8, *(const u16x8*)&kroot[(size_t)kr1 * 384]);
            f32x4 sA0 = mfma16(qfragA, kf0, *(const f32x4*)(bttA + (((size_t)(jb*2+0)) << 8)));
            f32x4 sA1 = mfma16(qfragA, kf1, *(const f32x4*)(bttA + (((size_t)(jb*2+1)) << 8)));
            f32x4 sB0 = mfma16(qfragB, kf0, *(const f32x4*)(bttB + (((size_t)(jb*2+0)) << 8)));
            f32x4 sB1 = mfma16(qfragB, kf1, *(const f32x4*)(bttB + (((size_t)(jb*2+1)) << 8)));
            f32x4 sC0 = mfma16(qfragC, kf0, *(const f32x4*)(bttC + (((size_t)(jb*2+0)) << 8)));
            f32x4 sC1 = mfma16(qfragC, kf1, *(const f32x4*)(bttC + (((size_t)(jb*2+1)) << 8)));
            #pragma unroll
            for (int r = 0; r < 4; ++r) {
                float p0 = exp2f(sA0[r] * 1.44269504f);
                float p1 = exp2f(sA1[r] * 1.44269504f);
                l4A[r] += p0 + p1;
                myPA[g4 * 4 + r][c16]      = f2bf(p0);
                myPA[g4 * 4 + r][16 + c16] = f2bf(p1);
            }
            #pragma unroll
            for (int r = 0; r < 4; ++r) {
                float p0 = exp2f(sB0[r] * 1.44269504f);
                float p1 = exp2f(sB1[r] * 1.44269504f);
                l4B[r] += p0 + p1;
                myPB[g4 * 4 + r][c16]      = f2bf(p0);
                myPB[g4 * 4 + r][16 + c16] = f2bf(p1);
            }
            #pragma unroll
            for (int r = 0; r < 4; ++r) {
                float p0 = exp2f(sC0[r] * 1.44269504f);
                float p1 = exp2f(sC1[r] * 1.44269504f);
                l4C[r] += p0 + p1;
                myPC[g4 * 4 + r][c16]      = f2bf(p0);
                myPC[g4 * 4 + r][16 + c16] = f2bf(p1);
            }
            s16x8 paA = __builtin_bit_cast(s16x8, *(const u16x8*)&myPA[c16][g4 * 8]);
            s16x8 paB = __builtin_bit_cast(s16x8, *(const u16x8*)&myPB[c16][g4 * 8]);
            s16x8 paC = __builtin_bit_cast(s16x8, *(const u16x8*)&myPC[c16][g4 * 8]);
            s16x8 vb0 = __builtin_bit_cast(s16x8, *(const u16x8*)&Vt[c16][jb * 32 + g4 * 8]);
            s16x8 vb1 = __builtin_bit_cast(s16x8, *(const u16x8*)&Vt[16 + c16][jb * 32 + g4 * 8]);
            oaccA0 = mfma16(paA, vb0, oaccA0);
            oaccA1 = mfma16(paA, vb1, oaccA1);
            oaccB0 = mfma16(paB, vb0, oaccB0);
            oaccB1 = mfma16(paB, vb1, oaccB1);
            oaccC0 = mfma16(paC, vb0, oaccC0);
            oaccC1 = mfma16(paC, vb1, oaccC1);
        }

        #pragma unroll
        for (int r = 0; r < 4; ++r) {
            #pragma unroll
            for (int o = 1; o <= 8; o <<= 1) {
                l4A[r] += __shfl_xor(l4A[r], o);
                l4B[r] += __shfl_xor(l4B[r], o);
                l4C[r] += __shfl_xor(l4C[r], o);
            }
            l4A[r] = 1.f / l4A[r];
            l4B[r] = 1.f / l4B[r];
            l4C[r] = 1.f / l4C[r];
        }
        #pragma unroll
        for (int r = 0; r < 4; ++r) {
            int qA = tA * 16 + g4 * 4 + r;
            int qB = tB * 16 + g4 * 4 + r;
            int qC = tC * 16 + g4 * 4 + r;
            size_t oA = ((size_t)(win * NTOK + qA)) * CH + head * 32 + c16;
            size_t oB = ((size_t)(win * NTOK + qB)) * CH + head * 32 + c16;
            size_t oC = ((size_t)(win * NTOK + qC)) * CH + head * 32 + c16;
            O[oA]      = f2bf(oaccA0[r] * l4A[r]);
            O[oA + 16] = f2bf(oaccA1[r] * l4A[r]);
            O[oB]      = f2bf(oaccB0[r] * l4B[r]);
            O[oB + 16] = f2bf(oaccB1[r] * l4B[r]);
            O[oC]      = f2bf(oaccC0[r] * l4C[r]);
            O[oC + 16] = f2bf(oaccC1[r] * l4C[r]);
        }
    }

    // ---- solo pass: t = 24 on wave 0 only ----
    if (w == 0) {
        int t = 24;
        int row0 = t * 16;
        int qr = row0 + c16; if (qr > NTOK - 1) qr = NTOK - 1;
        s16x8 afrag = __builtin_bit_cast(s16x8,
            *(const u16x8*)&Qb[qbase + (size_t)qr * 384 + head * 32 + g4 * 8]);
        const float* btt = bt + (((size_t)t * 26) << 8);

        float l4[4] = {0.f, 0.f, 0.f, 0.f};
        f32x4 oacc[2] = {{0.f,0.f,0.f,0.f},{0.f,0.f,0.f,0.f}};

        for (int jb = 0; jb < 13; ++jb) {
            f32x4 s[2];
            #pragma unroll
            for (int kk = 0; kk < 2; ++kk) {
                f32x4 cb = *(const f32x4*)(btt + (((size_t)(jb * 2 + kk)) << 8));
                int kr = jb * 32 + kk * 16 + c16;
                if (kr > NTOK - 1) kr = NTOK - 1;
                s16x8 bfrag = __builtin_bit_cast(s16x8,
                    *(const u16x8*)&kroot[(size_t)kr * 384]);
                s[kk] = mfma16(afrag, bfrag, cb);
            }
            #pragma unroll
            for (int kk = 0; kk < 2; ++kk)
                #pragma unroll
                for (int r = 0; r < 4; ++r) {
                    float p = exp2f(s[kk][r] * 1.44269504f);
                    l4[r] += p;
                    myPA[g4 * 4 + r][kk * 16 + c16] = f2bf(p);
                }
            s16x8 pa = __builtin_bit_cast(s16x8, *(const u16x8*)&myPA[c16][g4 * 8]);
            #pragma unroll
            for (int nd = 0; nd < 2; ++nd) {
                s16x8 vb = __builtin_bit_cast(s16x8,
                    *(const u16x8*)&Vt[nd * 16 + c16][jb * 32 + g4 * 8]);
                oacc[nd] = mfma16(pa, vb, oacc[nd]);
            }
        }

        #pragma unroll
        for (int r = 0; r < 4; ++r) {
            #pragma unroll
            for (int o = 1; o <= 8; o <<= 1)
                l4[r] += __shfl_xor(l4[r], o);
            l4[r] = 1.f / l4[r];
        }
        #pragma unroll
        for (int nd = 0; nd < 2; ++nd)
            #pragma unroll
            for (int r = 0; r < 4; ++r) {
                int qrow = row0 + g4 * 4 + r;
                if (qrow < NTOK)
                    O[((size_t)(win * NTOK + qrow)) * CH + head * 32 + nd * 16 + c16]
                        = f2bf(oacc[nd][r] * l4[r]);
            }
    }
}

extern "C" void kernel_launch(void* const* d_in, const int* in_sizes, int n_in,
                              void* d_out, int out_size, void* d_ws, size_t ws_size,
                              hipStream_t stream) {
    const float* x      = (const float*)d_in[0];
    const float* n1g    = (const float*)d_in[1];
    const float* n1b    = (const float*)d_in[2];
    const float* qkv_w  = (const float*)d_in[3];
    const float* qkv_b  = (const float*)d_in[4];
    const float* proj_w = (const float*)d_in[5];
    const float* proj_b = (const float*)d_in[6];
    const float* rpb    = (const float*)d_in[7];
    const float* n2g    = (const float*)d_in[8];
    const float* n2b    = (const float*)d_in[9];
    const float* fc1_w  = (const float*)d_in[10];
    const float* fc1_b  = (const float*)d_in[11];
    const float* fc2_w  = (const float*)d_in[12];
    const float* fc2_b  = (const float*)d_in[13];
    float* out = (float*)d_out;

    char* ws = (char*)d_ws;
    size_t off = 0;
    u16* A_bf  = (u16*)(ws + off);  off += (size_t)TOK * 128 * 2;
    u16* Qb_bf = (u16*)(ws + off);  off += (size_t)TOK * 384 * 2;
    u16* O_bf  = (u16*)(ws + off);  off += (size_t)TOK * 128 * 2;
    u16* R_bf  = (u16*)(ws + off);  off += (size_t)TOK * 128 * 2;   // bf16 residual trunk
    u16* qkvT  = (u16*)(ws + off);  off += 384 * 128 * 2;
    u16* projT = (u16*)(ws + off);  off += 128 * 128 * 2;
    u16* fc1T  = (u16*)(ws + off);  off += 512 * 128 * 2;
    u16* fc2T  = (u16*)(ws + off);  off += 128 * 512 * 2;
    float* biasT2 = (float*)A_bf;   // overlay; A_bf dead after qkv GEMM,
                                    // rewritten by proj's fused LN2

    // 0. weight transposes (+bf16), QSCALE folded into Wq
    hipLaunchKernelGGL(convT, dim3(384/32, 128/32), dim3(256), 0, stream, qkv_w,  qkvT, 128, 384, 128);
    hipLaunchKernelGGL(convT, dim3(128/32, 128/32), dim3(256), 0, stream, proj_w, projT, 128, 128, 0);
    hipLaunchKernelGGL(convT, dim3(512/32, 128/32), dim3(256), 0, stream, fc1_w,  fc1T, 128, 512, 0);
    hipLaunchKernelGGL(convT, dim3(128/32, 512/32), dim3(256), 0, stream, fc2_w,  fc2T, 512, 128, 0);
    // 1. LN1 + shift + window_partition -> bf16
    hipLaunchKernelGGL(ln_kernel, dim3(TOK), dim3(128), 0, stream, x, n1g, n1b, A_bf);
    // 2. qkv GEMM -> bf16
    hipLaunchKernelGGL((gemm_mfma<1, 128>), dim3(3, TOK/64), dim3(512), 0, stream,
                       A_bf, qkvT, qkv_b, Qb_bf, 384, nullptr, nullptr, nullptr, nullptr);
    // 2b. bias+mask table (A_bf dead; overlay)
    hipLaunchKernelGGL(bias_k, dim3(26, 25, 16), dim3(64), 0, stream, rpb, biasT2);
    // 3. three-tile interleaved flash attention -> bf16
    hipLaunchKernelGGL(attn_mfma, dim3(NWIN * NHEADS), dim3(512), 0, stream,
                       Qb_bf, biasT2, O_bf);
    // 4. proj GEMM + unshift + residual -> bf16 R, fused LN2 -> bf16 A_bf
    hipLaunchKernelGGL((gemm_mfma<2, 128>), dim3(1, TOK/64), dim3(512), 0, stream,
                       O_bf, projT, proj_b, R_bf, 128, x, n2g, n2b, A_bf);
    // 5+6. fused MLP: fc1 + GELU + fc2 + residual -> f32 out (H stays in LDS)
    hipLaunchKernelGGL(mlp_fused, dim3(TOK/64), dim3(512), 0, stream,
                       A_bf, fc1T, fc1_b, fc2T, fc2_b, R_bf, out);
}

// Round 16
// 150.290 us; speedup vs baseline: 1.5247x; 1.0841x over previous
//
#include <hip/hip_runtime.h>
#include <math.h>

// ---- problem constants ----
#define TOK    50176      // 2*8*56*56 tokens
#define CH     128
#define NWIN   128        // B * 64 windows
#define NTOK   392        // 8*7*7 tokens per window
#define NHEADS 4
#define QSCALE 0.17677669529663687f   // 32^-0.5
#define LNEPS  1e-3f

typedef unsigned short u16;
typedef unsigned int   u32;
typedef u16   u16x4  __attribute__((ext_vector_type(4)));
typedef u16   u16x8  __attribute__((ext_vector_type(8)));
typedef short s16x8  __attribute__((ext_vector_type(8)));
typedef float f32x4  __attribute__((ext_vector_type(4)));

__device__ __forceinline__ float bf2f(u16 u) {
    return __uint_as_float(((u32)u) << 16);
}
__device__ __forceinline__ u16 f2bf(float f) {
    u32 u = __float_as_uint(f);
    return (u16)((u + 0x7fffu + ((u >> 16) & 1u)) >> 16);
}
__device__ __forceinline__ f32x4 mfma16(s16x8 a, s16x8 b, f32x4 c) {
    return __builtin_amdgcn_mfma_f32_16x16x32_bf16(a, b, c, 0, 0, 0);
}

// token m in window layout -> flat token index in original layout (+3 roll)
__device__ __forceinline__ int src_index(int m) {
    int b = m / NTOK, t = m - b * NTOK;
    int batch = b >> 6, wIdx = b & 63;
    int bh = wIdx >> 3, bw = wIdx & 7;
    int d = t / 49, rem = t - d * 49;
    int h7 = rem / 7, w7 = rem - h7 * 7;
    int h = bh * 7 + h7 + 3; if (h >= 56) h -= 56;
    int w = bw * 7 + w7 + 3; if (w >= 56) w -= 56;
    return ((batch * 8 + d) * 56 + h) * 56 + w;
}

// ---- weight transpose + f32->bf16 convert: dst[n][k] = src[k][n] * sc ----
__global__ __launch_bounds__(256) void convT(
    const float* __restrict__ src, u16* __restrict__ dst,
    int K, int N, int scaleN)
{
    __shared__ float t[32][33];
    int n0 = blockIdx.x * 32, k0 = blockIdx.y * 32;
    int tx = threadIdx.x & 31, ty = threadIdx.x >> 5;   // ty 0..7
    #pragma unroll
    for (int r = 0; r < 4; ++r)
        t[ty + r * 8][tx] = src[(size_t)(k0 + ty + r * 8) * N + n0 + tx];
    __syncthreads();
    #pragma unroll
    for (int r = 0; r < 4; ++r) {
        int n = n0 + ty + r * 8;
        float sc = (n < scaleN) ? QSCALE : 1.f;
        dst[(size_t)n * K + k0 + tx] = f2bf(t[tx][ty + r * 8] * sc);
    }
}

// ---- MFMA GEMM, BM=64 x BN=128, 512 threads (8 waves = 4m x 2n), K=128 ----
// EPI 1: FUSED LN1 (x gather via src_index -> LN -> As) + qkv -> bf16
// EPI 2: proj + residual scatter -> bf16 R + fused LN2 -> bf16 ln_out
template<int EPI>
__global__ __launch_bounds__(512, 6) void gemm_mfma(
    const u16* __restrict__ A, const u16* __restrict__ W,
    const float* __restrict__ bias, void* __restrict__ outp,
    int Nn, const float* __restrict__ resid,
    const float* __restrict__ lng, const float* __restrict__ lnb,
    u16* __restrict__ ln_out)
{
    __shared__ u16 As[4][64][32];        // 16 KB  [kc][row][k32]
    __shared__ u16 Bs[4][128][32];       // 32 KB
    __shared__ float lnred[2][4][16][2]; // 1 KB

    int tid = threadIdx.x, w = tid >> 6, l = tid & 63;
    int c16 = l & 15, g4 = l >> 4;
    int m0 = blockIdx.y * 64, n0 = blockIdx.x * 128;
    int wm = w & 3, wn = w >> 2;

    // ---- stage A tile ----
    if (EPI == 1) {
        // fused LN1: gather x rows (src_index), row-LN in 16-lane groups
        #pragma unroll
        for (int p = 0; p < 2; ++p) {
            int e = tid + p * 512, row = e >> 4, c8 = e & 15;
            int src = src_index(m0 + row);
            f32x4 x0 = *(const f32x4*)&resid[(size_t)src * CH + c8 * 8];
            f32x4 x1 = *(const f32x4*)&resid[(size_t)src * CH + c8 * 8 + 4];
            float s = ((x0[0] + x0[1]) + (x0[2] + x0[3]))
                    + ((x1[0] + x1[1]) + (x1[2] + x1[3]));
            float q = ((x0[0]*x0[0] + x0[1]*x0[1]) + (x0[2]*x0[2] + x0[3]*x0[3]))
                    + ((x1[0]*x1[0] + x1[1]*x1[1]) + (x1[2]*x1[2] + x1[3]*x1[3]));
            #pragma unroll
            for (int o = 1; o <= 8; o <<= 1) {
                s += __shfl_xor(s, o);
                q += __shfl_xor(q, o);
            }
            float mean = s * (1.f / CH);
            float var  = q * (1.f / CH) - mean * mean;
            float rstd = rsqrtf(var + LNEPS);
            u16x8 av;
            #pragma unroll
            for (int i = 0; i < 4; ++i)
                av[i] = f2bf((x0[i] - mean) * rstd * lng[c8 * 8 + i] + lnb[c8 * 8 + i]);
            #pragma unroll
            for (int i = 0; i < 4; ++i)
                av[4 + i] = f2bf((x1[i] - mean) * rstd * lng[c8 * 8 + 4 + i] + lnb[c8 * 8 + 4 + i]);
            *(u16x8*)&As[c8 >> 2][row][(c8 & 3) * 8] = av;
        }
    } else {
        #pragma unroll
        for (int p = 0; p < 2; ++p) {
            int e = tid + p * 512, row = e >> 4, c8 = e & 15;
            u16x8 v = *(const u16x8*)&A[(size_t)(m0 + row) * 128 + c8 * 8];
            *(u16x8*)&As[c8 >> 2][row][(c8 & 3) * 8] = v;
        }
    }
    // ---- stage B tile ----
    #pragma unroll
    for (int p = 0; p < 4; ++p) {
        int e = tid + p * 512, row = e >> 4, c8 = e & 15;
        u16x8 v = *(const u16x8*)&W[(size_t)(n0 + row) * 128 + c8 * 8];
        *(u16x8*)&Bs[c8 >> 2][row][(c8 & 3) * 8] = v;
    }
    __syncthreads();

    f32x4 acc[4] = {};
    #pragma unroll
    for (int kc = 0; kc < 4; ++kc) {
        s16x8 af = __builtin_bit_cast(s16x8,
            *(const u16x8*)&As[kc][wm * 16 + c16][g4 * 8]);
        #pragma unroll
        for (int ni = 0; ni < 4; ++ni) {
            s16x8 bf = __builtin_bit_cast(s16x8,
                *(const u16x8*)&Bs[kc][wn * 64 + ni * 16 + c16][g4 * 8]);
            acc[ni] = mfma16(af, bf, acc[ni]);
        }
    }

    if (EPI == 2) {
        float psum[4], psq[4];
        int dstl[4];
        #pragma unroll
        for (int r = 0; r < 4; ++r) {
            int m = m0 + wm * 16 + g4 * 4 + r;
            int dst = src_index(m);
            dstl[r] = dst;
            float s = 0.f, q = 0.f;
            #pragma unroll
            for (int ni = 0; ni < 4; ++ni) {
                int col = wn * 64 + ni * 16 + c16;
                float v = acc[ni][r] + bias[col] + resid[(size_t)dst * CH + col];
                acc[ni][r] = v;
                s += v; q += v * v;
            }
            psum[r] = s; psq[r] = q;
        }
        #pragma unroll
        for (int o = 1; o <= 8; o <<= 1)
            #pragma unroll
            for (int r = 0; r < 4; ++r) {
                psum[r] += __shfl_xor(psum[r], o);
                psq[r]  += __shfl_xor(psq[r], o);
            }
        if (c16 == 0) {
            #pragma unroll
            for (int r = 0; r < 4; ++r) {
                int rl = g4 * 4 + r;
                lnred[wn][wm][rl][0] = psum[r];
                lnred[wn][wm][rl][1] = psq[r];
            }
        }
        __syncthreads();
        float gl[4], bl[4];
        #pragma unroll
        for (int ni = 0; ni < 4; ++ni) {
            int col = wn * 64 + ni * 16 + c16;
            gl[ni] = lng[col]; bl[ni] = lnb[col];
        }
        #pragma unroll
        for (int r = 0; r < 4; ++r) {
            int rl = g4 * 4 + r;
            float s = lnred[0][wm][rl][0] + lnred[1][wm][rl][0];
            float q = lnred[0][wm][rl][1] + lnred[1][wm][rl][1];
            float mean = s * (1.f / CH);
            float var  = q * (1.f / CH) - mean * mean;
            float rstd = rsqrtf(var + LNEPS);
            int dst = dstl[r];
            #pragma unroll
            for (int ni = 0; ni < 4; ++ni) {
                int col = wn * 64 + ni * 16 + c16;
                float v = acc[ni][r];
                ((u16*)outp)[(size_t)dst * CH + col] = f2bf(v);
                ln_out[(size_t)dst * CH + col] = f2bf((v - mean) * rstd * gl[ni] + bl[ni]);
            }
        }
    } else {
        #pragma unroll
        for (int r = 0; r < 4; ++r) {
            int m = m0 + wm * 16 + g4 * 4 + r;
            #pragma unroll
            for (int ni = 0; ni < 4; ++ni) {
                int col = n0 + wn * 64 + ni * 16 + c16;
                float v = acc[ni][r] + bias[col] * (col < 128 ? QSCALE : 1.f);
                ((u16*)outp)[(size_t)m * Nn + col] = f2bf(v);
            }
        }
    }
}

// ---- fused MLP: out = fc2(gelu(fc1(A) + b1)) + b2 + resid, BM=64, 512 thr ----
__global__ __launch_bounds__(512, 2) void mlp_fused(
    const u16* __restrict__ A, const u16* __restrict__ W1,
    const float* __restrict__ b1, const u16* __restrict__ W2,
    const float* __restrict__ b2, const u16* __restrict__ residb,
    float* __restrict__ outp)
{
    __shared__ u16 As[4][64][32];    // 16 KB
    __shared__ u16 Bs[4][128][32];   // 32 KB
    __shared__ u16 Hs[4][64][40];    // 20 KB
    // total 68.5 KB -> 2 blocks/CU

    int tid = threadIdx.x, w = tid >> 6, l = tid & 63;
    int c16 = l & 15, g4 = l >> 4;
    int m0 = blockIdx.x * 64;
    int wm = w & 3, wn = w >> 2;

    #pragma unroll
    for (int p = 0; p < 2; ++p) {
        int e = tid + p * 512, row = e >> 4, c8 = e & 15;
        u16x8 v = *(const u16x8*)&A[(size_t)(m0 + row) * 128 + c8 * 8];
        *(u16x8*)&As[c8 >> 2][row][(c8 & 3) * 8] = v;
    }

    f32x4 acc2[4] = {};
    for (int ch = 0; ch < 4; ++ch) {
        #pragma unroll
        for (int p = 0; p < 4; ++p) {
            int e = tid + p * 512, row = e >> 4, c8 = e & 15;
            u16x8 v = *(const u16x8*)&W1[(size_t)(ch * 128 + row) * 128 + c8 * 8];
            *(u16x8*)&Bs[c8 >> 2][row][(c8 & 3) * 8] = v;
        }
        __syncthreads();

        f32x4 hacc[4] = {};
        #pragma unroll
        for (int kc = 0; kc < 4; ++kc) {
            s16x8 af = __builtin_bit_cast(s16x8,
                *(const u16x8*)&As[kc][wm * 16 + c16][g4 * 8]);
            #pragma unroll
            for (int ni = 0; ni < 4; ++ni) {
                s16x8 bf = __builtin_bit_cast(s16x8,
                    *(const u16x8*)&Bs[kc][wn * 64 + ni * 16 + c16][g4 * 8]);
                hacc[ni] = mfma16(af, bf, hacc[ni]);
            }
        }
        #pragma unroll
        for (int r = 0; r < 4; ++r) {
            int row = wm * 16 + g4 * 4 + r;
            #pragma unroll
            for (int ni = 0; ni < 4; ++ni) {
                int col = wn * 64 + ni * 16 + c16;
                float v = hacc[ni][r] + b1[ch * 128 + col];
                v = 0.5f * v * (1.f + erff(v * 0.70710678118654752f));
                Hs[col >> 5][row][col & 31] = f2bf(v);
            }
        }
        __syncthreads();

        #pragma unroll
        for (int p = 0; p < 4; ++p) {
            int e = tid + p * 512, row = e >> 4, c8 = e & 15;
            u16x8 v = *(const u16x8*)&W2[(size_t)row * 512 + ch * 128 + c8 * 8];
            *(u16x8*)&Bs[c8 >> 2][row][(c8 & 3) * 8] = v;
        }
        __syncthreads();

        #pragma unroll
        for (int kc = 0; kc < 4; ++kc) {
            s16x8 af = __builtin_bit_cast(s16x8,
                *(const u16x8*)&Hs[kc][wm * 16 + c16][g4 * 8]);
            #pragma unroll
            for (int ni = 0; ni < 4; ++ni) {
                s16x8 bf = __builtin_bit_cast(s16x8,
                    *(const u16x8*)&Bs[kc][wn * 64 + ni * 16 + c16][g4 * 8]);
                acc2[ni] = mfma16(af, bf, acc2[ni]);
            }
        }
        __syncthreads();
    }

    #pragma unroll
    for (int r = 0; r < 4; ++r) {
        int m = m0 + wm * 16 + g4 * 4 + r;
        #pragma unroll
        for (int ni = 0; ni < 4; ++ni) {
            int col = wn * 64 + ni * 16 + c16;
            float v = acc2[ni][r] + b2[col];
            outp[(size_t)m * CH + col] = v + bf2f(residb[(size_t)m * CH + col]);
        }
    }
}

// ---- bias+mask table, f32, MFMA C-fragment layout: [hw][t][nt=26][lane][r] ----
__global__ __launch_bounds__(64) void bias_k(
    const float* __restrict__ rpb, float* __restrict__ biasT2)
{
    int nt = blockIdx.x;   // 0..25 (col tile; 25 is all -100 pad)
    int t  = blockIdx.y;   // 0..24 (row tile)
    int hw = blockIdx.z;   // head*4 + wt
    int l  = threadIdx.x;  // 0..63
    int head = hw >> 2, wt = hw & 3;
    int bh7 = wt >> 1, bw7 = wt & 1;
    int j = nt * 16 + (l & 15);
    int rb = t * 16 + (l >> 4) * 4;
    f32x4 outv;
    #pragma unroll
    for (int r = 0; r < 4; ++r) {
        int i = rb + r; if (i > NTOK - 1) i = NTOK - 1;
        float v;
        if (j >= NTOK) v = -100.f;
        else {
            int di = i / 49, ri = i - di * 49, hi = ri / 7, wi = ri - hi * 7;
            int dj = j / 49, rj = j - dj * 49, hj = rj / 7, wj = rj - hj * 7;
            int bidx = (di - dj + 7) * 169 + (hi - hj + 6) * 13 + (wi - wj + 6);
            v = rpb[bidx * NHEADS + head];
            int regi = (bh7 ? (hi < 4 ? 1 : 2) : 0) * 3 + (bw7 ? (wi < 4 ? 1 : 2) : 0);
            int regj = (bh7 ? (hj < 4 ? 1 : 2) : 0) * 3 + (bw7 ? (wj < 4 ? 1 : 2) : 0);
            if (regi != regj) v -= 100.f;
        }
        outv[r] = v;
    }
    *(f32x4*)&biasT2[((((size_t)hw * 25 + t) * 26 + nt) << 8) + (l << 2)] = outv;
}

// ---- flash-strip MFMA attention, 8 waves/block, THREE-tile interleaved ----
__global__ __launch_bounds__(512, 4) void attn_mfma(
    const u16* __restrict__ Qb, const float* __restrict__ biasT2,
    u16* __restrict__ O)
{
    __shared__ u16 Vt[32][420];         // 26880 B, cols 400..415 zero
    __shared__ u16 Pst[8][3][16][40];   // 30720 B, per-wave 3 P strips

    int bid = blockIdx.x;
    int win = bid >> 2, head = bid & 3;
    int tid = threadIdx.x, w = tid >> 6, l = tid & 63;
    int c16 = l & 15, g4 = l >> 4;

    const size_t qbase = (size_t)win * NTOK * 384;
    for (int e = tid; e < 1600; e += 512) {
        int j = e >> 2, d0 = (e & 3) * 8;
        u16x8 vv = {0, 0, 0, 0, 0, 0, 0, 0};
        if (j < NTOK)
            vv = *(const u16x8*)&Qb[qbase + (size_t)j * 384 + 256 + head * 32 + d0];
        #pragma unroll
        for (int i = 0; i < 8; ++i) Vt[d0 + i][j] = vv[i];
    }
    if (tid < 32 * 16) Vt[tid >> 4][400 + (tid & 15)] = 0;
    __syncthreads();

    int wIdx = win & 63;
    int wt = (((wIdx >> 3) == 7) ? 2 : 0) + (((wIdx & 7) == 7) ? 1 : 0);
    const float* bt = biasT2 + (((size_t)(head * 4 + wt) * 25 * 26) << 8) + (l << 2);
    const u16* kroot = Qb + qbase + 128 + head * 32 + g4 * 8;
    u16 (*myPA)[40] = Pst[w][0];
    u16 (*myPB)[40] = Pst[w][1];
    u16 (*myPC)[40] = Pst[w][2];

    // ---- triple pass: tiles tA = w, tB = w+8, tC = w+16 (rows < 384) ----
    {
        int tA = w, tB = w + 8, tC = w + 16;
        s16x8 qfragA = __builtin_bit_cast(s16x8,
            *(const u16x8*)&Qb[qbase + (size_t)(tA * 16 + c16) * 384 + head * 32 + g4 * 8]);
        s16x8 qfragB = __builtin_bit_cast(s16x8,
            *(const u16x8*)&Qb[qbase + (size_t)(tB * 16 + c16) * 384 + head * 32 + g4 * 8]);
        s16x8 qfragC = __builtin_bit_cast(s16x8,
            *(const u16x8*)&Qb[qbase + (size_t)(tC * 16 + c16) * 384 + head * 32 + g4 * 8]);
        const float* bttA = bt + (((size_t)tA * 26) << 8);
        const float* bttB = bt + (((size_t)tB * 26) << 8);
        const float* bttC = bt + (((size_t)tC * 26) << 8);

        float l4A[4] = {0.f,0.f,0.f,0.f}, l4B[4] = {0.f,0.f,0.f,0.f}, l4C[4] = {0.f,0.f,0.f,0.f};
        f32x4 oaccA0 = {0.f,0.f,0.f,0.f}, oaccA1 = {0.f,0.f,0.f,0.f};
        f32x4 oaccB0 = {0.f,0.f,0.f,0.f}, oaccB1 = {0.f,0.f,0.f,0.f};
        f32x4 oaccC0 = {0.f,0.f,0.f,0.f}, oaccC1 = {0.f,0.f,0.f,0.f};

        for (int jb = 0; jb < 13; ++jb) {
            int kr0 = jb * 32 + c16;      if (kr0 > NTOK - 1) kr0 = NTOK - 1;
            int kr1 = jb * 32 + 16 + c16; if (kr1 > NTOK - 1) kr1 = NTOK - 1;
            s16x8 kf0 = __builtin_bit_cast(s16x8, *(const u16x8*)&kroot[(size_t)kr0 * 384]);
            s16x8 kf1 = __builtin_bit_cast(s16x8, *(const u16x8*)&kroot[(size_t)kr1 * 384]);
            f32x4 sA0 = mfma16(qfragA, kf0, *(const f32x4*)(bttA + (((size_t)(jb*2+0)) << 8)));
            f32x4 sA1 = mfma16(qfragA, kf1, *(const f32x4*)(bttA + (((size_t)(jb*2+1)) << 8)));
            f32x4 sB0 = mfma16(qfragB, kf0, *(const f32x4*)(bttB + (((size_t)(jb*2+0)) << 8)));
            f32x4 sB1 = mfma16(qfragB, kf1, *(const f32x4*)(bttB + (((size_t)(jb*2+1)) << 8)));
            f32x4 sC0 = mfma16(qfragC, kf0, *(const f32x4*)(bttC + (((size_t)(jb*2+0)) << 8)));
            f32x4 sC1 = mfma16(qfragC, kf1, *(const f32x4*)(bttC + (((size_t)(jb*2+1)) << 8)));
            #pragma unroll
            for (int r = 0; r < 4; ++r) {
                float p0 = exp2f(sA0[r] * 1.44269504f);
                float p1 = exp2f(sA1[r] * 1.44269504f);
                l4A[r] += p0 + p1;
                myPA[g4 * 4 + r][c16]      = f2bf(p0);
                myPA[g4 * 4 + r][16 + c16] = f2bf(p1);
            }
            #pragma unroll
            for (int r = 0; r < 4; ++r) {
                float p0 = exp2f(sB0[r] * 1.44269504f);
                float p1 = exp2f(sB1[r] * 1.44269504f);
                l4B[r] += p0 + p1;
                myPB[g4 * 4 + r][c16]      = f2bf(p0);
                myPB[g4 * 4 + r][16 + c16] = f2bf(p1);
            }
            #pragma unroll
            for (int r = 0; r < 4; ++r) {
                float p0 = exp2f(sC0[r] * 1.44269504f);
                float p1 = exp2f(sC1[r] * 1.44269504f);
                l4C[r] += p0 + p1;
                myPC[g4 * 4 + r][c16]      = f2bf(p0);
                myPC[g4 * 4 + r][16 + c16] = f2bf(p1);
            }
            s16x8 paA = __builtin_bit_cast(s16x8, *(const u16x8*)&myPA[c16][g4 * 8]);
            s16x8 paB = __builtin_bit_cast(s16x8, *(const u16x8*)&myPB[c16][g4 * 8]);
            s16x8 paC = __builtin_bit_cast(s16x8, *(const u16x8*)&myPC[c16][g4 * 8]);
            s16x8 vb0 = __builtin_bit_cast(s16x8, *(const u16x8*)&Vt[c16][jb * 32 + g4 * 8]);
            s16x8 vb1 = __builtin_bit_cast(s16x8, *(const u16x8*)&Vt[16 + c16][jb * 32 + g4 * 8]);
            oaccA0 = mfma16(paA, vb0, oaccA0);
            oaccA1 = mfma16(paA, vb1, oaccA1);
            oaccB0 = mfma16(paB, vb0, oaccB0);
            oaccB1 = mfma16(paB, vb1, oaccB1);
            oaccC0 = mfma16(paC, vb0, oaccC0);
            oaccC1 = mfma16(paC, vb1, oaccC1);
        }

        #pragma unroll
        for (int r = 0; r < 4; ++r) {
            #pragma unroll
            for (int o = 1; o <= 8; o <<= 1) {
                l4A[r] += __shfl_xor(l4A[r], o);
                l4B[r] += __shfl_xor(l4B[r], o);
                l4C[r] += __shfl_xor(l4C[r], o);
            }
            l4A[r] = 1.f / l4A[r];
            l4B[r] = 1.f / l4B[r];
            l4C[r] = 1.f / l4C[r];
        }
        #pragma unroll
        for (int r = 0; r < 4; ++r) {
            int qA = tA * 16 + g4 * 4 + r;
            int qB = tB * 16 + g4 * 4 + r;
            int qC = tC * 16 + g4 * 4 + r;
            size_t oA = ((size_t)(win * NTOK + qA)) * CH + head * 32 + c16;
            size_t oB = ((size_t)(win * NTOK + qB)) * CH + head * 32 + c16;
            size_t oC = ((size_t)(win * NTOK + qC)) * CH + head * 32 + c16;
            O[oA]      = f2bf(oaccA0[r] * l4A[r]);
            O[oA + 16] = f2bf(oaccA1[r] * l4A[r]);
            O[oB]      = f2bf(oaccB0[r] * l4B[r]);
            O[oB + 16] = f2bf(oaccB1[r] * l4B[r]);
            O[oC]      = f2bf(oaccC0[r] * l4C[r]);
            O[oC + 16] = f2bf(oaccC1[r] * l4C[r]);
        }
    }

    // ---- solo pass: t = 24 on wave 0 only ----
    if (w == 0) {
        int t = 24;
        int row0 = t * 16;
        int qr = row0 + c16; if (qr > NTOK - 1) qr = NTOK - 1;
        s16x8 afrag = __builtin_bit_cast(s16x8,
            *(const u16x8*)&Qb[qbase + (size_t)qr * 384 + head * 32 + g4 * 8]);
        const float* btt = bt + (((size_t)t * 26) << 8);

        float l4[4] = {0.f, 0.f, 0.f, 0.f};
        f32x4 oacc[2] = {{0.f,0.f,0.f,0.f},{0.f,0.f,0.f,0.f}};

        for (int jb = 0; jb < 13; ++jb) {
            f32x4 s[2];
            #pragma unroll
            for (int kk = 0; kk < 2; ++kk) {
                f32x4 cb = *(const f32x4*)(btt + (((size_t)(jb * 2 + kk)) << 8));
                int kr = jb * 32 + kk * 16 + c16;
                if (kr > NTOK - 1) kr = NTOK - 1;
                s16x8 bfrag = __builtin_bit_cast(s16x8,
                    *(const u16x8*)&kroot[(size_t)kr * 384]);
                s[kk] = mfma16(afrag, bfrag, cb);
            }
            #pragma unroll
            for (int kk = 0; kk < 2; ++kk)
                #pragma unroll
                for (int r = 0; r < 4; ++r) {
                    float p = exp2f(s[kk][r] * 1.44269504f);
                    l4[r] += p;
                    myPA[g4 * 4 + r][kk * 16 + c16] = f2bf(p);
                }
            s16x8 pa = __builtin_bit_cast(s16x8, *(const u16x8*)&myPA[c16][g4 * 8]);
            #pragma unroll
            for (int nd = 0; nd < 2; ++nd) {
                s16x8 vb = __builtin_bit_cast(s16x8,
                    *(const u16x8*)&Vt[nd * 16 + c16][jb * 32 + g4 * 8]);
                oacc[nd] = mfma16(pa, vb, oacc[nd]);
            }
        }

        #pragma unroll
        for (int r = 0; r < 4; ++r) {
            #pragma unroll
            for (int o = 1; o <= 8; o <<= 1)
                l4[r] += __shfl_xor(l4[r], o);
            l4[r] = 1.f / l4[r];
        }
        #pragma unroll
        for (int nd = 0; nd < 2; ++nd)
            #pragma unroll
            for (int r = 0; r < 4; ++r) {
                int qrow = row0 + g4 * 4 + r;
                if (qrow < NTOK)
                    O[((size_t)(win * NTOK + qrow)) * CH + head * 32 + nd * 16 + c16]
                        = f2bf(oacc[nd][r] * l4[r]);
            }
    }
}

extern "C" void kernel_launch(void* const* d_in, const int* in_sizes, int n_in,
                              void* d_out, int out_size, void* d_ws, size_t ws_size,
                              hipStream_t stream) {
    const float* x      = (const float*)d_in[0];
    const float* n1g    = (const float*)d_in[1];
    const float* n1b    = (const float*)d_in[2];
    const float* qkv_w  = (const float*)d_in[3];
    const float* qkv_b  = (const float*)d_in[4];
    const float* proj_w = (const float*)d_in[5];
    const float* proj_b = (const float*)d_in[6];
    const float* rpb    = (const float*)d_in[7];
    const float* n2g    = (const float*)d_in[8];
    const float* n2b    = (const float*)d_in[9];
    const float* fc1_w  = (const float*)d_in[10];
    const float* fc1_b  = (const float*)d_in[11];
    const float* fc2_w  = (const float*)d_in[12];
    const float* fc2_b  = (const float*)d_in[13];
    float* out = (float*)d_out;

    char* ws = (char*)d_ws;
    size_t off = 0;
    u16* A_bf  = (u16*)(ws + off);  off += (size_t)TOK * 128 * 2;   // LN2 out / biasT2 overlay
    u16* Qb_bf = (u16*)(ws + off);  off += (size_t)TOK * 384 * 2;
    u16* O_bf  = (u16*)(ws + off);  off += (size_t)TOK * 128 * 2;
    u16* R_bf  = (u16*)(ws + off);  off += (size_t)TOK * 128 * 2;   // bf16 residual trunk
    u16* qkvT  = (u16*)(ws + off);  off += 384 * 128 * 2;
    u16* projT = (u16*)(ws + off);  off += 128 * 128 * 2;
    u16* fc1T  = (u16*)(ws + off);  off += 512 * 128 * 2;
    u16* fc2T  = (u16*)(ws + off);  off += 128 * 512 * 2;
    float* biasT2 = (float*)A_bf;   // overlay; dead once proj's LN2 rewrites A_bf

    // 0. weight transposes (+bf16), QSCALE folded into Wq
    hipLaunchKernelGGL(convT, dim3(384/32, 128/32), dim3(256), 0, stream, qkv_w,  qkvT, 128, 384, 128);
    hipLaunchKernelGGL(convT, dim3(128/32, 128/32), dim3(256), 0, stream, proj_w, projT, 128, 128, 0);
    hipLaunchKernelGGL(convT, dim3(512/32, 128/32), dim3(256), 0, stream, fc1_w,  fc1T, 128, 512, 0);
    hipLaunchKernelGGL(convT, dim3(128/32, 512/32), dim3(256), 0, stream, fc2_w,  fc2T, 512, 128, 0);
    // 1. fused LN1 + shift + qkv GEMM -> bf16
    hipLaunchKernelGGL((gemm_mfma<1>), dim3(3, TOK/64), dim3(512), 0, stream,
                       nullptr, qkvT, qkv_b, Qb_bf, 384, x, n1g, n1b, nullptr);
    // 1b. bias+mask table (overlay in A_bf)
    hipLaunchKernelGGL(bias_k, dim3(26, 25, 16), dim3(64), 0, stream, rpb, biasT2);
    // 2. three-tile interleaved flash attention -> bf16
    hipLaunchKernelGGL(attn_mfma, dim3(NWIN * NHEADS), dim3(512), 0, stream,
                       Qb_bf, biasT2, O_bf);
    // 3. proj GEMM + unshift + residual -> bf16 R, fused LN2 -> bf16 A_bf
    hipLaunchKernelGGL((gemm_mfma<2>), dim3(1, TOK/64), dim3(512), 0, stream,
                       O_bf, projT, proj_b, R_bf, 128, x, n2g, n2b, A_bf);
    // 4. fused MLP: fc1 + GELU + fc2 + residual -> f32 out (H stays in LDS)
    hipLaunchKernelGGL(mlp_fused, dim3(TOK/64), dim3(512), 0, stream,
                       A_bf, fc1T, fc1_b, fc2T, fc2_b, R_bf, out);
}

// Round 17
// 147.549 us; speedup vs baseline: 1.5530x; 1.0186x over previous
//
#include <hip/hip_runtime.h>
#include <math.h>

// ---- problem constants ----
#define TOK    50176      // 2*8*56*56 tokens
#define CH     128
#define NWIN   128        // B * 64 windows
#define NTOK   392        // 8*7*7 tokens per window
#define NHEADS 4
#define QSCALE 0.17677669529663687f   // 32^-0.5
#define LNEPS  1e-3f

typedef unsigned short u16;
typedef unsigned int   u32;
typedef u16   u16x4  __attribute__((ext_vector_type(4)));
typedef u16   u16x8  __attribute__((ext_vector_type(8)));
typedef short s16x8  __attribute__((ext_vector_type(8)));
typedef float f32x4  __attribute__((ext_vector_type(4)));

__device__ __forceinline__ float bf2f(u16 u) {
    return __uint_as_float(((u32)u) << 16);
}
__device__ __forceinline__ u16 f2bf(float f) {
    u32 u = __float_as_uint(f);
    return (u16)((u + 0x7fffu + ((u >> 16) & 1u)) >> 16);
}
__device__ __forceinline__ f32x4 mfma16(s16x8 a, s16x8 b, f32x4 c) {
    return __builtin_amdgcn_mfma_f32_16x16x32_bf16(a, b, c, 0, 0, 0);
}

// token m in window layout -> flat token index in original layout (+3 roll)
__device__ __forceinline__ int src_index(int m) {
    int b = m / NTOK, t = m - b * NTOK;
    int batch = b >> 6, wIdx = b & 63;
    int bh = wIdx >> 3, bw = wIdx & 7;
    int d = t / 49, rem = t - d * 49;
    int h7 = rem / 7, w7 = rem - h7 * 7;
    int h = bh * 7 + h7 + 3; if (h >= 56) h -= 56;
    int w = bw * 7 + w7 + 3; if (w >= 56) w -= 56;
    return ((batch * 8 + d) * 56 + h) * 56 + w;
}

// ---- weight transpose + f32->bf16 convert: dst[n][k] = src[k][n] * sc ----
__global__ __launch_bounds__(256) void convT(
    const float* __restrict__ src, u16* __restrict__ dst,
    int K, int N, int scaleN)
{
    __shared__ float t[32][33];
    int n0 = blockIdx.x * 32, k0 = blockIdx.y * 32;
    int tx = threadIdx.x & 31, ty = threadIdx.x >> 5;   // ty 0..7
    #pragma unroll
    for (int r = 0; r < 4; ++r)
        t[ty + r * 8][tx] = src[(size_t)(k0 + ty + r * 8) * N + n0 + tx];
    __syncthreads();
    #pragma unroll
    for (int r = 0; r < 4; ++r) {
        int n = n0 + ty + r * 8;
        float sc = (n < scaleN) ? QSCALE : 1.f;
        dst[(size_t)n * K + k0 + tx] = f2bf(t[tx][ty + r * 8] * sc);
    }
}

// ---- MFMA GEMM, BM=64 x BN=128, 512 threads (8 waves = 4m x 2n), K=128 ----
// EPI 1: FUSED LN1 (x gather via src_index -> LN -> As) + qkv -> bf16
// EPI 2: proj + residual scatter -> bf16 R + fused LN2 -> bf16 ln_out
template<int EPI>
__global__ __launch_bounds__(512, 6) void gemm_mfma(
    const u16* __restrict__ A, const u16* __restrict__ W,
    const float* __restrict__ bias, void* __restrict__ outp,
    int Nn, const float* __restrict__ resid,
    const float* __restrict__ lng, const float* __restrict__ lnb,
    u16* __restrict__ ln_out)
{
    __shared__ u16 As[4][64][32];        // 16 KB  [kc][row][k32]
    __shared__ u16 Bs[4][128][32];       // 32 KB
    __shared__ float lnred[2][4][16][2]; // 1 KB

    int tid = threadIdx.x, w = tid >> 6, l = tid & 63;
    int c16 = l & 15, g4 = l >> 4;
    int m0 = blockIdx.y * 64, n0 = blockIdx.x * 128;
    int wm = w & 3, wn = w >> 2;

    // ---- stage A tile ----
    if (EPI == 1) {
        // fused LN1: gather x rows (src_index), row-LN in 16-lane groups
        #pragma unroll
        for (int p = 0; p < 2; ++p) {
            int e = tid + p * 512, row = e >> 4, c8 = e & 15;
            int src = src_index(m0 + row);
            f32x4 x0 = *(const f32x4*)&resid[(size_t)src * CH + c8 * 8];
            f32x4 x1 = *(const f32x4*)&resid[(size_t)src * CH + c8 * 8 + 4];
            float s = ((x0[0] + x0[1]) + (x0[2] + x0[3]))
                    + ((x1[0] + x1[1]) + (x1[2] + x1[3]));
            float q = ((x0[0]*x0[0] + x0[1]*x0[1]) + (x0[2]*x0[2] + x0[3]*x0[3]))
                    + ((x1[0]*x1[0] + x1[1]*x1[1]) + (x1[2]*x1[2] + x1[3]*x1[3]));
            #pragma unroll
            for (int o = 1; o <= 8; o <<= 1) {
                s += __shfl_xor(s, o);
                q += __shfl_xor(q, o);
            }
            float mean = s * (1.f / CH);
            float var  = q * (1.f / CH) - mean * mean;
            float rstd = rsqrtf(var + LNEPS);
            u16x8 av;
            #pragma unroll
            for (int i = 0; i < 4; ++i)
                av[i] = f2bf((x0[i] - mean) * rstd * lng[c8 * 8 + i] + lnb[c8 * 8 + i]);
            #pragma unroll
            for (int i = 0; i < 4; ++i)
                av[4 + i] = f2bf((x1[i] - mean) * rstd * lng[c8 * 8 + 4 + i] + lnb[c8 * 8 + 4 + i]);
            *(u16x8*)&As[c8 >> 2][row][(c8 & 3) * 8] = av;
        }
    } else {
        #pragma unroll
        for (int p = 0; p < 2; ++p) {
            int e = tid + p * 512, row = e >> 4, c8 = e & 15;
            u16x8 v = *(const u16x8*)&A[(size_t)(m0 + row) * 128 + c8 * 8];
            *(u16x8*)&As[c8 >> 2][row][(c8 & 3) * 8] = v;
        }
    }
    // ---- stage B tile ----
    #pragma unroll
    for (int p = 0; p < 4; ++p) {
        int e = tid + p * 512, row = e >> 4, c8 = e & 15;
        u16x8 v = *(const u16x8*)&W[(size_t)(n0 + row) * 128 + c8 * 8];
        *(u16x8*)&Bs[c8 >> 2][row][(c8 & 3) * 8] = v;
    }
    __syncthreads();

    f32x4 acc[4] = {};
    #pragma unroll
    for (int kc = 0; kc < 4; ++kc) {
        s16x8 af = __builtin_bit_cast(s16x8,
            *(const u16x8*)&As[kc][wm * 16 + c16][g4 * 8]);
        #pragma unroll
        for (int ni = 0; ni < 4; ++ni) {
            s16x8 bf = __builtin_bit_cast(s16x8,
                *(const u16x8*)&Bs[kc][wn * 64 + ni * 16 + c16][g4 * 8]);
            acc[ni] = mfma16(af, bf, acc[ni]);
        }
    }

    if (EPI == 2) {
        float psum[4], psq[4];
        int dstl[4];
        #pragma unroll
        for (int r = 0; r < 4; ++r) {
            int m = m0 + wm * 16 + g4 * 4 + r;
            int dst = src_index(m);
            dstl[r] = dst;
            float s = 0.f, q = 0.f;
            #pragma unroll
            for (int ni = 0; ni < 4; ++ni) {
                int col = wn * 64 + ni * 16 + c16;
                float v = acc[ni][r] + bias[col] + resid[(size_t)dst * CH + col];
                acc[ni][r] = v;
                s += v; q += v * v;
            }
            psum[r] = s; psq[r] = q;
        }
        #pragma unroll
        for (int o = 1; o <= 8; o <<= 1)
            #pragma unroll
            for (int r = 0; r < 4; ++r) {
                psum[r] += __shfl_xor(psum[r], o);
                psq[r]  += __shfl_xor(psq[r], o);
            }
        if (c16 == 0) {
            #pragma unroll
            for (int r = 0; r < 4; ++r) {
                int rl = g4 * 4 + r;
                lnred[wn][wm][rl][0] = psum[r];
                lnred[wn][wm][rl][1] = psq[r];
            }
        }
        __syncthreads();
        float gl[4], bl[4];
        #pragma unroll
        for (int ni = 0; ni < 4; ++ni) {
            int col = wn * 64 + ni * 16 + c16;
            gl[ni] = lng[col]; bl[ni] = lnb[col];
        }
        #pragma unroll
        for (int r = 0; r < 4; ++r) {
            int rl = g4 * 4 + r;
            float s = lnred[0][wm][rl][0] + lnred[1][wm][rl][0];
            float q = lnred[0][wm][rl][1] + lnred[1][wm][rl][1];
            float mean = s * (1.f / CH);
            float var  = q * (1.f / CH) - mean * mean;
            float rstd = rsqrtf(var + LNEPS);
            int dst = dstl[r];
            #pragma unroll
            for (int ni = 0; ni < 4; ++ni) {
                int col = wn * 64 + ni * 16 + c16;
                float v = acc[ni][r];
                ((u16*)outp)[(size_t)dst * CH + col] = f2bf(v);
                ln_out[(size_t)dst * CH + col] = f2bf((v - mean) * rstd * gl[ni] + bl[ni]);
            }
        }
    } else {
        #pragma unroll
        for (int r = 0; r < 4; ++r) {
            int m = m0 + wm * 16 + g4 * 4 + r;
            #pragma unroll
            for (int ni = 0; ni < 4; ++ni) {
                int col = n0 + wn * 64 + ni * 16 + c16;
                float v = acc[ni][r] + bias[col] * (col < 128 ? QSCALE : 1.f);
                ((u16*)outp)[(size_t)m * Nn + col] = f2bf(v);
            }
        }
    }
}

// ---- fused MLP with register-prefetched weights ----
// out = fc2(gelu(fc1(A) + b1)) + b2 + resid, BM=64, 512 thr, H stays in LDS
__global__ __launch_bounds__(512, 2) void mlp_fused(
    const u16* __restrict__ A, const u16* __restrict__ W1,
    const float* __restrict__ b1, const u16* __restrict__ W2,
    const float* __restrict__ b2, const u16* __restrict__ residb,
    float* __restrict__ outp)
{
    __shared__ u16 As[4][64][32];    // 16 KB
    __shared__ u16 Bs[4][128][32];   // 32 KB
    __shared__ u16 Hs[4][64][40];    // 20 KB
    // total 68.5 KB -> 2 blocks/CU

    int tid = threadIdx.x, w = tid >> 6, l = tid & 63;
    int c16 = l & 15, g4 = l >> 4;
    int m0 = blockIdx.x * 64;
    int wm = w & 3, wn = w >> 2;
    int srow = tid >> 4, sc8 = tid & 15;   // staging row/col8 (p stride 32 rows)

    // stage A tile + prefetch W1 chunk 0 into regs
    u16x8 wv[4];
    #pragma unroll
    for (int p = 0; p < 4; ++p)
        wv[p] = *(const u16x8*)&W1[(size_t)(srow + p * 32) * 128 + sc8 * 8];
    #pragma unroll
    for (int p = 0; p < 2; ++p) {
        int row = srow + p * 32;
        u16x8 v = *(const u16x8*)&A[(size_t)(m0 + row) * 128 + sc8 * 8];
        *(u16x8*)&As[sc8 >> 2][row][(sc8 & 3) * 8] = v;
    }

    f32x4 acc2[4] = {};
    for (int ch = 0; ch < 4; ++ch) {
        // write Bs = W1[ch] (from prefetched regs)
        #pragma unroll
        for (int p = 0; p < 4; ++p)
            *(u16x8*)&Bs[sc8 >> 2][srow + p * 32][(sc8 & 3) * 8] = wv[p];
        __syncthreads();

        // prefetch W2[ch] into regs (overlaps fc1 MFMA + gelu)
        u16x8 wv2[4];
        #pragma unroll
        for (int p = 0; p < 4; ++p)
            wv2[p] = *(const u16x8*)&W2[(size_t)(srow + p * 32) * 512 + ch * 128 + sc8 * 8];

        f32x4 hacc[4] = {};
        #pragma unroll
        for (int kc = 0; kc < 4; ++kc) {
            s16x8 af = __builtin_bit_cast(s16x8,
                *(const u16x8*)&As[kc][wm * 16 + c16][g4 * 8]);
            #pragma unroll
            for (int ni = 0; ni < 4; ++ni) {
                s16x8 bf = __builtin_bit_cast(s16x8,
                    *(const u16x8*)&Bs[kc][wn * 64 + ni * 16 + c16][g4 * 8]);
                hacc[ni] = mfma16(af, bf, hacc[ni]);
            }
        }
        #pragma unroll
        for (int r = 0; r < 4; ++r) {
            int row = wm * 16 + g4 * 4 + r;
            #pragma unroll
            for (int ni = 0; ni < 4; ++ni) {
                int col = wn * 64 + ni * 16 + c16;
                float v = hacc[ni][r] + b1[ch * 128 + col];
                v = 0.5f * v * (1.f + erff(v * 0.70710678118654752f));
                Hs[col >> 5][row][col & 31] = f2bf(v);
            }
        }
        __syncthreads();   // Hs visible; Bs reads done

        // write Bs = W2[ch] (from prefetched regs)
        #pragma unroll
        for (int p = 0; p < 4; ++p)
            *(u16x8*)&Bs[sc8 >> 2][srow + p * 32][(sc8 & 3) * 8] = wv2[p];
        __syncthreads();

        // prefetch W1[ch+1] into regs (overlaps fc2 MFMA)
        if (ch < 3) {
            #pragma unroll
            for (int p = 0; p < 4; ++p)
                wv[p] = *(const u16x8*)&W1[(size_t)((ch + 1) * 128 + srow + p * 32) * 128 + sc8 * 8];
        }

        #pragma unroll
        for (int kc = 0; kc < 4; ++kc) {
            s16x8 af = __builtin_bit_cast(s16x8,
                *(const u16x8*)&Hs[kc][wm * 16 + c16][g4 * 8]);
            #pragma unroll
            for (int ni = 0; ni < 4; ++ni) {
                s16x8 bf = __builtin_bit_cast(s16x8,
                    *(const u16x8*)&Bs[kc][wn * 64 + ni * 16 + c16][g4 * 8]);
                acc2[ni] = mfma16(af, bf, acc2[ni]);
            }
        }
        if (ch < 3) __syncthreads();   // Hs/Bs reads done before next overwrite
    }

    #pragma unroll
    for (int r = 0; r < 4; ++r) {
        int m = m0 + wm * 16 + g4 * 4 + r;
        #pragma unroll
        for (int ni = 0; ni < 4; ++ni) {
            int col = wn * 64 + ni * 16 + c16;
            float v = acc2[ni][r] + b2[col];
            outp[(size_t)m * CH + col] = v + bf2f(residb[(size_t)m * CH + col]);
        }
    }
}

// ---- bias+mask table, f32, MFMA C-fragment layout: [hw][t][nt=26][lane][r] ----
__global__ __launch_bounds__(64) void bias_k(
    const float* __restrict__ rpb, float* __restrict__ biasT2)
{
    int nt = blockIdx.x;   // 0..25 (col tile; 25 is all -100 pad)
    int t  = blockIdx.y;   // 0..24 (row tile)
    int hw = blockIdx.z;   // head*4 + wt
    int l  = threadIdx.x;  // 0..63
    int head = hw >> 2, wt = hw & 3;
    int bh7 = wt >> 1, bw7 = wt & 1;
    int j = nt * 16 + (l & 15);
    int rb = t * 16 + (l >> 4) * 4;
    f32x4 outv;
    #pragma unroll
    for (int r = 0; r < 4; ++r) {
        int i = rb + r; if (i > NTOK - 1) i = NTOK - 1;
        float v;
        if (j >= NTOK) v = -100.f;
        else {
            int di = i / 49, ri = i - di * 49, hi = ri / 7, wi = ri - hi * 7;
            int dj = j / 49, rj = j - dj * 49, hj = rj / 7, wj = rj - hj * 7;
            int bidx = (di - dj + 7) * 169 + (hi - hj + 6) * 13 + (wi - wj + 6);
            v = rpb[bidx * NHEADS + head];
            int regi = (bh7 ? (hi < 4 ? 1 : 2) : 0) * 3 + (bw7 ? (wi < 4 ? 1 : 2) : 0);
            int regj = (bh7 ? (hj < 4 ? 1 : 2) : 0) * 3 + (bw7 ? (wj < 4 ? 1 : 2) : 0);
            if (regi != regj) v -= 100.f;
        }
        outv[r] = v;
    }
    *(f32x4*)&biasT2[((((size_t)hw * 25 + t) * 26 + nt) << 8) + (l << 2)] = outv;
}

// ---- flash-strip MFMA attention, 8 waves/block, THREE-tile interleaved ----
__global__ __launch_bounds__(512, 4) void attn_mfma(
    const u16* __restrict__ Qb, const float* __restrict__ biasT2,
    u16* __restrict__ O)
{
    __shared__ u16 Vt[32][420];         // 26880 B, cols 400..415 zero
    __shared__ u16 Pst[8][3][16][40];   // 30720 B, per-wave 3 P strips

    int bid = blockIdx.x;
    int win = bid >> 2, head = bid & 3;
    int tid = threadIdx.x, w = tid >> 6, l = tid & 63;
    int c16 = l & 15, g4 = l >> 4;

    const size_t qbase = (size_t)win * NTOK * 384;
    for (int e = tid; e < 1600; e += 512) {
        int j = e >> 2, d0 = (e & 3) * 8;
        u16x8 vv = {0, 0, 0, 0, 0, 0, 0, 0};
        if (j < NTOK)
            vv = *(const u16x8*)&Qb[qbase + (size_t)j * 384 + 256 + head * 32 + d0];
        #pragma unroll
        for (int i = 0; i < 8; ++i) Vt[d0 + i][j] = vv[i];
    }
    if (tid < 32 * 16) Vt[tid >> 4][400 + (tid & 15)] = 0;
    __syncthreads();

    int wIdx = win & 63;
    int wt = (((wIdx >> 3) == 7) ? 2 : 0) + (((wIdx & 7) == 7) ? 1 : 0);
    const float* bt = biasT2 + (((size_t)(head * 4 + wt) * 25 * 26) << 8) + (l << 2);
    const u16* kroot = Qb + qbase + 128 + head * 32 + g4 * 8;
    u16 (*myPA)[40] = Pst[w][0];
    u16 (*myPB)[40] = Pst[w][1];
    u16 (*myPC)[40] = Pst[w][2];

    // ---- triple pass: tiles tA = w, tB = w+8, tC = w+16 (rows < 384) ----
    {
        int tA = w, tB = w + 8, tC = w + 16;
        s16x8 qfragA = __builtin_bit_cast(s16x8,
            *(const u16x8*)&Qb[qbase + (size_t)(tA * 16 + c16) * 384 + head * 32 + g4 * 8]);
        s16x8 qfragB = __builtin_bit_cast(s16x8,
            *(const u16x8*)&Qb[qbase + (size_t)(tB * 16 + c16) * 384 + head * 32 + g4 * 8]);
        s16x8 qfragC = __builtin_bit_cast(s16x8,
            *(const u16x8*)&Qb[qbase + (size_t)(tC * 16 + c16) * 384 + head * 32 + g4 * 8]);
        const float* bttA = bt + (((size_t)tA * 26) << 8);
        const float* bttB = bt + (((size_t)tB * 26) << 8);
        const float* bttC = bt + (((size_t)tC * 26) << 8);

        float l4A[4] = {0.f,0.f,0.f,0.f}, l4B[4] = {0.f,0.f,0.f,0.f}, l4C[4] = {0.f,0.f,0.f,0.f};
        f32x4 oaccA0 = {0.f,0.f,0.f,0.f}, oaccA1 = {0.f,0.f,0.f,0.f};
        f32x4 oaccB0 = {0.f,0.f,0.f,0.f}, oaccB1 = {0.f,0.f,0.f,0.f};
        f32x4 oaccC0 = {0.f,0.f,0.f,0.f}, oaccC1 = {0.f,0.f,0.f,0.f};

        for (int jb = 0; jb < 13; ++jb) {
            int kr0 = jb * 32 + c16;      if (kr0 > NTOK - 1) kr0 = NTOK - 1;
            int kr1 = jb * 32 + 16 + c16; if (kr1 > NTOK - 1) kr1 = NTOK - 1;
            s16x8 kf0 = __builtin_bit_cast(s16x8, *(const u16x8*)&kroot[(size_t)kr0 * 384]);
            s16x8 kf1 = __builtin_bit_cast(s16x8, *(const u16x8*)&kroot[(size_t)kr1 * 384]);
            f32x4 sA0 = mfma16(qfragA, kf0, *(const f32x4*)(bttA + (((size_t)(jb*2+0)) << 8)));
            f32x4 sA1 = mfma16(qfragA, kf1, *(const f32x4*)(bttA + (((size_t)(jb*2+1)) << 8)));
            f32x4 sB0 = mfma16(qfragB, kf0, *(const f32x4*)(bttB + (((size_t)(jb*2+0)) << 8)));
            f32x4 sB1 = mfma16(qfragB, kf1, *(const f32x4*)(bttB + (((size_t)(jb*2+1)) << 8)));
            f32x4 sC0 = mfma16(qfragC, kf0, *(const f32x4*)(bttC + (((size_t)(jb*2+0)) << 8)));
            f32x4 sC1 = mfma16(qfragC, kf1, *(const f32x4*)(bttC + (((size_t)(jb*2+1)) << 8)));
            #pragma unroll
            for (int r = 0; r < 4; ++r) {
                float p0 = exp2f(sA0[r] * 1.44269504f);
                float p1 = exp2f(sA1[r] * 1.44269504f);
                l4A[r] += p0 + p1;
                myPA[g4 * 4 + r][c16]      = f2bf(p0);
                myPA[g4 * 4 + r][16 + c16] = f2bf(p1);
            }
            #pragma unroll
            for (int r = 0; r < 4; ++r) {
                float p0 = exp2f(sB0[r] * 1.44269504f);
                float p1 = exp2f(sB1[r] * 1.44269504f);
                l4B[r] += p0 + p1;
                myPB[g4 * 4 + r][c16]      = f2bf(p0);
                myPB[g4 * 4 + r][16 + c16] = f2bf(p1);
            }
            #pragma unroll
            for (int r = 0; r < 4; ++r) {
                float p0 = exp2f(sC0[r] * 1.44269504f);
                float p1 = exp2f(sC1[r] * 1.44269504f);
                l4C[r] += p0 + p1;
                myPC[g4 * 4 + r][c16]      = f2bf(p0);
                myPC[g4 * 4 + r][16 + c16] = f2bf(p1);
            }
            s16x8 paA = __builtin_bit_cast(s16x8, *(const u16x8*)&myPA[c16][g4 * 8]);
            s16x8 paB = __builtin_bit_cast(s16x8, *(const u16x8*)&myPB[c16][g4 * 8]);
            s16x8 paC = __builtin_bit_cast(s16x8, *(const u16x8*)&myPC[c16][g4 * 8]);
            s16x8 vb0 = __builtin_bit_cast(s16x8, *(const u16x8*)&Vt[c16][jb * 32 + g4 * 8]);
            s16x8 vb1 = __builtin_bit_cast(s16x8, *(const u16x8*)&Vt[16 + c16][jb * 32 + g4 * 8]);
            oaccA0 = mfma16(paA, vb0, oaccA0);
            oaccA1 = mfma16(paA, vb1, oaccA1);
            oaccB0 = mfma16(paB, vb0, oaccB0);
            oaccB1 = mfma16(paB, vb1, oaccB1);
            oaccC0 = mfma16(paC, vb0, oaccC0);
            oaccC1 = mfma16(paC, vb1, oaccC1);
        }

        #pragma unroll
        for (int r = 0; r < 4; ++r) {
            #pragma unroll
            for (int o = 1; o <= 8; o <<= 1) {
                l4A[r] += __shfl_xor(l4A[r], o);
                l4B[r] += __shfl_xor(l4B[r], o);
                l4C[r] += __shfl_xor(l4C[r], o);
            }
            l4A[r] = 1.f / l4A[r];
            l4B[r] = 1.f / l4B[r];
            l4C[r] = 1.f / l4C[r];
        }
        #pragma unroll
        for (int r = 0; r < 4; ++r) {
            int qA = tA * 16 + g4 * 4 + r;
            int qB = tB * 16 + g4 * 4 + r;
            int qC = tC * 16 + g4 * 4 + r;
            size_t oA = ((size_t)(win * NTOK + qA)) * CH + head * 32 + c16;
            size_t oB = ((size_t)(win * NTOK + qB)) * CH + head * 32 + c16;
            size_t oC = ((size_t)(win * NTOK + qC)) * CH + head * 32 + c16;
            O[oA]      = f2bf(oaccA0[r] * l4A[r]);
            O[oA + 16] = f2bf(oaccA1[r] * l4A[r]);
            O[oB]      = f2bf(oaccB0[r] * l4B[r]);
            O[oB + 16] = f2bf(oaccB1[r] * l4B[r]);
            O[oC]      = f2bf(oaccC0[r] * l4C[r]);
            O[oC + 16] = f2bf(oaccC1[r] * l4C[r]);
        }
    }

    // ---- solo pass: t = 24 on wave 0 only ----
    if (w == 0) {
        int t = 24;
        int row0 = t * 16;
        int qr = row0 + c16; if (qr > NTOK - 1) qr = NTOK - 1;
        s16x8 afrag = __builtin_bit_cast(s16x8,
            *(const u16x8*)&Qb[qbase + (size_t)qr * 384 + head * 32 + g4 * 8]);
        const float* btt = bt + (((size_t)t * 26) << 8);

        float l4[4] = {0.f, 0.f, 0.f, 0.f};
        f32x4 oacc[2] = {{0.f,0.f,0.f,0.f},{0.f,0.f,0.f,0.f}};

        for (int jb = 0; jb < 13; ++jb) {
            f32x4 s[2];
            #pragma unroll
            for (int kk = 0; kk < 2; ++kk) {
                f32x4 cb = *(const f32x4*)(btt + (((size_t)(jb * 2 + kk)) << 8));
                int kr = jb * 32 + kk * 16 + c16;
                if (kr > NTOK - 1) kr = NTOK - 1;
                s16x8 bfrag = __builtin_bit_cast(s16x8,
                    *(const u16x8*)&kroot[(size_t)kr * 384]);
                s[kk] = mfma16(afrag, bfrag, cb);
            }
            #pragma unroll
            for (int kk = 0; kk < 2; ++kk)
                #pragma unroll
                for (int r = 0; r < 4; ++r) {
                    float p = exp2f(s[kk][r] * 1.44269504f);
                    l4[r] += p;
                    myPA[g4 * 4 + r][kk * 16 + c16] = f2bf(p);
                }
            s16x8 pa = __builtin_bit_cast(s16x8, *(const u16x8*)&myPA[c16][g4 * 8]);
            #pragma unroll
            for (int nd = 0; nd < 2; ++nd) {
                s16x8 vb = __builtin_bit_cast(s16x8,
                    *(const u16x8*)&Vt[nd * 16 + c16][jb * 32 + g4 * 8]);
                oacc[nd] = mfma16(pa, vb, oacc[nd]);
            }
        }

        #pragma unroll
        for (int r = 0; r < 4; ++r) {
            #pragma unroll
            for (int o = 1; o <= 8; o <<= 1)
                l4[r] += __shfl_xor(l4[r], o);
            l4[r] = 1.f / l4[r];
        }
        #pragma unroll
        for (int nd = 0; nd < 2; ++nd)
            #pragma unroll
            for (int r = 0; r < 4; ++r) {
                int qrow = row0 + g4 * 4 + r;
                if (qrow < NTOK)
                    O[((size_t)(win * NTOK + qrow)) * CH + head * 32 + nd * 16 + c16]
                        = f2bf(oacc[nd][r] * l4[r]);
            }
    }
}

extern "C" void kernel_launch(void* const* d_in, const int* in_sizes, int n_in,
                              void* d_out, int out_size, void* d_ws, size_t ws_size,
                              hipStream_t stream) {
    const float* x      = (const float*)d_in[0];
    const float* n1g    = (const float*)d_in[1];
    const float* n1b    = (const float*)d_in[2];
    const float* qkv_w  = (const float*)d_in[3];
    const float* qkv_b  = (const float*)d_in[4];
    const float* proj_w = (const float*)d_in[5];
    const float* proj_b = (const float*)d_in[6];
    const float* rpb    = (const float*)d_in[7];
    const float* n2g    = (const float*)d_in[8];
    const float* n2b    = (const float*)d_in[9];
    const float* fc1_w  = (const float*)d_in[10];
    const float* fc1_b  = (const float*)d_in[11];
    const float* fc2_w  = (const float*)d_in[12];
    const float* fc2_b  = (const float*)d_in[13];
    float* out = (float*)d_out;

    char* ws = (char*)d_ws;
    size_t off = 0;
    u16* A_bf  = (u16*)(ws + off);  off += (size_t)TOK * 128 * 2;   // LN2 out / biasT2 overlay
    u16* Qb_bf = (u16*)(ws + off);  off += (size_t)TOK * 384 * 2;
    u16* O_bf  = (u16*)(ws + off);  off += (size_t)TOK * 128 * 2;
    u16* R_bf  = (u16*)(ws + off);  off += (size_t)TOK * 128 * 2;   // bf16 residual trunk
    u16* qkvT  = (u16*)(ws + off);  off += 384 * 128 * 2;
    u16* projT = (u16*)(ws + off);  off += 128 * 128 * 2;
    u16* fc1T  = (u16*)(ws + off);  off += 512 * 128 * 2;
    u16* fc2T  = (u16*)(ws + off);  off += 128 * 512 * 2;
    float* biasT2 = (float*)A_bf;   // overlay; dead once proj's LN2 rewrites A_bf

    // 0. weight transposes (+bf16), QSCALE folded into Wq
    hipLaunchKernelGGL(convT, dim3(384/32, 128/32), dim3(256), 0, stream, qkv_w,  qkvT, 128, 384, 128);
    hipLaunchKernelGGL(convT, dim3(128/32, 128/32), dim3(256), 0, stream, proj_w, projT, 128, 128, 0);
    hipLaunchKernelGGL(convT, dim3(512/32, 128/32), dim3(256), 0, stream, fc1_w,  fc1T, 128, 512, 0);
    hipLaunchKernelGGL(convT, dim3(128/32, 512/32), dim3(256), 0, stream, fc2_w,  fc2T, 512, 128, 0);
    // 1. fused LN1 + shift + qkv GEMM -> bf16
    hipLaunchKernelGGL((gemm_mfma<1>), dim3(3, TOK/64), dim3(512), 0, stream,
                       nullptr, qkvT, qkv_b, Qb_bf, 384, x, n1g, n1b, nullptr);
    // 1b. bias+mask table (overlay in A_bf)
    hipLaunchKernelGGL(bias_k, dim3(26, 25, 16), dim3(64), 0, stream, rpb, biasT2);
    // 2. three-tile interleaved flash attention -> bf16
    hipLaunchKernelGGL(attn_mfma, dim3(NWIN * NHEADS), dim3(512), 0, stream,
                       Qb_bf, biasT2, O_bf);
    // 3. proj GEMM + unshift + residual -> bf16 R, fused LN2 -> bf16 A_bf
    hipLaunchKernelGGL((gemm_mfma<2>), dim3(1, TOK/64), dim3(512), 0, stream,
                       O_bf, projT, proj_b, R_bf, 128, x, n2g, n2b, A_bf);
    // 4. fused MLP (prefetched): fc1 + GELU + fc2 + residual -> f32 out
    hipLaunchKernelGGL(mlp_fused, dim3(TOK/64), dim3(512), 0, stream,
                       A_bf, fc1T, fc1_b, fc2T, fc2_b, R_bf, out);
}

// Round 18
// 144.822 us; speedup vs baseline: 1.5823x; 1.0188x over previous
//
#include <hip/hip_runtime.h>
#include <math.h>

// ---- problem constants ----
#define TOK    50176      // 2*8*56*56 tokens
#define CH     128
#define NWIN   128        // B * 64 windows
#define NTOK   392        // 8*7*7 tokens per window
#define NHEADS 4
#define QSCALE 0.17677669529663687f   // 32^-0.5
#define LNEPS  1e-3f

typedef unsigned short u16;
typedef unsigned int   u32;
typedef u16   u16x4  __attribute__((ext_vector_type(4)));
typedef u16   u16x8  __attribute__((ext_vector_type(8)));
typedef short s16x8  __attribute__((ext_vector_type(8)));
typedef float f32x4  __attribute__((ext_vector_type(4)));

__device__ __forceinline__ float bf2f(u16 u) {
    return __uint_as_float(((u32)u) << 16);
}
__device__ __forceinline__ u16 f2bf(float f) {
    u32 u = __float_as_uint(f);
    return (u16)((u + 0x7fffu + ((u >> 16) & 1u)) >> 16);
}
__device__ __forceinline__ f32x4 mfma16(s16x8 a, s16x8 b, f32x4 c) {
    return __builtin_amdgcn_mfma_f32_16x16x32_bf16(a, b, c, 0, 0, 0);
}

// token m in window layout -> flat token index in original layout (+3 roll)
__device__ __forceinline__ int src_index(int m) {
    int b = m / NTOK, t = m - b * NTOK;
    int batch = b >> 6, wIdx = b & 63;
    int bh = wIdx >> 3, bw = wIdx & 7;
    int d = t / 49, rem = t - d * 49;
    int h7 = rem / 7, w7 = rem - h7 * 7;
    int h = bh * 7 + h7 + 3; if (h >= 56) h -= 56;
    int w = bw * 7 + w7 + 3; if (w >= 56) w -= 56;
    return ((batch * 8 + d) * 56 + h) * 56 + w;
}

// ---- weight transpose + f32->bf16 convert: dst[n][k] = src[k][n] * sc ----
__global__ __launch_bounds__(256) void convT(
    const float* __restrict__ src, u16* __restrict__ dst,
    int K, int N, int scaleN)
{
    __shared__ float t[32][33];
    int n0 = blockIdx.x * 32, k0 = blockIdx.y * 32;
    int tx = threadIdx.x & 31, ty = threadIdx.x >> 5;   // ty 0..7
    #pragma unroll
    for (int r = 0; r < 4; ++r)
        t[ty + r * 8][tx] = src[(size_t)(k0 + ty + r * 8) * N + n0 + tx];
    __syncthreads();
    #pragma unroll
    for (int r = 0; r < 4; ++r) {
        int n = n0 + ty + r * 8;
        float sc = (n < scaleN) ? QSCALE : 1.f;
        dst[(size_t)n * K + k0 + tx] = f2bf(t[tx][ty + r * 8] * sc);
    }
}

// ---- fused LN1 + qkv GEMM, one block per 64-token tile, loops 3 n-tiles ----
// As staged once (LN1 of x via src_index); W tiles register-prefetched.
__global__ __launch_bounds__(512, 6) void qkv_ln(
    const float* __restrict__ x, const u16* __restrict__ W,
    const float* __restrict__ bias, u16* __restrict__ outp,
    const float* __restrict__ lng, const float* __restrict__ lnb)
{
    __shared__ u16 As[4][64][32];    // 16 KB
    __shared__ u16 Bs[4][128][32];   // 32 KB  -> total ~49 KB, 3 blocks/CU

    int tid = threadIdx.x, l = tid & 63;
    int c16 = l & 15, g4 = l >> 4;
    int m0 = blockIdx.x * 64;
    int w = tid >> 6, wm = w & 3, wn = w >> 2;
    int srow = tid >> 4, sc8 = tid & 15;

    // prefetch W tile 0
    u16x8 wv[4];
    #pragma unroll
    for (int p = 0; p < 4; ++p)
        wv[p] = *(const u16x8*)&W[(size_t)(srow + p * 32) * 128 + sc8 * 8];

    // fused LN1: gather x rows (src_index), row-LN in 16-lane groups -> As
    #pragma unroll
    for (int p = 0; p < 2; ++p) {
        int row = srow + p * 32;
        int src = src_index(m0 + row);
        f32x4 x0 = *(const f32x4*)&x[(size_t)src * CH + sc8 * 8];
        f32x4 x1 = *(const f32x4*)&x[(size_t)src * CH + sc8 * 8 + 4];
        float s = ((x0[0] + x0[1]) + (x0[2] + x0[3]))
                + ((x1[0] + x1[1]) + (x1[2] + x1[3]));
        float q = ((x0[0]*x0[0] + x0[1]*x0[1]) + (x0[2]*x0[2] + x0[3]*x0[3]))
                + ((x1[0]*x1[0] + x1[1]*x1[1]) + (x1[2]*x1[2] + x1[3]*x1[3]));
        #pragma unroll
        for (int o = 1; o <= 8; o <<= 1) {
            s += __shfl_xor(s, o);
            q += __shfl_xor(q, o);
        }
        float mean = s * (1.f / CH);
        float var  = q * (1.f / CH) - mean * mean;
        float rstd = rsqrtf(var + LNEPS);
        u16x8 av;
        #pragma unroll
        for (int i = 0; i < 4; ++i)
            av[i] = f2bf((x0[i] - mean) * rstd * lng[sc8 * 8 + i] + lnb[sc8 * 8 + i]);
        #pragma unroll
        for (int i = 0; i < 4; ++i)
            av[4 + i] = f2bf((x1[i] - mean) * rstd * lng[sc8 * 8 + 4 + i] + lnb[sc8 * 8 + 4 + i]);
        *(u16x8*)&As[sc8 >> 2][row][(sc8 & 3) * 8] = av;
    }

    for (int nt = 0; nt < 3; ++nt) {
        // write Bs from prefetched regs
        #pragma unroll
        for (int p = 0; p < 4; ++p)
            *(u16x8*)&Bs[sc8 >> 2][srow + p * 32][(sc8 & 3) * 8] = wv[p];
        __syncthreads();
        // prefetch next W tile (overlaps MFMA)
        if (nt < 2) {
            #pragma unroll
            for (int p = 0; p < 4; ++p)
                wv[p] = *(const u16x8*)&W[(size_t)((nt + 1) * 128 + srow + p * 32) * 128 + sc8 * 8];
        }
        f32x4 acc[4] = {};
        #pragma unroll
        for (int kc = 0; kc < 4; ++kc) {
            s16x8 af = __builtin_bit_cast(s16x8,
                *(const u16x8*)&As[kc][wm * 16 + c16][g4 * 8]);
            #pragma unroll
            for (int ni = 0; ni < 4; ++ni) {
                s16x8 bf = __builtin_bit_cast(s16x8,
                    *(const u16x8*)&Bs[kc][wn * 64 + ni * 16 + c16][g4 * 8]);
                acc[ni] = mfma16(af, bf, acc[ni]);
            }
        }
        #pragma unroll
        for (int r = 0; r < 4; ++r) {
            int m = m0 + wm * 16 + g4 * 4 + r;
            #pragma unroll
            for (int ni = 0; ni < 4; ++ni) {
                int col = nt * 128 + wn * 64 + ni * 16 + c16;
                float v = acc[ni][r] + bias[col] * (col < 128 ? QSCALE : 1.f);
                outp[(size_t)m * 384 + col] = f2bf(v);
            }
        }
        if (nt < 2) __syncthreads();   // Bs reads done before overwrite
    }
}

// ---- proj GEMM + residual scatter -> bf16 R + fused LN2 -> bf16 ln_out ----
__global__ __launch_bounds__(512, 6) void proj_ln(
    const u16* __restrict__ A, const u16* __restrict__ W,
    const float* __restrict__ bias, u16* __restrict__ outp,
    const float* __restrict__ resid,
    const float* __restrict__ lng, const float* __restrict__ lnb,
    u16* __restrict__ ln_out)
{
    __shared__ u16 As[4][64][32];        // 16 KB
    __shared__ u16 Bs[4][128][32];       // 32 KB
    __shared__ float lnred[2][4][16][2]; // 1 KB

    int tid = threadIdx.x, w = tid >> 6, l = tid & 63;
    int c16 = l & 15, g4 = l >> 4;
    int m0 = blockIdx.x * 64;
    int wm = w & 3, wn = w >> 2;

    #pragma unroll
    for (int p = 0; p < 2; ++p) {
        int e = tid + p * 512, row = e >> 4, c8 = e & 15;
        u16x8 v = *(const u16x8*)&A[(size_t)(m0 + row) * 128 + c8 * 8];
        *(u16x8*)&As[c8 >> 2][row][(c8 & 3) * 8] = v;
    }
    #pragma unroll
    for (int p = 0; p < 4; ++p) {
        int e = tid + p * 512, row = e >> 4, c8 = e & 15;
        u16x8 v = *(const u16x8*)&W[(size_t)row * 128 + c8 * 8];
        *(u16x8*)&Bs[c8 >> 2][row][(c8 & 3) * 8] = v;
    }
    __syncthreads();

    f32x4 acc[4] = {};
    #pragma unroll
    for (int kc = 0; kc < 4; ++kc) {
        s16x8 af = __builtin_bit_cast(s16x8,
            *(const u16x8*)&As[kc][wm * 16 + c16][g4 * 8]);
        #pragma unroll
        for (int ni = 0; ni < 4; ++ni) {
            s16x8 bf = __builtin_bit_cast(s16x8,
                *(const u16x8*)&Bs[kc][wn * 64 + ni * 16 + c16][g4 * 8]);
            acc[ni] = mfma16(af, bf, acc[ni]);
        }
    }

    float psum[4], psq[4];
    int dstl[4];
    #pragma unroll
    for (int r = 0; r < 4; ++r) {
        int m = m0 + wm * 16 + g4 * 4 + r;
        int dst = src_index(m);
        dstl[r] = dst;
        float s = 0.f, q = 0.f;
        #pragma unroll
        for (int ni = 0; ni < 4; ++ni) {
            int col = wn * 64 + ni * 16 + c16;
            float v = acc[ni][r] + bias[col] + resid[(size_t)dst * CH + col];
            acc[ni][r] = v;
            s += v; q += v * v;
        }
        psum[r] = s; psq[r] = q;
    }
    #pragma unroll
    for (int o = 1; o <= 8; o <<= 1)
        #pragma unroll
        for (int r = 0; r < 4; ++r) {
            psum[r] += __shfl_xor(psum[r], o);
            psq[r]  += __shfl_xor(psq[r], o);
        }
    if (c16 == 0) {
        #pragma unroll
        for (int r = 0; r < 4; ++r) {
            int rl = g4 * 4 + r;
            lnred[wn][wm][rl][0] = psum[r];
            lnred[wn][wm][rl][1] = psq[r];
        }
    }
    __syncthreads();
    float gl[4], bl[4];
    #pragma unroll
    for (int ni = 0; ni < 4; ++ni) {
        int col = wn * 64 + ni * 16 + c16;
        gl[ni] = lng[col]; bl[ni] = lnb[col];
    }
    #pragma unroll
    for (int r = 0; r < 4; ++r) {
        int rl = g4 * 4 + r;
        float s = lnred[0][wm][rl][0] + lnred[1][wm][rl][0];
        float q = lnred[0][wm][rl][1] + lnred[1][wm][rl][1];
        float mean = s * (1.f / CH);
        float var  = q * (1.f / CH) - mean * mean;
        float rstd = rsqrtf(var + LNEPS);
        int dst = dstl[r];
        #pragma unroll
        for (int ni = 0; ni < 4; ++ni) {
            int col = wn * 64 + ni * 16 + c16;
            float v = acc[ni][r];
            outp[(size_t)dst * CH + col] = f2bf(v);
            ln_out[(size_t)dst * CH + col] = f2bf((v - mean) * rstd * gl[ni] + bl[ni]);
        }
    }
}

// ---- fused MLP with register-prefetched weights ----
__global__ __launch_bounds__(512, 2) void mlp_fused(
    const u16* __restrict__ A, const u16* __restrict__ W1,
    const float* __restrict__ b1, const u16* __restrict__ W2,
    const float* __restrict__ b2, const u16* __restrict__ residb,
    float* __restrict__ outp)
{
    __shared__ u16 As[4][64][32];    // 16 KB
    __shared__ u16 Bs[4][128][32];   // 32 KB
    __shared__ u16 Hs[4][64][40];    // 20 KB

    int tid = threadIdx.x, w = tid >> 6, l = tid & 63;
    int c16 = l & 15, g4 = l >> 4;
    int m0 = blockIdx.x * 64;
    int wm = w & 3, wn = w >> 2;
    int srow = tid >> 4, sc8 = tid & 15;

    u16x8 wv[4];
    #pragma unroll
    for (int p = 0; p < 4; ++p)
        wv[p] = *(const u16x8*)&W1[(size_t)(srow + p * 32) * 128 + sc8 * 8];
    #pragma unroll
    for (int p = 0; p < 2; ++p) {
        int row = srow + p * 32;
        u16x8 v = *(const u16x8*)&A[(size_t)(m0 + row) * 128 + sc8 * 8];
        *(u16x8*)&As[sc8 >> 2][row][(sc8 & 3) * 8] = v;
    }

    f32x4 acc2[4] = {};
    for (int ch = 0; ch < 4; ++ch) {
        #pragma unroll
        for (int p = 0; p < 4; ++p)
            *(u16x8*)&Bs[sc8 >> 2][srow + p * 32][(sc8 & 3) * 8] = wv[p];
        __syncthreads();

        u16x8 wv2[4];
        #pragma unroll
        for (int p = 0; p < 4; ++p)
            wv2[p] = *(const u16x8*)&W2[(size_t)(srow + p * 32) * 512 + ch * 128 + sc8 * 8];

        f32x4 hacc[4] = {};
        #pragma unroll
        for (int kc = 0; kc < 4; ++kc) {
            s16x8 af = __builtin_bit_cast(s16x8,
                *(const u16x8*)&As[kc][wm * 16 + c16][g4 * 8]);
            #pragma unroll
            for (int ni = 0; ni < 4; ++ni) {
                s16x8 bf = __builtin_bit_cast(s16x8,
                    *(const u16x8*)&Bs[kc][wn * 64 + ni * 16 + c16][g4 * 8]);
                hacc[ni] = mfma16(af, bf, hacc[ni]);
            }
        }
        #pragma unroll
        for (int r = 0; r < 4; ++r) {
            int row = wm * 16 + g4 * 4 + r;
            #pragma unroll
            for (int ni = 0; ni < 4; ++ni) {
                int col = wn * 64 + ni * 16 + c16;
                float v = hacc[ni][r] + b1[ch * 128 + col];
                v = 0.5f * v * (1.f + erff(v * 0.70710678118654752f));
                Hs[col >> 5][row][col & 31] = f2bf(v);
            }
        }
        __syncthreads();

        #pragma unroll
        for (int p = 0; p < 4; ++p)
            *(u16x8*)&Bs[sc8 >> 2][srow + p * 32][(sc8 & 3) * 8] = wv2[p];
        __syncthreads();

        if (ch < 3) {
            #pragma unroll
            for (int p = 0; p < 4; ++p)
                wv[p] = *(const u16x8*)&W1[(size_t)((ch + 1) * 128 + srow + p * 32) * 128 + sc8 * 8];
        }

        #pragma unroll
        for (int kc = 0; kc < 4; ++kc) {
            s16x8 af = __builtin_bit_cast(s16x8,
                *(const u16x8*)&Hs[kc][wm * 16 + c16][g4 * 8]);
            #pragma unroll
            for (int ni = 0; ni < 4; ++ni) {
                s16x8 bf = __builtin_bit_cast(s16x8,
                    *(const u16x8*)&Bs[kc][wn * 64 + ni * 16 + c16][g4 * 8]);
                acc2[ni] = mfma16(af, bf, acc2[ni]);
            }
        }
        if (ch < 3) __syncthreads();
    }

    #pragma unroll
    for (int r = 0; r < 4; ++r) {
        int m = m0 + wm * 16 + g4 * 4 + r;
        #pragma unroll
        for (int ni = 0; ni < 4; ++ni) {
            int col = wn * 64 + ni * 16 + c16;
            float v = acc2[ni][r] + b2[col];
            outp[(size_t)m * CH + col] = v + bf2f(residb[(size_t)m * CH + col]);
        }
    }
}

// ---- bias+mask table, f32, MFMA C-fragment layout: [hw][t][nt=26][lane][r] ----
__global__ __launch_bounds__(64) void bias_k(
    const float* __restrict__ rpb, float* __restrict__ biasT2)
{
    int nt = blockIdx.x;
    int t  = blockIdx.y;
    int hw = blockIdx.z;
    int l  = threadIdx.x;
    int head = hw >> 2, wt = hw & 3;
    int bh7 = wt >> 1, bw7 = wt & 1;
    int j = nt * 16 + (l & 15);
    int rb = t * 16 + (l >> 4) * 4;
    f32x4 outv;
    #pragma unroll
    for (int r = 0; r < 4; ++r) {
        int i = rb + r; if (i > NTOK - 1) i = NTOK - 1;
        float v;
        if (j >= NTOK) v = -100.f;
        else {
            int di = i / 49, ri = i - di * 49, hi = ri / 7, wi = ri - hi * 7;
            int dj = j / 49, rj = j - dj * 49, hj = rj / 7, wj = rj - hj * 7;
            int bidx = (di - dj + 7) * 169 + (hi - hj + 6) * 13 + (wi - wj + 6);
            v = rpb[bidx * NHEADS + head];
            int regi = (bh7 ? (hi < 4 ? 1 : 2) : 0) * 3 + (bw7 ? (wi < 4 ? 1 : 2) : 0);
            int regj = (bh7 ? (hj < 4 ? 1 : 2) : 0) * 3 + (bw7 ? (wj < 4 ? 1 : 2) : 0);
            if (regi != regj) v -= 100.f;
        }
        outv[r] = v;
    }
    *(f32x4*)&biasT2[((((size_t)hw * 25 + t) * 26 + nt) << 8) + (l << 2)] = outv;
}

// ---- flash-strip MFMA attention, 8 waves/block, THREE-tile interleaved ----
__global__ __launch_bounds__(512, 4) void attn_mfma(
    const u16* __restrict__ Qb, const float* __restrict__ biasT2,
    u16* __restrict__ O)
{
    __shared__ u16 Vt[32][420];
    __shared__ u16 Pst[8][3][16][40];

    int bid = blockIdx.x;
    int win = bid >> 2, head = bid & 3;
    int tid = threadIdx.x, w = tid >> 6, l = tid & 63;
    int c16 = l & 15, g4 = l >> 4;

    const size_t qbase = (size_t)win * NTOK * 384;
    for (int e = tid; e < 1600; e += 512) {
        int j = e >> 2, d0 = (e & 3) * 8;
        u16x8 vv = {0, 0, 0, 0, 0, 0, 0, 0};
        if (j < NTOK)
            vv = *(const u16x8*)&Qb[qbase + (size_t)j * 384 + 256 + head * 32 + d0];
        #pragma unroll
        for (int i = 0; i < 8; ++i) Vt[d0 + i][j] = vv[i];
    }
    if (tid < 32 * 16) Vt[tid >> 4][400 + (tid & 15)] = 0;
    __syncthreads();

    int wIdx = win & 63;
    int wt = (((wIdx >> 3) == 7) ? 2 : 0) + (((wIdx & 7) == 7) ? 1 : 0);
    const float* bt = biasT2 + (((size_t)(head * 4 + wt) * 25 * 26) << 8) + (l << 2);
    const u16* kroot = Qb + qbase + 128 + head * 32 + g4 * 8;
    u16 (*myPA)[40] = Pst[w][0];
    u16 (*myPB)[40] = Pst[w][1];
    u16 (*myPC)[40] = Pst[w][2];

    {
        int tA = w, tB = w + 8, tC = w + 16;
        s16x8 qfragA = __builtin_bit_cast(s16x8,
            *(const u16x8*)&Qb[qbase + (size_t)(tA * 16 + c16) * 384 + head * 32 + g4 * 8]);
        s16x8 qfragB = __builtin_bit_cast(s16x8,
            *(const u16x8*)&Qb[qbase + (size_t)(tB * 16 + c16) * 384 + head * 32 + g4 * 8]);
        s16x8 qfragC = __builtin_bit_cast(s16x8,
            *(const u16x8*)&Qb[qbase + (size_t)(tC * 16 + c16) * 384 + head * 32 + g4 * 8]);
        const float* bttA = bt + (((size_t)tA * 26) << 8);
        const float* bttB = bt + (((size_t)tB * 26) << 8);
        const float* bttC = bt + (((size_t)tC * 26) << 8);

        float l4A[4] = {0.f,0.f,0.f,0.f}, l4B[4] = {0.f,0.f,0.f,0.f}, l4C[4] = {0.f,0.f,0.f,0.f};
        f32x4 oaccA0 = {0.f,0.f,0.f,0.f}, oaccA1 = {0.f,0.f,0.f,0.f};
        f32x4 oaccB0 = {0.f,0.f,0.f,0.f}, oaccB1 = {0.f,0.f,0.f,0.f};
        f32x4 oaccC0 = {0.f,0.f,0.f,0.f}, oaccC1 = {0.f,0.f,0.f,0.f};

        for (int jb = 0; jb < 13; ++jb) {
            int kr0 = jb * 32 + c16;      if (kr0 > NTOK - 1) kr0 = NTOK - 1;
            int kr1 = jb * 32 + 16 + c16; if (kr1 > NTOK - 1) kr1 = NTOK - 1;
            s16x8 kf0 = __builtin_bit_cast(s16x8, *(const u16x8*)&kroot[(size_t)kr0 * 384]);
            s16x8 kf1 = __builtin_bit_cast(s16x8, *(const u16x8*)&kroot[(size_t)kr1 * 384]);
            f32x4 sA0 = mfma16(qfragA, kf0, *(const f32x4*)(bttA + (((size_t)(jb*2+0)) << 8)));
            f32x4 sA1 = mfma16(qfragA, kf1, *(const f32x4*)(bttA + (((size_t)(jb*2+1)) << 8)));
            f32x4 sB0 = mfma16(qfragB, kf0, *(const f32x4*)(bttB + (((size_t)(jb*2+0)) << 8)));
            f32x4 sB1 = mfma16(qfragB, kf1, *(const f32x4*)(bttB + (((size_t)(jb*2+1)) << 8)));
            f32x4 sC0 = mfma16(qfragC, kf0, *(const f32x4*)(bttC + (((size_t)(jb*2+0)) << 8)));
            f32x4 sC1 = mfma16(qfragC, kf1, *(const f32x4*)(bttC + (((size_t)(jb*2+1)) << 8)));
            #pragma unroll
            for (int r = 0; r < 4; ++r) {
                float p0 = exp2f(sA0[r] * 1.44269504f);
                float p1 = exp2f(sA1[r] * 1.44269504f);
                l4A[r] += p0 + p1;
                myPA[g4 * 4 + r][c16]      = f2bf(p0);
                myPA[g4 * 4 + r][16 + c16] = f2bf(p1);
            }
            #pragma unroll
            for (int r = 0; r < 4; ++r) {
                float p0 = exp2f(sB0[r] * 1.44269504f);
                float p1 = exp2f(sB1[r] * 1.44269504f);
                l4B[r] += p0 + p1;
                myPB[g4 * 4 + r][c16]      = f2bf(p0);
                myPB[g4 * 4 + r][16 + c16] = f2bf(p1);
            }
            #pragma unroll
            for (int r = 0; r < 4; ++r) {
                float p0 = exp2f(sC0[r] * 1.44269504f);
                float p1 = exp2f(sC1[r] * 1.44269504f);
                l4C[r] += p0 + p1;
                myPC[g4 * 4 + r][c16]      = f2bf(p0);
                myPC[g4 * 4 + r][16 + c16] = f2bf(p1);
            }
            s16x8 paA = __builtin_bit_cast(s16x8, *(const u16x8*)&myPA[c16][g4 * 8]);
            s16x8 paB = __builtin_bit_cast(s16x8, *(const u16x8*)&myPB[c16][g4 * 8]);
            s16x8 paC = __builtin_bit_cast(s16x8, *(const u16x8*)&myPC[c16][g4 * 8]);
            s16x8 vb0 = __builtin_bit_cast(s16x8, *(const u16x8*)&Vt[c16][jb * 32 + g4 * 8]);
            s16x8 vb1 = __builtin_bit_cast(s16x8, *(const u16x8*)&Vt[16 + c16][jb * 32 + g4 * 8]);
            oaccA0 = mfma16(paA, vb0, oaccA0);
            oaccA1 = mfma16(paA, vb1, oaccA1);
            oaccB0 = mfma16(paB, vb0, oaccB0);
            oaccB1 = mfma16(paB, vb1, oaccB1);
            oaccC0 = mfma16(paC, vb0, oaccC0);
            oaccC1 = mfma16(paC, vb1, oaccC1);
        }

        #pragma unroll
        for (int r = 0; r < 4; ++r) {
            #pragma unroll
            for (int o = 1; o <= 8; o <<= 1) {
                l4A[r] += __shfl_xor(l4A[r], o);
                l4B[r] += __shfl_xor(l4B[r], o);
                l4C[r] += __shfl_xor(l4C[r], o);
            }
            l4A[r] = 1.f / l4A[r];
            l4B[r] = 1.f / l4B[r];
            l4C[r] = 1.f / l4C[r];
        }
        #pragma unroll
        for (int r = 0; r < 4; ++r) {
            int qA = tA * 16 + g4 * 4 + r;
            int qB = tB * 16 + g4 * 4 + r;
            int qC = tC * 16 + g4 * 4 + r;
            size_t oA = ((size_t)(win * NTOK + qA)) * CH + head * 32 + c16;
            size_t oB = ((size_t)(win * NTOK + qB)) * CH + head * 32 + c16;
            size_t oC = ((size_t)(win * NTOK + qC)) * CH + head * 32 + c16;
            O[oA]      = f2bf(oaccA0[r] * l4A[r]);
            O[oA + 16] = f2bf(oaccA1[r] * l4A[r]);
            O[oB]      = f2bf(oaccB0[r] * l4B[r]);
            O[oB + 16] = f2bf(oaccB1[r] * l4B[r]);
            O[oC]      = f2bf(oaccC0[r] * l4C[r]);
            O[oC + 16] = f2bf(oaccC1[r] * l4C[r]);
        }
    }

    if (w == 0) {
        int t = 24;
        int row0 = t * 16;
        int qr = row0 + c16; if (qr > NTOK - 1) qr = NTOK - 1;
        s16x8 afrag = __builtin_bit_cast(s16x8,
            *(const u16x8*)&Qb[qbase + (size_t)qr * 384 + head * 32 + g4 * 8]);
        const float* btt = bt + (((size_t)t * 26) << 8);

        float l4[4] = {0.f, 0.f, 0.f, 0.f};
        f32x4 oacc[2] = {{0.f,0.f,0.f,0.f},{0.f,0.f,0.f,0.f}};

        for (int jb = 0; jb < 13; ++jb) {
            f32x4 s[2];
            #pragma unroll
            for (int kk = 0; kk < 2; ++kk) {
                f32x4 cb = *(const f32x4*)(btt + (((size_t)(jb * 2 + kk)) << 8));
                int kr = jb * 32 + kk * 16 + c16;
                if (kr > NTOK - 1) kr = NTOK - 1;
                s16x8 bfrag = __builtin_bit_cast(s16x8,
                    *(const u16x8*)&kroot[(size_t)kr * 384]);
                s[kk] = mfma16(afrag, bfrag, cb);
            }
            #pragma unroll
            for (int kk = 0; kk < 2; ++kk)
                #pragma unroll
                for (int r = 0; r < 4; ++r) {
                    float p = exp2f(s[kk][r] * 1.44269504f);
                    l4[r] += p;
                    myPA[g4 * 4 + r][kk * 16 + c16] = f2bf(p);
                }
            s16x8 pa = __builtin_bit_cast(s16x8, *(const u16x8*)&myPA[c16][g4 * 8]);
            #pragma unroll
            for (int nd = 0; nd < 2; ++nd) {
                s16x8 vb = __builtin_bit_cast(s16x8,
                    *(const u16x8*)&Vt[nd * 16 + c16][jb * 32 + g4 * 8]);
                oacc[nd] = mfma16(pa, vb, oacc[nd]);
            }
        }

        #pragma unroll
        for (int r = 0; r < 4; ++r) {
            #pragma unroll
            for (int o = 1; o <= 8; o <<= 1)
                l4[r] += __shfl_xor(l4[r], o);
            l4[r] = 1.f / l4[r];
        }
        #pragma unroll
        for (int nd = 0; nd < 2; ++nd)
            #pragma unroll
            for (int r = 0; r < 4; ++r) {
                int qrow = row0 + g4 * 4 + r;
                if (qrow < NTOK)
                    O[((size_t)(win * NTOK + qrow)) * CH + head * 32 + nd * 16 + c16]
                        = f2bf(oacc[nd][r] * l4[r]);
            }
    }
}

extern "C" void kernel_launch(void* const* d_in, const int* in_sizes, int n_in,
                              void* d_out, int out_size, void* d_ws, size_t ws_size,
                              hipStream_t stream) {
    const float* x      = (const float*)d_in[0];
    const float* n1g    = (const float*)d_in[1];
    const float* n1b    = (const float*)d_in[2];
    const float* qkv_w  = (const float*)d_in[3];
    const float* qkv_b  = (const float*)d_in[4];
    const float* proj_w = (const float*)d_in[5];
    const float* proj_b = (const float*)d_in[6];
    const float* rpb    = (const float*)d_in[7];
    const float* n2g    = (const float*)d_in[8];
    const float* n2b    = (const float*)d_in[9];
    const float* fc1_w  = (const float*)d_in[10];
    const float* fc1_b  = (const float*)d_in[11];
    const float* fc2_w  = (const float*)d_in[12];
    const float* fc2_b  = (const float*)d_in[13];
    float* out = (float*)d_out;

    char* ws = (char*)d_ws;
    size_t off = 0;
    u16* A_bf  = (u16*)(ws + off);  off += (size_t)TOK * 128 * 2;   // LN2 out / biasT2 overlay
    u16* Qb_bf = (u16*)(ws + off);  off += (size_t)TOK * 384 * 2;
    u16* O_bf  = (u16*)(ws + off);  off += (size_t)TOK * 128 * 2;
    u16* R_bf  = (u16*)(ws + off);  off += (size_t)TOK * 128 * 2;   // bf16 residual trunk
    u16* qkvT  = (u16*)(ws + off);  off += 384 * 128 * 2;
    u16* projT = (u16*)(ws + off);  off += 128 * 128 * 2;
    u16* fc1T  = (u16*)(ws + off);  off += 512 * 128 * 2;
    u16* fc2T  = (u16*)(ws + off);  off += 128 * 512 * 2;
    float* biasT2 = (float*)A_bf;   // overlay; dead once proj's LN2 rewrites A_bf

    // 0. weight transposes (+bf16), QSCALE folded into Wq
    hipLaunchKernelGGL(convT, dim3(384/32, 128/32), dim3(256), 0, stream, qkv_w,  qkvT, 128, 384, 128);
    hipLaunchKernelGGL(convT, dim3(128/32, 128/32), dim3(256), 0, stream, proj_w, projT, 128, 128, 0);
    hipLaunchKernelGGL(convT, dim3(512/32, 128/32), dim3(256), 0, stream, fc1_w,  fc1T, 128, 512, 0);
    hipLaunchKernelGGL(convT, dim3(128/32, 512/32), dim3(256), 0, stream, fc2_w,  fc2T, 512, 128, 0);
    // 1. fused LN1 + shift + qkv GEMM (single pass over x, 3 weight tiles)
    hipLaunchKernelGGL(qkv_ln, dim3(TOK/64), dim3(512), 0, stream,
                       x, qkvT, qkv_b, Qb_bf, n1g, n1b);
    // 1b. bias+mask table (overlay in A_bf)
    hipLaunchKernelGGL(bias_k, dim3(26, 25, 16), dim3(64), 0, stream, rpb, biasT2);
    // 2. three-tile interleaved flash attention -> bf16
    hipLaunchKernelGGL(attn_mfma, dim3(NWIN * NHEADS), dim3(512), 0, stream,
                       Qb_bf, biasT2, O_bf);
    // 3. proj GEMM + unshift + residual -> bf16 R, fused LN2 -> bf16 A_bf
    hipLaunchKernelGGL(proj_ln, dim3(TOK/64), dim3(512), 0, stream,
                       O_bf, projT, proj_b, R_bf, x, n2g, n2b, A_bf);
    // 4. fused MLP (prefetched): fc1 + GELU + fc2 + residual -> f32 out
    hipLaunchKernelGGL(mlp_fused, dim3(TOK/64), dim3(512), 0, stream,
                       A_bf, fc1T, fc1_b, fc2T, fc2_b, R_bf, out);
}

// Round 19
// 143.508 us; speedup vs baseline: 1.5967x; 1.0092x over previous
//
#include <hip/hip_runtime.h>
#include <math.h>

// ---- problem constants ----
#define TOK    50176      // 2*8*56*56 tokens
#define CH     128
#define NWIN   128        // B * 64 windows
#define NTOK   392        // 8*7*7 tokens per window
#define NHEADS 4
#define QSCALE 0.17677669529663687f   // 32^-0.5
#define LNEPS  1e-3f

typedef unsigned short u16;
typedef unsigned int   u32;
typedef u16   u16x4  __attribute__((ext_vector_type(4)));
typedef u16   u16x8  __attribute__((ext_vector_type(8)));
typedef short s16x8  __attribute__((ext_vector_type(8)));
typedef float f32x4  __attribute__((ext_vector_type(4)));

__device__ __forceinline__ float bf2f(u16 u) {
    return __uint_as_float(((u32)u) << 16);
}
__device__ __forceinline__ u16 f2bf(float f) {
    u32 u = __float_as_uint(f);
    return (u16)((u + 0x7fffu + ((u >> 16) & 1u)) >> 16);
}
__device__ __forceinline__ f32x4 mfma16(s16x8 a, s16x8 b, f32x4 c) {
    return __builtin_amdgcn_mfma_f32_16x16x32_bf16(a, b, c, 0, 0, 0);
}

// token m in window layout -> flat token index in original layout (+3 roll)
__device__ __forceinline__ int src_index(int m) {
    int b = m / NTOK, t = m - b * NTOK;
    int batch = b >> 6, wIdx = b & 63;
    int bh = wIdx >> 3, bw = wIdx & 7;
    int d = t / 49, rem = t - d * 49;
    int h7 = rem / 7, w7 = rem - h7 * 7;
    int h = bh * 7 + h7 + 3; if (h >= 56) h -= 56;
    int w = bw * 7 + w7 + 3; if (w >= 56) w -= 56;
    return ((batch * 8 + d) * 56 + h) * 56 + w;
}

// ---- batched weight transpose + f32->bf16: all 4 weights, one launch ----
__global__ __launch_bounds__(256) void convT_all(
    const float* __restrict__ qkv_w, const float* __restrict__ proj_w,
    const float* __restrict__ fc1_w, const float* __restrict__ fc2_w,
    u16* __restrict__ qkvT, u16* __restrict__ projT,
    u16* __restrict__ fc1T, u16* __restrict__ fc2T)
{
    const float* src; u16* dst; int K, N, scaleN;
    switch (blockIdx.z) {
    case 0:  src = qkv_w;  dst = qkvT;  K = 128; N = 384; scaleN = 128; break;
    case 1:  src = proj_w; dst = projT; K = 128; N = 128; scaleN = 0;   break;
    case 2:  src = fc1_w;  dst = fc1T;  K = 128; N = 512; scaleN = 0;   break;
    default: src = fc2_w;  dst = fc2T;  K = 512; N = 128; scaleN = 0;   break;
    }
    int n0 = blockIdx.x * 32, k0 = blockIdx.y * 32;
    if (n0 >= N || k0 >= K) return;
    __shared__ float t[32][33];
    int tx = threadIdx.x & 31, ty = threadIdx.x >> 5;   // ty 0..7
    #pragma unroll
    for (int r = 0; r < 4; ++r)
        t[ty + r * 8][tx] = src[(size_t)(k0 + ty + r * 8) * N + n0 + tx];
    __syncthreads();
    #pragma unroll
    for (int r = 0; r < 4; ++r) {
        int n = n0 + ty + r * 8;
        float sc = (n < scaleN) ? QSCALE : 1.f;
        dst[(size_t)n * K + k0 + tx] = f2bf(t[tx][ty + r * 8] * sc);
    }
}

// ---- fused LN1 + qkv GEMM, one block per 64-token tile, loops 3 n-tiles ----
__global__ __launch_bounds__(512, 6) void qkv_ln(
    const float* __restrict__ x, const u16* __restrict__ W,
    const float* __restrict__ bias, u16* __restrict__ outp,
    const float* __restrict__ lng, const float* __restrict__ lnb)
{
    __shared__ u16 As[4][64][32];    // 16 KB
    __shared__ u16 Bs[4][128][32];   // 32 KB

    int tid = threadIdx.x, l = tid & 63;
    int c16 = l & 15, g4 = l >> 4;
    int m0 = blockIdx.x * 64;
    int w = tid >> 6, wm = w & 3, wn = w >> 2;
    int srow = tid >> 4, sc8 = tid & 15;

    u16x8 wv[4];
    #pragma unroll
    for (int p = 0; p < 4; ++p)
        wv[p] = *(const u16x8*)&W[(size_t)(srow + p * 32) * 128 + sc8 * 8];

    #pragma unroll
    for (int p = 0; p < 2; ++p) {
        int row = srow + p * 32;
        int src = src_index(m0 + row);
        f32x4 x0 = *(const f32x4*)&x[(size_t)src * CH + sc8 * 8];
        f32x4 x1 = *(const f32x4*)&x[(size_t)src * CH + sc8 * 8 + 4];
        float s = ((x0[0] + x0[1]) + (x0[2] + x0[3]))
                + ((x1[0] + x1[1]) + (x1[2] + x1[3]));
        float q = ((x0[0]*x0[0] + x0[1]*x0[1]) + (x0[2]*x0[2] + x0[3]*x0[3]))
                + ((x1[0]*x1[0] + x1[1]*x1[1]) + (x1[2]*x1[2] + x1[3]*x1[3]));
        #pragma unroll
        for (int o = 1; o <= 8; o <<= 1) {
            s += __shfl_xor(s, o);
            q += __shfl_xor(q, o);
        }
        float mean = s * (1.f / CH);
        float var  = q * (1.f / CH) - mean * mean;
        float rstd = rsqrtf(var + LNEPS);
        u16x8 av;
        #pragma unroll
        for (int i = 0; i < 4; ++i)
            av[i] = f2bf((x0[i] - mean) * rstd * lng[sc8 * 8 + i] + lnb[sc8 * 8 + i]);
        #pragma unroll
        for (int i = 0; i < 4; ++i)
            av[4 + i] = f2bf((x1[i] - mean) * rstd * lng[sc8 * 8 + 4 + i] + lnb[sc8 * 8 + 4 + i]);
        *(u16x8*)&As[sc8 >> 2][row][(sc8 & 3) * 8] = av;
    }

    for (int nt = 0; nt < 3; ++nt) {
        #pragma unroll
        for (int p = 0; p < 4; ++p)
            *(u16x8*)&Bs[sc8 >> 2][srow + p * 32][(sc8 & 3) * 8] = wv[p];
        __syncthreads();
        if (nt < 2) {
            #pragma unroll
            for (int p = 0; p < 4; ++p)
                wv[p] = *(const u16x8*)&W[(size_t)((nt + 1) * 128 + srow + p * 32) * 128 + sc8 * 8];
        }
        f32x4 acc[4] = {};
        #pragma unroll
        for (int kc = 0; kc < 4; ++kc) {
            s16x8 af = __builtin_bit_cast(s16x8,
                *(const u16x8*)&As[kc][wm * 16 + c16][g4 * 8]);
            #pragma unroll
            for (int ni = 0; ni < 4; ++ni) {
                s16x8 bf = __builtin_bit_cast(s16x8,
                    *(const u16x8*)&Bs[kc][wn * 64 + ni * 16 + c16][g4 * 8]);
                acc[ni] = mfma16(af, bf, acc[ni]);
            }
        }
        #pragma unroll
        for (int r = 0; r < 4; ++r) {
            int m = m0 + wm * 16 + g4 * 4 + r;
            #pragma unroll
            for (int ni = 0; ni < 4; ++ni) {
                int col = nt * 128 + wn * 64 + ni * 16 + c16;
                float v = acc[ni][r] + bias[col] * (col < 128 ? QSCALE : 1.f);
                outp[(size_t)m * 384 + col] = f2bf(v);
            }
        }
        if (nt < 2) __syncthreads();
    }
}

// ---- proj GEMM + residual scatter -> bf16 R + fused LN2 -> bf16 ln_out ----
__global__ __launch_bounds__(512, 6) void proj_ln(
    const u16* __restrict__ A, const u16* __restrict__ W,
    const float* __restrict__ bias, u16* __restrict__ outp,
    const float* __restrict__ resid,
    const float* __restrict__ lng, const float* __restrict__ lnb,
    u16* __restrict__ ln_out)
{
    __shared__ u16 As[4][64][32];
    __shared__ u16 Bs[4][128][32];
    __shared__ float lnred[2][4][16][2];

    int tid = threadIdx.x, w = tid >> 6, l = tid & 63;
    int c16 = l & 15, g4 = l >> 4;
    int m0 = blockIdx.x * 64;
    int wm = w & 3, wn = w >> 2;

    #pragma unroll
    for (int p = 0; p < 2; ++p) {
        int e = tid + p * 512, row = e >> 4, c8 = e & 15;
        u16x8 v = *(const u16x8*)&A[(size_t)(m0 + row) * 128 + c8 * 8];
        *(u16x8*)&As[c8 >> 2][row][(c8 & 3) * 8] = v;
    }
    #pragma unroll
    for (int p = 0; p < 4; ++p) {
        int e = tid + p * 512, row = e >> 4, c8 = e & 15;
        u16x8 v = *(const u16x8*)&W[(size_t)row * 128 + c8 * 8];
        *(u16x8*)&Bs[c8 >> 2][row][(c8 & 3) * 8] = v;
    }
    __syncthreads();

    f32x4 acc[4] = {};
    #pragma unroll
    for (int kc = 0; kc < 4; ++kc) {
        s16x8 af = __builtin_bit_cast(s16x8,
            *(const u16x8*)&As[kc][wm * 16 + c16][g4 * 8]);
        #pragma unroll
        for (int ni = 0; ni < 4; ++ni) {
            s16x8 bf = __builtin_bit_cast(s16x8,
                *(const u16x8*)&Bs[kc][wn * 64 + ni * 16 + c16][g4 * 8]);
            acc[ni] = mfma16(af, bf, acc[ni]);
        }
    }

    float psum[4], psq[4];
    int dstl[4];
    #pragma unroll
    for (int r = 0; r < 4; ++r) {
        int m = m0 + wm * 16 + g4 * 4 + r;
        int dst = src_index(m);
        dstl[r] = dst;
        float s = 0.f, q = 0.f;
        #pragma unroll
        for (int ni = 0; ni < 4; ++ni) {
            int col = wn * 64 + ni * 16 + c16;
            float v = acc[ni][r] + bias[col] + resid[(size_t)dst * CH + col];
            acc[ni][r] = v;
            s += v; q += v * v;
        }
        psum[r] = s; psq[r] = q;
    }
    #pragma unroll
    for (int o = 1; o <= 8; o <<= 1)
        #pragma unroll
        for (int r = 0; r < 4; ++r) {
            psum[r] += __shfl_xor(psum[r], o);
            psq[r]  += __shfl_xor(psq[r], o);
        }
    if (c16 == 0) {
        #pragma unroll
        for (int r = 0; r < 4; ++r) {
            int rl = g4 * 4 + r;
            lnred[wn][wm][rl][0] = psum[r];
            lnred[wn][wm][rl][1] = psq[r];
        }
    }
    __syncthreads();
    float gl[4], bl[4];
    #pragma unroll
    for (int ni = 0; ni < 4; ++ni) {
        int col = wn * 64 + ni * 16 + c16;
        gl[ni] = lng[col]; bl[ni] = lnb[col];
    }
    #pragma unroll
    for (int r = 0; r < 4; ++r) {
        int rl = g4 * 4 + r;
        float s = lnred[0][wm][rl][0] + lnred[1][wm][rl][0];
        float q = lnred[0][wm][rl][1] + lnred[1][wm][rl][1];
        float mean = s * (1.f / CH);
        float var  = q * (1.f / CH) - mean * mean;
        float rstd = rsqrtf(var + LNEPS);
        int dst = dstl[r];
        #pragma unroll
        for (int ni = 0; ni < 4; ++ni) {
            int col = wn * 64 + ni * 16 + c16;
            float v = acc[ni][r];
            outp[(size_t)dst * CH + col] = f2bf(v);
            ln_out[(size_t)dst * CH + col] = f2bf((v - mean) * rstd * gl[ni] + bl[ni]);
        }
    }
}

// ---- fused MLP with register-prefetched weights ----
__global__ __launch_bounds__(512, 2) void mlp_fused(
    const u16* __restrict__ A, const u16* __restrict__ W1,
    const float* __restrict__ b1, const u16* __restrict__ W2,
    const float* __restrict__ b2, const u16* __restrict__ residb,
    float* __restrict__ outp)
{
    __shared__ u16 As[4][64][32];
    __shared__ u16 Bs[4][128][32];
    __shared__ u16 Hs[4][64][40];

    int tid = threadIdx.x, w = tid >> 6, l = tid & 63;
    int c16 = l & 15, g4 = l >> 4;
    int m0 = blockIdx.x * 64;
    int wm = w & 3, wn = w >> 2;
    int srow = tid >> 4, sc8 = tid & 15;

    u16x8 wv[4];
    #pragma unroll
    for (int p = 0; p < 4; ++p)
        wv[p] = *(const u16x8*)&W1[(size_t)(srow + p * 32) * 128 + sc8 * 8];
    #pragma unroll
    for (int p = 0; p < 2; ++p) {
        int row = srow + p * 32;
        u16x8 v = *(const u16x8*)&A[(size_t)(m0 + row) * 128 + sc8 * 8];
        *(u16x8*)&As[sc8 >> 2][row][(sc8 & 3) * 8] = v;
    }

    f32x4 acc2[4] = {};
    for (int ch = 0; ch < 4; ++ch) {
        #pragma unroll
        for (int p = 0; p < 4; ++p)
            *(u16x8*)&Bs[sc8 >> 2][srow + p * 32][(sc8 & 3) * 8] = wv[p];
        __syncthreads();

        u16x8 wv2[4];
        #pragma unroll
        for (int p = 0; p < 4; ++p)
            wv2[p] = *(const u16x8*)&W2[(size_t)(srow + p * 32) * 512 + ch * 128 + sc8 * 8];

        f32x4 hacc[4] = {};
        #pragma unroll
        for (int kc = 0; kc < 4; ++kc) {
            s16x8 af = __builtin_bit_cast(s16x8,
                *(const u16x8*)&As[kc][wm * 16 + c16][g4 * 8]);
            #pragma unroll
            for (int ni = 0; ni < 4; ++ni) {
                s16x8 bf = __builtin_bit_cast(s16x8,
                    *(const u16x8*)&Bs[kc][wn * 64 + ni * 16 + c16][g4 * 8]);
                hacc[ni] = mfma16(af, bf, hacc[ni]);
            }
        }
        #pragma unroll
        for (int r = 0; r < 4; ++r) {
            int row = wm * 16 + g4 * 4 + r;
            #pragma unroll
            for (int ni = 0; ni < 4; ++ni) {
                int col = wn * 64 + ni * 16 + c16;
                float v = hacc[ni][r] + b1[ch * 128 + col];
                v = 0.5f * v * (1.f + erff(v * 0.70710678118654752f));
                Hs[col >> 5][row][col & 31] = f2bf(v);
            }
        }
        __syncthreads();

        #pragma unroll
        for (int p = 0; p < 4; ++p)
            *(u16x8*)&Bs[sc8 >> 2][srow + p * 32][(sc8 & 3) * 8] = wv2[p];
        __syncthreads();

        if (ch < 3) {
            #pragma unroll
            for (int p = 0; p < 4; ++p)
                wv[p] = *(const u16x8*)&W1[(size_t)((ch + 1) * 128 + srow + p * 32) * 128 + sc8 * 8];
        }

        #pragma unroll
        for (int kc = 0; kc < 4; ++kc) {
            s16x8 af = __builtin_bit_cast(s16x8,
                *(const u16x8*)&Hs[kc][wm * 16 + c16][g4 * 8]);
            #pragma unroll
            for (int ni = 0; ni < 4; ++ni) {
                s16x8 bf = __builtin_bit_cast(s16x8,
                    *(const u16x8*)&Bs[kc][wn * 64 + ni * 16 + c16][g4 * 8]);
                acc2[ni] = mfma16(af, bf, acc2[ni]);
            }
        }
        if (ch < 3) __syncthreads();
    }

    #pragma unroll
    for (int r = 0; r < 4; ++r) {
        int m = m0 + wm * 16 + g4 * 4 + r;
        #pragma unroll
        for (int ni = 0; ni < 4; ++ni) {
            int col = wn * 64 + ni * 16 + c16;
            float v = acc2[ni][r] + b2[col];
            outp[(size_t)m * CH + col] = v + bf2f(residb[(size_t)m * CH + col]);
        }
    }
}

// ---- bias+mask table, f32, MFMA C-fragment layout: [hw][t][nt=26][lane][r] ----
__global__ __launch_bounds__(64) void bias_k(
    const float* __restrict__ rpb, float* __restrict__ biasT2)
{
    int nt = blockIdx.x;
    int t  = blockIdx.y;
    int hw = blockIdx.z;
    int l  = threadIdx.x;
    int head = hw >> 2, wt = hw & 3;
    int bh7 = wt >> 1, bw7 = wt & 1;
    int j = nt * 16 + (l & 15);
    int rb = t * 16 + (l >> 4) * 4;
    f32x4 outv;
    #pragma unroll
    for (int r = 0; r < 4; ++r) {
        int i = rb + r; if (i > NTOK - 1) i = NTOK - 1;
        float v;
        if (j >= NTOK) v = -100.f;
        else {
            int di = i / 49, ri = i - di * 49, hi = ri / 7, wi = ri - hi * 7;
            int dj = j / 49, rj = j - dj * 49, hj = rj / 7, wj = rj - hj * 7;
            int bidx = (di - dj + 7) * 169 + (hi - hj + 6) * 13 + (wi - wj + 6);
            v = rpb[bidx * NHEADS + head];
            int regi = (bh7 ? (hi < 4 ? 1 : 2) : 0) * 3 + (bw7 ? (wi < 4 ? 1 : 2) : 0);
            int regj = (bh7 ? (hj < 4 ? 1 : 2) : 0) * 3 + (bw7 ? (wj < 4 ? 1 : 2) : 0);
            if (regi != regj) v -= 100.f;
        }
        outv[r] = v;
    }
    *(f32x4*)&biasT2[((((size_t)hw * 25 + t) * 26 + nt) << 8) + (l << 2)] = outv;
}

// ---- flash-strip MFMA attention, 8 waves, 3-tile interleave + wave-0 4th tile ----
__global__ __launch_bounds__(512, 4) void attn_mfma(
    const u16* __restrict__ Qb, const float* __restrict__ biasT2,
    u16* __restrict__ O)
{
    __shared__ u16 Vt[32][420];         // 26880 B, cols 400..415 zero
    __shared__ u16 Pst[8][3][16][40];   // 30720 B
    __shared__ u16 PstD[16][40];        // 1280 B (wave 0's 4th tile)

    int bid = blockIdx.x;
    int win = bid >> 2, head = bid & 3;
    int tid = threadIdx.x, w = tid >> 6, l = tid & 63;
    int c16 = l & 15, g4 = l >> 4;

    const size_t qbase = (size_t)win * NTOK * 384;
    for (int e = tid; e < 1600; e += 512) {
        int j = e >> 2, d0 = (e & 3) * 8;
        u16x8 vv = {0, 0, 0, 0, 0, 0, 0, 0};
        if (j < NTOK)
            vv = *(const u16x8*)&Qb[qbase + (size_t)j * 384 + 256 + head * 32 + d0];
        #pragma unroll
        for (int i = 0; i < 8; ++i) Vt[d0 + i][j] = vv[i];
    }
    if (tid < 32 * 16) Vt[tid >> 4][400 + (tid & 15)] = 0;
    __syncthreads();

    int wIdx = win & 63;
    int wt = (((wIdx >> 3) == 7) ? 2 : 0) + (((wIdx & 7) == 7) ? 1 : 0);
    const float* bt = biasT2 + (((size_t)(head * 4 + wt) * 25 * 26) << 8) + (l << 2);
    const u16* kroot = Qb + qbase + 128 + head * 32 + g4 * 8;
    u16 (*myPA)[40] = Pst[w][0];
    u16 (*myPB)[40] = Pst[w][1];
    u16 (*myPC)[40] = Pst[w][2];
    bool hasD = (w == 0);

    int tA = w, tB = w + 8, tC = w + 16;                 // rows < 384, clamp-free
    s16x8 qfragA = __builtin_bit_cast(s16x8,
        *(const u16x8*)&Qb[qbase + (size_t)(tA * 16 + c16) * 384 + head * 32 + g4 * 8]);
    s16x8 qfragB = __builtin_bit_cast(s16x8,
        *(const u16x8*)&Qb[qbase + (size_t)(tB * 16 + c16) * 384 + head * 32 + g4 * 8]);
    s16x8 qfragC = __builtin_bit_cast(s16x8,
        *(const u16x8*)&Qb[qbase + (size_t)(tC * 16 + c16) * 384 + head * 32 + g4 * 8]);
    const float* bttA = bt + (((size_t)tA * 26) << 8);
    const float* bttB = bt + (((size_t)tB * 26) << 8);
    const float* bttC = bt + (((size_t)tC * 26) << 8);
    // wave-0 4th tile: t = 24 (rows 384..399, clamped; bias -100 on pads)
    int qrD = 384 + c16; if (qrD > NTOK - 1) qrD = NTOK - 1;
    s16x8 qfragD = __builtin_bit_cast(s16x8,
        *(const u16x8*)&Qb[qbase + (size_t)qrD * 384 + head * 32 + g4 * 8]);
    const float* bttD = bt + (((size_t)24 * 26) << 8);

    float l4A[4] = {0.f,0.f,0.f,0.f}, l4B[4] = {0.f,0.f,0.f,0.f};
    float l4C[4] = {0.f,0.f,0.f,0.f}, l4D[4] = {0.f,0.f,0.f,0.f};
    f32x4 oaccA0 = {0.f,0.f,0.f,0.f}, oaccA1 = {0.f,0.f,0.f,0.f};
    f32x4 oaccB0 = {0.f,0.f,0.f,0.f}, oaccB1 = {0.f,0.f,0.f,0.f};
    f32x4 oaccC0 = {0.f,0.f,0.f,0.f}, oaccC1 = {0.f,0.f,0.f,0.f};
    f32x4 oaccD0 = {0.f,0.f,0.f,0.f}, oaccD1 = {0.f,0.f,0.f,0.f};

    for (int jb = 0; jb < 13; ++jb) {
        int kr0 = jb * 32 + c16;      if (kr0 > NTOK - 1) kr0 = NTOK - 1;
        int kr1 = jb * 32 + 16 + c16; if (kr1 > NTOK - 1) kr1 = NTOK - 1;
        s16x8 kf0 = __builtin_bit_cast(s16x8, *(const u16x8*)&kroot[(size_t)kr0 * 384]);
        s16x8 kf1 = __builtin_bit_cast(s16x8, *(const u16x8*)&kroot[(size_t)kr1 * 384]);
        f32x4 sA0 = mfma16(qfragA, kf0, *(const f32x4*)(bttA + (((size_t)(jb*2+0)) << 8)));
        f32x4 sA1 = mfma16(qfragA, kf1, *(const f32x4*)(bttA + (((size_t)(jb*2+1)) << 8)));
        f32x4 sB0 = mfma16(qfragB, kf0, *(const f32x4*)(bttB + (((size_t)(jb*2+0)) << 8)));
        f32x4 sB1 = mfma16(qfragB, kf1, *(const f32x4*)(bttB + (((size_t)(jb*2+1)) << 8)));
        f32x4 sC0 = mfma16(qfragC, kf0, *(const f32x4*)(bttC + (((size_t)(jb*2+0)) << 8)));
        f32x4 sC1 = mfma16(qfragC, kf1, *(const f32x4*)(bttC + (((size_t)(jb*2+1)) << 8)));
        #pragma unroll
        for (int r = 0; r < 4; ++r) {
            float p0 = exp2f(sA0[r] * 1.44269504f);
            float p1 = exp2f(sA1[r] * 1.44269504f);
            l4A[r] += p0 + p1;
            myPA[g4 * 4 + r][c16]      = f2bf(p0);
            myPA[g4 * 4 + r][16 + c16] = f2bf(p1);
        }
        #pragma unroll
        for (int r = 0; r < 4; ++r) {
            float p0 = exp2f(sB0[r] * 1.44269504f);
            float p1 = exp2f(sB1[r] * 1.44269504f);
            l4B[r] += p0 + p1;
            myPB[g4 * 4 + r][c16]      = f2bf(p0);
            myPB[g4 * 4 + r][16 + c16] = f2bf(p1);
        }
        #pragma unroll
        for (int r = 0; r < 4; ++r) {
            float p0 = exp2f(sC0[r] * 1.44269504f);
            float p1 = exp2f(sC1[r] * 1.44269504f);
            l4C[r] += p0 + p1;
            myPC[g4 * 4 + r][c16]      = f2bf(p0);
            myPC[g4 * 4 + r][16 + c16] = f2bf(p1);
        }
        if (hasD) {
            f32x4 sD0 = mfma16(qfragD, kf0, *(const f32x4*)(bttD + (((size_t)(jb*2+0)) << 8)));
            f32x4 sD1 = mfma16(qfragD, kf1, *(const f32x4*)(bttD + (((size_t)(jb*2+1)) << 8)));
            #pragma unroll
            for (int r = 0; r < 4; ++r) {
                float p0 = exp2f(sD0[r] * 1.44269504f);
                float p1 = exp2f(sD1[r] * 1.44269504f);
                l4D[r] += p0 + p1;
                PstD[g4 * 4 + r][c16]      = f2bf(p0);
                PstD[g4 * 4 + r][16 + c16] = f2bf(p1);
            }
        }
        s16x8 paA = __builtin_bit_cast(s16x8, *(const u16x8*)&myPA[c16][g4 * 8]);
        s16x8 paB = __builtin_bit_cast(s16x8, *(const u16x8*)&myPB[c16][g4 * 8]);
        s16x8 paC = __builtin_bit_cast(s16x8, *(const u16x8*)&myPC[c16][g4 * 8]);
        s16x8 vb0 = __builtin_bit_cast(s16x8, *(const u16x8*)&Vt[c16][jb * 32 + g4 * 8]);
        s16x8 vb1 = __builtin_bit_cast(s16x8, *(const u16x8*)&Vt[16 + c16][jb * 32 + g4 * 8]);
        oaccA0 = mfma16(paA, vb0, oaccA0);
        oaccA1 = mfma16(paA, vb1, oaccA1);
        oaccB0 = mfma16(paB, vb0, oaccB0);
        oaccB1 = mfma16(paB, vb1, oaccB1);
        oaccC0 = mfma16(paC, vb0, oaccC0);
        oaccC1 = mfma16(paC, vb1, oaccC1);
        if (hasD) {
            s16x8 paD = __builtin_bit_cast(s16x8, *(const u16x8*)&PstD[c16][g4 * 8]);
            oaccD0 = mfma16(paD, vb0, oaccD0);
            oaccD1 = mfma16(paD, vb1, oaccD1);
        }
    }

    #pragma unroll
    for (int r = 0; r < 4; ++r) {
        #pragma unroll
        for (int o = 1; o <= 8; o <<= 1) {
            l4A[r] += __shfl_xor(l4A[r], o);
            l4B[r] += __shfl_xor(l4B[r], o);
            l4C[r] += __shfl_xor(l4C[r], o);
        }
        l4A[r] = 1.f / l4A[r];
        l4B[r] = 1.f / l4B[r];
        l4C[r] = 1.f / l4C[r];
    }
    #pragma unroll
    for (int r = 0; r < 4; ++r) {
        int qA = tA * 16 + g4 * 4 + r;
        int qB = tB * 16 + g4 * 4 + r;
        int qC = tC * 16 + g4 * 4 + r;
        size_t oA = ((size_t)(win * NTOK + qA)) * CH + head * 32 + c16;
        size_t oB = ((size_t)(win * NTOK + qB)) * CH + head * 32 + c16;
        size_t oC = ((size_t)(win * NTOK + qC)) * CH + head * 32 + c16;
        O[oA]      = f2bf(oaccA0[r] * l4A[r]);
        O[oA + 16] = f2bf(oaccA1[r] * l4A[r]);
        O[oB]      = f2bf(oaccB0[r] * l4B[r]);
        O[oB + 16] = f2bf(oaccB1[r] * l4B[r]);
        O[oC]      = f2bf(oaccC0[r] * l4C[r]);
        O[oC + 16] = f2bf(oaccC1[r] * l4C[r]);
    }
    if (hasD) {
        #pragma unroll
        for (int r = 0; r < 4; ++r) {
            #pragma unroll
            for (int o = 1; o <= 8; o <<= 1)
                l4D[r] += __shfl_xor(l4D[r], o);
            l4D[r] = 1.f / l4D[r];
        }
        #pragma unroll
        for (int r = 0; r < 4; ++r) {
            int qD = 384 + g4 * 4 + r;
            if (qD < NTOK) {
                size_t oD = ((size_t)(win * NTOK + qD)) * CH + head * 32 + c16;
                O[oD]      = f2bf(oaccD0[r] * l4D[r]);
                O[oD + 16] = f2bf(oaccD1[r] * l4D[r]);
            }
        }
    }
}

extern "C" void kernel_launch(void* const* d_in, const int* in_sizes, int n_in,
                              void* d_out, int out_size, void* d_ws, size_t ws_size,
                              hipStream_t stream) {
    const float* x      = (const float*)d_in[0];
    const float* n1g    = (const float*)d_in[1];
    const float* n1b    = (const float*)d_in[2];
    const float* qkv_w  = (const float*)d_in[3];
    const float* qkv_b  = (const float*)d_in[4];
    const float* proj_w = (const float*)d_in[5];
    const float* proj_b = (const float*)d_in[6];
    const float* rpb    = (const float*)d_in[7];
    const float* n2g    = (const float*)d_in[8];
    const float* n2b    = (const float*)d_in[9];
    const float* fc1_w  = (const float*)d_in[10];
    const float* fc1_b  = (const float*)d_in[11];
    const float* fc2_w  = (const float*)d_in[12];
    const float* fc2_b  = (const float*)d_in[13];
    float* out = (float*)d_out;

    char* ws = (char*)d_ws;
    size_t off = 0;
    u16* A_bf  = (u16*)(ws + off);  off += (size_t)TOK * 128 * 2;   // LN2 out / biasT2 overlay
    u16* Qb_bf = (u16*)(ws + off);  off += (size_t)TOK * 384 * 2;
    u16* O_bf  = (u16*)(ws + off);  off += (size_t)TOK * 128 * 2;
    u16* R_bf  = (u16*)(ws + off);  off += (size_t)TOK * 128 * 2;   // bf16 residual trunk
    u16* qkvT  = (u16*)(ws + off);  off += 384 * 128 * 2;
    u16* projT = (u16*)(ws + off);  off += 128 * 128 * 2;
    u16* fc1T  = (u16*)(ws + off);  off += 512 * 128 * 2;
    u16* fc2T  = (u16*)(ws + off);  off += 128 * 512 * 2;
    float* biasT2 = (float*)A_bf;   // overlay; dead once proj's LN2 rewrites A_bf

    // 0. all weight transposes (+bf16), one launch; QSCALE folded into Wq
    hipLaunchKernelGGL(convT_all, dim3(16, 16, 4), dim3(256), 0, stream,
                       qkv_w, proj_w, fc1_w, fc2_w, qkvT, projT, fc1T, fc2T);
    // 0b. bias+mask table (overlay in A_bf)
    hipLaunchKernelGGL(bias_k, dim3(26, 25, 16), dim3(64), 0, stream, rpb, biasT2);
    // 1. fused LN1 + shift + qkv GEMM (single pass over x, 3 weight tiles)
    hipLaunchKernelGGL(qkv_ln, dim3(TOK/64), dim3(512), 0, stream,
                       x, qkvT, qkv_b, Qb_bf, n1g, n1b);
    // 2. flash attention, 3-tile interleave + wave-0 4th tile -> bf16
    hipLaunchKernelGGL(attn_mfma, dim3(NWIN * NHEADS), dim3(512), 0, stream,
                       Qb_bf, biasT2, O_bf);
    // 3. proj GEMM + unshift + residual -> bf16 R, fused LN2 -> bf16 A_bf
    hipLaunchKernelGGL(proj_ln, dim3(TOK/64), dim3(512), 0, stream,
                       O_bf, projT, proj_b, R_bf, x, n2g, n2b, A_bf);
    // 4. fused MLP (prefetched): fc1 + GELU + fc2 + residual -> f32 out
    hipLaunchKernelGGL(mlp_fused, dim3(TOK/64), dim3(512), 0, stream,
                       A_bf, fc1T, fc1_b, fc2T, fc2_b, R_bf, out);
}